// Round 1
// baseline (580.803 us; speedup 1.0000x reference)
//
#include <hip/hip_runtime.h>
#include <hip/hip_bf16.h>

#define HID 128

// ---------------- degree / histogram ----------------
__global__ void k_count(const int* __restrict__ src, const int* __restrict__ dst, int E,
                        int* __restrict__ degsrc, int* __restrict__ indeg) {
  int e = blockIdx.x * 256 + threadIdx.x;
  if (e < E) {
    atomicAdd(&degsrc[src[e]], 1);
    atomicAdd(&indeg[dst[e]], 1);
  }
}

__global__ void k_maxpart(const int* __restrict__ degsrc, int N, int* __restrict__ part) {
  __shared__ int sm[256];
  int m = 0;
  for (int i = blockIdx.x * 256 + threadIdx.x; i < N; i += 256 * 256) m = max(m, degsrc[i]);
  sm[threadIdx.x] = m; __syncthreads();
  for (int s = 128; s > 0; s >>= 1) {
    if (threadIdx.x < s) sm[threadIdx.x] = max(sm[threadIdx.x], sm[threadIdx.x + s]);
    __syncthreads();
  }
  if (threadIdx.x == 0) part[blockIdx.x] = sm[0];
}

__global__ void k_maxfin(const int* __restrict__ part, float* __restrict__ scal) {
  __shared__ int sm[256];
  sm[threadIdx.x] = part[threadIdx.x]; __syncthreads();
  for (int s = 128; s > 0; s >>= 1) {
    if (threadIdx.x < s) sm[threadIdx.x] = max(sm[threadIdx.x], sm[threadIdx.x + s]);
    __syncthreads();
  }
  if (threadIdx.x == 0) scal[0] = 1.0f / (float)max(sm[0], 1);
}

// node features x0=[cx,cy,degnorm], dinv = rsqrt(indeg+1)
__global__ void k_node(const float* __restrict__ coords, const int* __restrict__ degsrc,
                       const int* __restrict__ indeg, const float* __restrict__ scal,
                       int N, float* __restrict__ x0, float* __restrict__ dinv) {
  int n = blockIdx.x * 256 + threadIdx.x;
  if (n >= N) return;
  float inv = scal[0];
  x0[n * 3 + 0] = coords[n * 2 + 0];
  x0[n * 3 + 1] = coords[n * 2 + 1];
  x0[n * 3 + 2] = (float)degsrc[n] * inv;
  dinv[n] = rsqrtf((float)(indeg[n] + 1));
}

// ---------------- prefix sum (CSR rowptr) ----------------
__global__ void k_scan_part(const int* __restrict__ cnt, int N, int* __restrict__ rowptr,
                            int* __restrict__ bsum) {
  __shared__ int sm[256];
  int i = blockIdx.x * 256 + threadIdx.x;
  int v = (i < N) ? cnt[i] : 0;
  sm[threadIdx.x] = v; __syncthreads();
  for (int s = 1; s < 256; s <<= 1) {
    int t = (threadIdx.x >= s) ? sm[threadIdx.x - s] : 0;
    __syncthreads();
    sm[threadIdx.x] += t;
    __syncthreads();
  }
  if (i < N) rowptr[i] = sm[threadIdx.x] - v;  // block-local exclusive
  if (threadIdx.x == 255) bsum[blockIdx.x] = sm[255];
}

__global__ void k_scan_mid(int* __restrict__ bsum, int nblk) {
  __shared__ int sm[512];
  int i = threadIdx.x;
  int v = (i < nblk) ? bsum[i] : 0;
  sm[i] = v; __syncthreads();
  for (int s = 1; s < 512; s <<= 1) {
    int t = (i >= s) ? sm[i - s] : 0;
    __syncthreads();
    sm[i] += t;
    __syncthreads();
  }
  if (i < nblk) bsum[i] = sm[i] - v;  // exclusive
}

__global__ void k_scan_add(int* __restrict__ rowptr, const int* __restrict__ bsum, int N, int E) {
  int i = blockIdx.x * 256 + threadIdx.x;
  if (i < N) rowptr[i] += bsum[blockIdx.x];
  if (i == 0) rowptr[N] = E;
}

__global__ void k_scatter(const int* __restrict__ src, const int* __restrict__ dst, int E,
                          const int* __restrict__ rowptr, int* __restrict__ cursor,
                          int* __restrict__ col) {
  int e = blockIdx.x * 256 + threadIdx.x;
  if (e < E) {
    int d = dst[e];
    int pos = rowptr[d] + atomicAdd(&cursor[d], 1);
    col[pos] = src[e];
  }
}

// ---------------- GCN aggregation ----------------
// layer 1: 3 features, one thread per node
__global__ void k_agg3(const float* __restrict__ x0, const float* __restrict__ dinv,
                       const int* __restrict__ rowptr, const int* __restrict__ col,
                       int N, float* __restrict__ xa3) {
  int n = blockIdx.x * 256 + threadIdx.x;
  if (n >= N) return;
  float di = dinv[n];
  float a0 = x0[n * 3 + 0] * di;
  float a1 = x0[n * 3 + 1] * di;
  float a2 = x0[n * 3 + 2] * di;
  int b = rowptr[n], en = rowptr[n + 1];
  for (int k = b; k < en; k++) {
    int s = col[k];
    float ds = dinv[s];
    a0 += x0[s * 3 + 0] * ds;
    a1 += x0[s * 3 + 1] * ds;
    a2 += x0[s * 3 + 2] * ds;
  }
  xa3[n * 3 + 0] = a0 * di;
  xa3[n * 3 + 1] = a1 * di;
  xa3[n * 3 + 2] = a2 * di;
}

// layer 1 linear: x1 = relu(xa3 @ W1 + b1), thread per (node, feature)
__global__ void k_lin1(const float* __restrict__ xa3, const float* __restrict__ W1,
                       const float* __restrict__ b1, int N, float* __restrict__ x1) {
  int idx = blockIdx.x * 256 + threadIdx.x;
  if (idx >= N * HID) return;
  int n = idx >> 7, f = idx & 127;
  float v = b1[f] + xa3[n * 3 + 0] * W1[f] + xa3[n * 3 + 1] * W1[128 + f] +
            xa3[n * 3 + 2] * W1[256 + f];
  x1[idx] = fmaxf(v, 0.f);
}

// layer 2 aggregation: 32 lanes per node, float4 per lane (128 feats)
__global__ void k_agg128(const float* __restrict__ x1, const float* __restrict__ dinv,
                         const int* __restrict__ rowptr, const int* __restrict__ col,
                         int N, float* __restrict__ xa) {
  int g = (int)((blockIdx.x * 256 + threadIdx.x) >> 5);
  int lane = threadIdx.x & 31;
  if (g >= N) return;
  float di = dinv[g];
  float4 acc = *(const float4*)(x1 + (size_t)g * HID + lane * 4);
  acc.x *= di; acc.y *= di; acc.z *= di; acc.w *= di;
  int b = rowptr[g], en = rowptr[g + 1];
  for (int k = b; k < en; k++) {
    int s = col[k];
    float ds = dinv[s];
    float4 w = *(const float4*)(x1 + (size_t)s * HID + lane * 4);
    acc.x += w.x * ds; acc.y += w.y * ds; acc.z += w.z * ds; acc.w += w.w * ds;
  }
  acc.x *= di; acc.y *= di; acc.z *= di; acc.w *= di;
  *(float4*)(xa + (size_t)g * HID + lane * 4) = acc;
}

// layer 2 GEMM: x2 = relu(xa @ W2 + b2). 64-node tile, 4 nodes x 8 feats per thread.
__global__ __launch_bounds__(256) void k_gemm2(const float* __restrict__ xa,
                                               const float* __restrict__ W2,
                                               const float* __restrict__ b2, int N,
                                               float* __restrict__ x2) {
  __shared__ float xs[64 * 132];
  int n0 = blockIdx.x * 64;
  for (int t = threadIdx.x; t < 64 * 32; t += 256) {
    int n = t >> 5, c = t & 31;
    int gn = n0 + n;
    float4 v = make_float4(0.f, 0.f, 0.f, 0.f);
    if (gn < N) v = *(const float4*)(xa + (size_t)gn * HID + c * 4);
    *(float4*)(xs + n * 132 + c * 4) = v;
  }
  __syncthreads();
  int col = threadIdx.x & 15;
  int row = threadIdx.x >> 4;
  int j0 = col * 8;
  float acc[4][8];
#pragma unroll
  for (int i = 0; i < 4; i++)
#pragma unroll
    for (int j = 0; j < 8; j++) acc[i][j] = 0.f;
  for (int k = 0; k < 128; k++) {
    float4 wA = *(const float4*)(W2 + k * 128 + j0);
    float4 wB = *(const float4*)(W2 + k * 128 + j0 + 4);
    float xv[4];
#pragma unroll
    for (int i = 0; i < 4; i++) xv[i] = xs[(row * 4 + i) * 132 + k];
#pragma unroll
    for (int i = 0; i < 4; i++) {
      acc[i][0] += xv[i] * wA.x; acc[i][1] += xv[i] * wA.y;
      acc[i][2] += xv[i] * wA.z; acc[i][3] += xv[i] * wA.w;
      acc[i][4] += xv[i] * wB.x; acc[i][5] += xv[i] * wB.y;
      acc[i][6] += xv[i] * wB.z; acc[i][7] += xv[i] * wB.w;
    }
  }
  float bj[8];
#pragma unroll
  for (int j = 0; j < 8; j++) bj[j] = b2[j0 + j];
#pragma unroll
  for (int i = 0; i < 4; i++) {
    int gn = n0 + row * 4 + i;
    if (gn < N) {
      float4 o1 = make_float4(fmaxf(acc[i][0] + bj[0], 0.f), fmaxf(acc[i][1] + bj[1], 0.f),
                              fmaxf(acc[i][2] + bj[2], 0.f), fmaxf(acc[i][3] + bj[3], 0.f));
      float4 o2 = make_float4(fmaxf(acc[i][4] + bj[4], 0.f), fmaxf(acc[i][5] + bj[5], 0.f),
                              fmaxf(acc[i][6] + bj[6], 0.f), fmaxf(acc[i][7] + bj[7], 0.f));
      *(float4*)(x2 + (size_t)gn * HID + j0) = o1;
      *(float4*)(x2 + (size_t)gn * HID + j0 + 4) = o2;
    }
  }
}

// ---------------- heads ----------------
// per node: s = x@Ws+bs (store), mu = x@Wmu+bmu, ls = clip(x@Wls+bls). 32 lanes/node.
__global__ void k_heads(const float* __restrict__ x2, const float* __restrict__ Ws,
                        const float* __restrict__ bs, const float* __restrict__ Wmu,
                        const float* __restrict__ bmu, const float* __restrict__ Wls,
                        const float* __restrict__ bls, int N, float* __restrict__ s_arr,
                        float* __restrict__ out) {
  __shared__ float w[640];
  for (int t = threadIdx.x; t < 128; t += 256) {
    w[t] = Ws[t];
    w[128 + t] = Wmu[t * 2 + 0];
    w[256 + t] = Wmu[t * 2 + 1];
    w[384 + t] = Wls[t * 2 + 0];
    w[512 + t] = Wls[t * 2 + 1];
  }
  __syncthreads();
  int g = (int)((blockIdx.x * 256 + threadIdx.x) >> 5);
  int lane = threadIdx.x & 31;
  if (g >= N) return;
  float4 v = *(const float4*)(x2 + (size_t)g * HID + lane * 4);
  float xv[4] = {v.x, v.y, v.z, v.w};
  int f0 = lane * 4;
  float p0 = 0, p1 = 0, p2 = 0, p3 = 0, p4 = 0;
#pragma unroll
  for (int i = 0; i < 4; i++) {
    p0 += xv[i] * w[f0 + i];
    p1 += xv[i] * w[128 + f0 + i];
    p2 += xv[i] * w[256 + f0 + i];
    p3 += xv[i] * w[384 + f0 + i];
    p4 += xv[i] * w[512 + f0 + i];
  }
#pragma unroll
  for (int m = 1; m < 32; m <<= 1) {
    p0 += __shfl_xor(p0, m);
    p1 += __shfl_xor(p1, m);
    p2 += __shfl_xor(p2, m);
    p3 += __shfl_xor(p3, m);
    p4 += __shfl_xor(p4, m);
  }
  if (lane == 0) {
    s_arr[g] = p0 + bs[0];
    out[(size_t)N + g * 2 + 0] = p1 + bmu[0];
    out[(size_t)N + g * 2 + 1] = p2 + bmu[1];
    out[(size_t)3 * N + g * 2 + 0] = fminf(fmaxf(p3 + bls[0], -4.f), 2.f);
    out[(size_t)3 * N + g * 2 + 1] = fminf(fmaxf(p4 + bls[1], -4.f), 2.f);
  }
}

// column sums of x2 (for mean)
__global__ void k_colsum(const float* __restrict__ x2, int N, float* __restrict__ colsum) {
  int f = threadIdx.x & 127;
  int r = threadIdx.x >> 7;  // 0..1
  float acc = 0.f;
  for (int n = blockIdx.x * 2 + r; n < N; n += gridDim.x * 2) acc += x2[(size_t)n * HID + f];
  __shared__ float sm[256];
  sm[threadIdx.x] = acc; __syncthreads();
  if (threadIdx.x < 128) atomicAdd(&colsum[f], sm[f] + sm[128 + f]);
}

// ---------------- logsumexp ----------------
__global__ void k_smax_part(const float* __restrict__ s, int N, float* __restrict__ part) {
  __shared__ float sm[256];
  float m = -1e30f;
  for (int i = blockIdx.x * 256 + threadIdx.x; i < N; i += 256 * 256) m = fmaxf(m, s[i]);
  sm[threadIdx.x] = m; __syncthreads();
  for (int st = 128; st > 0; st >>= 1) {
    if (threadIdx.x < st) sm[threadIdx.x] = fmaxf(sm[threadIdx.x], sm[threadIdx.x + st]);
    __syncthreads();
  }
  if (threadIdx.x == 0) part[blockIdx.x] = sm[0];
}

__global__ void k_smax_fin(const float* __restrict__ part, float* __restrict__ scal) {
  __shared__ float sm[256];
  sm[threadIdx.x] = part[threadIdx.x]; __syncthreads();
  for (int st = 128; st > 0; st >>= 1) {
    if (threadIdx.x < st) sm[threadIdx.x] = fmaxf(sm[threadIdx.x], sm[threadIdx.x + st]);
    __syncthreads();
  }
  if (threadIdx.x == 0) scal[1] = sm[0];
}

__global__ void k_sexp_part(const float* __restrict__ s, const float* __restrict__ scal, int N,
                            float* __restrict__ part) {
  __shared__ float sm[256];
  float m = scal[1];
  float a = 0.f;
  for (int i = blockIdx.x * 256 + threadIdx.x; i < N; i += 256 * 256) a += expf(s[i] - m);
  sm[threadIdx.x] = a; __syncthreads();
  for (int st = 128; st > 0; st >>= 1) {
    if (threadIdx.x < st) sm[threadIdx.x] += sm[threadIdx.x + st];
    __syncthreads();
  }
  if (threadIdx.x == 0) part[blockIdx.x] = sm[0];
}

__global__ void k_lse_fin(const float* __restrict__ part, float* __restrict__ scal) {
  __shared__ float sm[256];
  sm[threadIdx.x] = part[threadIdx.x]; __syncthreads();
  for (int st = 128; st > 0; st >>= 1) {
    if (threadIdx.x < st) sm[threadIdx.x] += sm[threadIdx.x + st];
    __syncthreads();
  }
  if (threadIdx.x == 0) scal[2] = scal[1] + logf(sm[0]);
}

__global__ void k_logits(const float* __restrict__ s, const float* __restrict__ scal, int N,
                         float* __restrict__ out) {
  int n = blockIdx.x * 256 + threadIdx.x;
  if (n < N) out[n] = s[n] - scal[2];
}

// ---------------- value head ----------------
__global__ void k_value(const float* __restrict__ colsum, const float* __restrict__ Wv1,
                        const float* __restrict__ bv1, const float* __restrict__ Wv2,
                        const float* __restrict__ bv2, int N, float* __restrict__ out5N) {
  __shared__ float hid[64];
  float invN = 1.0f / (float)N;
  int j = threadIdx.x;
  if (j < 64) {
    float a = bv1[j];
    for (int f = 0; f < 128; f++) a += (colsum[f] * invN) * Wv1[f * 64 + j];
    hid[j] = fmaxf(a, 0.f) * Wv2[j];
  }
  __syncthreads();
  if (threadIdx.x == 0) {
    float v = bv2[0];
    for (int jj = 0; jj < 64; jj++) v += hid[jj];
    out5N[0] = v;
  }
}

extern "C" void kernel_launch(void* const* d_in, const int* in_sizes, int n_in,
                              void* d_out, int out_size, void* d_ws, size_t ws_size,
                              hipStream_t stream) {
  const float* coords = (const float*)d_in[0];
  const int* ei = (const int*)d_in[1];
  const float* W1 = (const float*)d_in[2];
  const float* b1 = (const float*)d_in[3];
  const float* W2 = (const float*)d_in[4];
  const float* b2 = (const float*)d_in[5];
  const float* Wsw = (const float*)d_in[6];
  const float* bsw = (const float*)d_in[7];
  const float* Wmu = (const float*)d_in[8];
  const float* bmu = (const float*)d_in[9];
  const float* Wls = (const float*)d_in[10];
  const float* bls = (const float*)d_in[11];
  const float* Wv1 = (const float*)d_in[12];
  const float* bv1 = (const float*)d_in[13];
  const float* Wv2 = (const float*)d_in[14];
  const float* bv2 = (const float*)d_in[15];
  int N = in_sizes[0] / 2;
  int E = in_sizes[1] / 2;
  const int* src = ei;
  const int* dst = ei + E;
  float* outf = (float*)d_out;

  char* base = (char*)d_ws;
  size_t off = 0;
  auto alloc = [&](size_t bytes) -> void* {
    void* r = base + off;
    off += (bytes + 255) & ~(size_t)255;
    return r;
  };
  size_t zero_start = off;
  int* degsrc = (int*)alloc((size_t)N * 4);
  int* indeg = (int*)alloc((size_t)N * 4);
  int* cursor = (int*)alloc((size_t)N * 4);
  float* colsum = (float*)alloc(128 * 4);
  size_t zero_bytes = off - zero_start;
  int* rowptr = (int*)alloc(((size_t)N + 1) * 4);
  int* bsum = (int*)alloc(512 * 4);
  int* colarr = (int*)alloc((size_t)E * 4);
  float* x0 = (float*)alloc((size_t)N * 3 * 4);
  float* xa3 = (float*)alloc((size_t)N * 3 * 4);
  float* dinv = (float*)alloc((size_t)N * 4);
  float* sarr = (float*)alloc((size_t)N * 4);
  float* part = (float*)alloc(256 * 4);
  float* part2 = (float*)alloc(256 * 4);
  float* scal = (float*)alloc(16 * 4);
  float* bufA = (float*)alloc((size_t)N * HID * 4);
  float* bufC = (float*)alloc((size_t)N * HID * 4);
  if (off > ws_size) return;  // insufficient workspace; fail loudly in validation

  int nblkE = (E + 255) / 256;
  int nblkN = (N + 255) / 256;

  hipMemsetAsync(base + zero_start, 0, zero_bytes, stream);
  k_count<<<nblkE, 256, 0, stream>>>(src, dst, E, degsrc, indeg);
  k_maxpart<<<256, 256, 0, stream>>>(degsrc, N, (int*)part);
  k_maxfin<<<1, 256, 0, stream>>>((int*)part, scal);
  k_node<<<nblkN, 256, 0, stream>>>(coords, degsrc, indeg, scal, N, x0, dinv);
  k_scan_part<<<nblkN, 256, 0, stream>>>(indeg, N, rowptr, bsum);
  k_scan_mid<<<1, 512, 0, stream>>>(bsum, nblkN);
  k_scan_add<<<nblkN, 256, 0, stream>>>(rowptr, bsum, N, E);
  k_scatter<<<nblkE, 256, 0, stream>>>(src, dst, E, rowptr, cursor, colarr);
  k_agg3<<<nblkN, 256, 0, stream>>>(x0, dinv, rowptr, colarr, N, xa3);
  k_lin1<<<(N * HID + 255) / 256, 256, 0, stream>>>(xa3, W1, b1, N, bufC);
  k_agg128<<<(N + 7) / 8, 256, 0, stream>>>(bufC, dinv, rowptr, colarr, N, bufA);
  k_gemm2<<<(N + 63) / 64, 256, 0, stream>>>(bufA, W2, b2, N, bufC);
  k_heads<<<(N + 7) / 8, 256, 0, stream>>>(bufC, Wsw, bsw, Wmu, bmu, Wls, bls, N, sarr, outf);
  k_colsum<<<256, 256, 0, stream>>>(bufC, N, colsum);
  k_smax_part<<<256, 256, 0, stream>>>(sarr, N, part);
  k_smax_fin<<<1, 256, 0, stream>>>(part, scal);
  k_sexp_part<<<256, 256, 0, stream>>>(sarr, scal, N, part2);
  k_lse_fin<<<1, 256, 0, stream>>>(part2, scal);
  k_logits<<<nblkN, 256, 0, stream>>>(sarr, scal, N, outf);
  k_value<<<1, 64, 0, stream>>>(colsum, Wv1, bv1, Wv2, bv2, N, outf + (size_t)5 * N);
}

// Round 2
// 483.780 us; speedup vs baseline: 1.2006x; 1.2006x over previous
//
#include <hip/hip_runtime.h>
#include <hip/hip_bf16.h>

#define HID 128

__device__ __forceinline__ float b2f(unsigned int u) { return __uint_as_float(u << 16); }
__device__ __forceinline__ float b2f_hi(unsigned int u) { return __uint_as_float(u & 0xFFFF0000u); }
__device__ __forceinline__ unsigned int f2b(float f) {
  unsigned int b = __float_as_uint(f);
  return (b + 0x7FFFu + ((b >> 16) & 1u)) >> 16;
}
__device__ __forceinline__ unsigned int pack2(float lo, float hi) {
  return f2b(lo) | (f2b(hi) << 16);
}

// ---------------- degree / histogram ----------------
__global__ void k_count(const int* __restrict__ src, const int* __restrict__ dst, int E,
                        int* __restrict__ degsrc, int* __restrict__ indeg) {
  int e = blockIdx.x * 256 + threadIdx.x;
  if (e < E) {
    atomicAdd(&degsrc[src[e]], 1);
    atomicAdd(&indeg[dst[e]], 1);
  }
}

__global__ void k_maxpart(const int* __restrict__ degsrc, int N, int* __restrict__ part) {
  __shared__ int sm[256];
  int m = 0;
  for (int i = blockIdx.x * 256 + threadIdx.x; i < N; i += 256 * 256) m = max(m, degsrc[i]);
  sm[threadIdx.x] = m; __syncthreads();
  for (int s = 128; s > 0; s >>= 1) {
    if (threadIdx.x < s) sm[threadIdx.x] = max(sm[threadIdx.x], sm[threadIdx.x + s]);
    __syncthreads();
  }
  if (threadIdx.x == 0) part[blockIdx.x] = sm[0];
}

__global__ void k_maxfin(const int* __restrict__ part, float* __restrict__ scal) {
  __shared__ int sm[256];
  sm[threadIdx.x] = part[threadIdx.x]; __syncthreads();
  for (int s = 128; s > 0; s >>= 1) {
    if (threadIdx.x < s) sm[threadIdx.x] = max(sm[threadIdx.x], sm[threadIdx.x + s]);
    __syncthreads();
  }
  if (threadIdx.x == 0) scal[0] = 1.0f / (float)max(sm[0], 1);
}

// node features prescaled by own dinv: x0s[n] = [cx,cy,degn,0] * dinv[n] (float4 padded)
__global__ void k_node(const float* __restrict__ coords, const int* __restrict__ degsrc,
                       const int* __restrict__ indeg, const float* __restrict__ scal,
                       int N, float4* __restrict__ x0s, float* __restrict__ dinv) {
  int n = blockIdx.x * 256 + threadIdx.x;
  if (n >= N) return;
  float inv = scal[0];
  float di = rsqrtf((float)(indeg[n] + 1));
  dinv[n] = di;
  float4 v;
  v.x = coords[n * 2 + 0] * di;
  v.y = coords[n * 2 + 1] * di;
  v.z = (float)degsrc[n] * inv * di;
  v.w = 0.f;
  x0s[n] = v;
}

// ---------------- prefix sum (CSR rowptr) ----------------
__global__ void k_scan_part(const int* __restrict__ cnt, int N, int* __restrict__ rowptr,
                            int* __restrict__ bsum) {
  __shared__ int sm[256];
  int i = blockIdx.x * 256 + threadIdx.x;
  int v = (i < N) ? cnt[i] : 0;
  sm[threadIdx.x] = v; __syncthreads();
  for (int s = 1; s < 256; s <<= 1) {
    int t = (threadIdx.x >= s) ? sm[threadIdx.x - s] : 0;
    __syncthreads();
    sm[threadIdx.x] += t;
    __syncthreads();
  }
  if (i < N) rowptr[i] = sm[threadIdx.x] - v;
  if (threadIdx.x == 255) bsum[blockIdx.x] = sm[255];
}

__global__ void k_scan_mid(int* __restrict__ bsum, int nblk) {
  __shared__ int sm[512];
  int i = threadIdx.x;
  int v = (i < nblk) ? bsum[i] : 0;
  sm[i] = v; __syncthreads();
  for (int s = 1; s < 512; s <<= 1) {
    int t = (i >= s) ? sm[i - s] : 0;
    __syncthreads();
    sm[i] += t;
    __syncthreads();
  }
  if (i < nblk) bsum[i] = sm[i] - v;
}

__global__ void k_scan_add(int* __restrict__ rowptr, const int* __restrict__ bsum, int N, int E) {
  int i = blockIdx.x * 256 + threadIdx.x;
  if (i < N) rowptr[i] += bsum[blockIdx.x];
  if (i == 0) rowptr[N] = E;
}

__global__ void k_scatter(const int* __restrict__ src, const int* __restrict__ dst, int E,
                          const int* __restrict__ rowptr, int* __restrict__ cursor,
                          int* __restrict__ col) {
  int e = blockIdx.x * 256 + threadIdx.x;
  if (e < E) {
    int d = dst[e];
    int pos = rowptr[d] + atomicAdd(&cursor[d], 1);
    col[pos] = src[e];
  }
}

// ---------------- GCN layer 1 ----------------
// agg: xa3[n] = dinv[n] * (sum_{s->n} x0s[s] + x0s[n])   (float4 gathers)
__global__ void k_agg3(const float4* __restrict__ x0s, const float* __restrict__ dinv,
                       const int* __restrict__ rowptr, const int* __restrict__ col,
                       int N, float4* __restrict__ xa3) {
  int n = blockIdx.x * 256 + threadIdx.x;
  if (n >= N) return;
  float4 a = x0s[n];
  int b = rowptr[n], en = rowptr[n + 1];
  int k = b;
  for (; k + 1 < en; k += 2) {
    int s0 = col[k], s1 = col[k + 1];
    float4 w0 = x0s[s0];
    float4 w1 = x0s[s1];
    a.x += w0.x + w1.x; a.y += w0.y + w1.y; a.z += w0.z + w1.z;
  }
  if (k < en) {
    float4 w = x0s[col[k]];
    a.x += w.x; a.y += w.y; a.z += w.z;
  }
  float di = dinv[n];
  a.x *= di; a.y *= di; a.z *= di; a.w = 0.f;
  xa3[n] = a;
}

// linear: x1s = relu(xa3 @ W1 + b1) * dinv[n], stored bf16
__global__ void k_lin1(const float4* __restrict__ xa3, const float* __restrict__ dinv,
                       const float* __restrict__ W1, const float* __restrict__ b1, int N,
                       unsigned short* __restrict__ x1s) {
  int idx = blockIdx.x * 256 + threadIdx.x;
  if (idx >= N * HID) return;
  int n = idx >> 7, f = idx & 127;
  float4 a = xa3[n];
  float v = b1[f] + a.x * W1[f] + a.y * W1[128 + f] + a.z * W1[256 + f];
  v = fmaxf(v, 0.f) * dinv[n];
  x1s[idx] = (unsigned short)f2b(v);
}

// ---------------- GCN layer 2 aggregation ----------------
// 32 lanes/node, uint2 (4 bf16) per lane. xa[n] = dinv[n]*(sum x1s[s] + x1s[n]) as bf16
__global__ void k_agg128(const unsigned short* __restrict__ x1s, const float* __restrict__ dinv,
                         const int* __restrict__ rowptr, const int* __restrict__ col,
                         int N, unsigned short* __restrict__ xa) {
  int g = (int)((blockIdx.x * 256 + threadIdx.x) >> 5);
  int lane = threadIdx.x & 31;
  if (g >= N) return;
  const uint2* base = (const uint2*)x1s + lane;  // element stride 32 uint2 per row
  uint2 self = base[(size_t)g * 32];
  float a0 = b2f(self.x), a1 = b2f_hi(self.x), a2 = b2f(self.y), a3 = b2f_hi(self.y);
  int b = rowptr[g], en = rowptr[g + 1];
  int k = b;
  for (; k + 1 < en; k += 2) {
    int s0 = col[k], s1 = col[k + 1];
    uint2 w0 = base[(size_t)s0 * 32];
    uint2 w1 = base[(size_t)s1 * 32];
    a0 += b2f(w0.x) + b2f(w1.x);
    a1 += b2f_hi(w0.x) + b2f_hi(w1.x);
    a2 += b2f(w0.y) + b2f(w1.y);
    a3 += b2f_hi(w0.y) + b2f_hi(w1.y);
  }
  if (k < en) {
    uint2 w = base[(size_t)col[k] * 32];
    a0 += b2f(w.x); a1 += b2f_hi(w.x); a2 += b2f(w.y); a3 += b2f_hi(w.y);
  }
  float di = dinv[g];
  uint2 o;
  o.x = pack2(a0 * di, a1 * di);
  o.y = pack2(a2 * di, a3 * di);
  ((uint2*)xa)[(size_t)g * 32 + lane] = o;
}

// ---------------- layer 2 GEMM (bf16 in/out, f32 compute) + fused colsum ----------------
__global__ __launch_bounds__(256) void k_gemm2(const unsigned short* __restrict__ xa,
                                               const float* __restrict__ W2,
                                               const float* __restrict__ b2, int N,
                                               unsigned short* __restrict__ x2,
                                               float* __restrict__ colsum) {
  __shared__ float xs[64 * 132];
  __shared__ float cs[16][128];
  int n0 = blockIdx.x * 64;
  for (int t = threadIdx.x; t < 64 * 16; t += 256) {
    int n = t >> 4, c = t & 15;
    int gn = n0 + n;
    uint4 v = make_uint4(0, 0, 0, 0);
    if (gn < N) v = ((const uint4*)(xa + (size_t)gn * HID))[c];
    float* d = xs + n * 132 + c * 8;
    d[0] = b2f(v.x); d[1] = b2f_hi(v.x);
    d[2] = b2f(v.y); d[3] = b2f_hi(v.y);
    d[4] = b2f(v.z); d[5] = b2f_hi(v.z);
    d[6] = b2f(v.w); d[7] = b2f_hi(v.w);
  }
  __syncthreads();
  int col = threadIdx.x & 15;
  int row = threadIdx.x >> 4;
  int j0 = col * 8;
  float acc[4][8];
#pragma unroll
  for (int i = 0; i < 4; i++)
#pragma unroll
    for (int j = 0; j < 8; j++) acc[i][j] = 0.f;
  for (int k = 0; k < 128; k++) {
    float4 wA = *(const float4*)(W2 + k * 128 + j0);
    float4 wB = *(const float4*)(W2 + k * 128 + j0 + 4);
    float xv[4];
#pragma unroll
    for (int i = 0; i < 4; i++) xv[i] = xs[(row * 4 + i) * 132 + k];
#pragma unroll
    for (int i = 0; i < 4; i++) {
      acc[i][0] += xv[i] * wA.x; acc[i][1] += xv[i] * wA.y;
      acc[i][2] += xv[i] * wA.z; acc[i][3] += xv[i] * wA.w;
      acc[i][4] += xv[i] * wB.x; acc[i][5] += xv[i] * wB.y;
      acc[i][6] += xv[i] * wB.z; acc[i][7] += xv[i] * wB.w;
    }
  }
  float bj[8];
#pragma unroll
  for (int j = 0; j < 8; j++) bj[j] = b2[j0 + j];
  float csum[8];
#pragma unroll
  for (int j = 0; j < 8; j++) csum[j] = 0.f;
#pragma unroll
  for (int i = 0; i < 4; i++) {
    int gn = n0 + row * 4 + i;
    if (gn < N) {
      float o[8];
#pragma unroll
      for (int j = 0; j < 8; j++) {
        o[j] = fmaxf(acc[i][j] + bj[j], 0.f);
        csum[j] += o[j];
      }
      uint4 pk;
      pk.x = pack2(o[0], o[1]);
      pk.y = pack2(o[2], o[3]);
      pk.z = pack2(o[4], o[5]);
      pk.w = pack2(o[6], o[7]);
      *(uint4*)(x2 + (size_t)gn * HID + j0) = pk;
    }
  }
#pragma unroll
  for (int j = 0; j < 8; j++) cs[row][j0 + j] = csum[j];
  __syncthreads();
  if (threadIdx.x < 128) {
    int f = threadIdx.x;
    float t = 0.f;
#pragma unroll
    for (int r = 0; r < 16; r++) t += cs[r][f];
    atomicAdd(&colsum[f], t);
  }
}

// ---------------- heads (x2 bf16) ----------------
__global__ void k_heads(const unsigned short* __restrict__ x2, const float* __restrict__ Ws,
                        const float* __restrict__ bs, const float* __restrict__ Wmu,
                        const float* __restrict__ bmu, const float* __restrict__ Wls,
                        const float* __restrict__ bls, int N, float* __restrict__ s_arr,
                        float* __restrict__ out) {
  __shared__ float w[640];
  for (int t = threadIdx.x; t < 128; t += 256) {
    w[t] = Ws[t];
    w[128 + t] = Wmu[t * 2 + 0];
    w[256 + t] = Wmu[t * 2 + 1];
    w[384 + t] = Wls[t * 2 + 0];
    w[512 + t] = Wls[t * 2 + 1];
  }
  __syncthreads();
  int g = (int)((blockIdx.x * 256 + threadIdx.x) >> 5);
  int lane = threadIdx.x & 31;
  if (g >= N) return;
  uint2 v = ((const uint2*)x2)[(size_t)g * 32 + lane];
  float xv[4] = {b2f(v.x), b2f_hi(v.x), b2f(v.y), b2f_hi(v.y)};
  int f0 = lane * 4;
  float p0 = 0, p1 = 0, p2 = 0, p3 = 0, p4 = 0;
#pragma unroll
  for (int i = 0; i < 4; i++) {
    p0 += xv[i] * w[f0 + i];
    p1 += xv[i] * w[128 + f0 + i];
    p2 += xv[i] * w[256 + f0 + i];
    p3 += xv[i] * w[384 + f0 + i];
    p4 += xv[i] * w[512 + f0 + i];
  }
#pragma unroll
  for (int m = 1; m < 32; m <<= 1) {
    p0 += __shfl_xor(p0, m);
    p1 += __shfl_xor(p1, m);
    p2 += __shfl_xor(p2, m);
    p3 += __shfl_xor(p3, m);
    p4 += __shfl_xor(p4, m);
  }
  if (lane == 0) {
    s_arr[g] = p0 + bs[0];
    out[(size_t)N + g * 2 + 0] = p1 + bmu[0];
    out[(size_t)N + g * 2 + 1] = p2 + bmu[1];
    out[(size_t)3 * N + g * 2 + 0] = fminf(fmaxf(p3 + bls[0], -4.f), 2.f);
    out[(size_t)3 * N + g * 2 + 1] = fminf(fmaxf(p4 + bls[1], -4.f), 2.f);
  }
}

// ---------------- online logsumexp (2 kernels) ----------------
__global__ void k_lse_part(const float* __restrict__ s, int N, float* __restrict__ pm,
                           float* __restrict__ pt) {
  __shared__ float smM[256], smT[256];
  float m = -1e30f, t = 0.f;
  for (int i = blockIdx.x * 256 + threadIdx.x; i < N; i += 256 * 256) {
    float v = s[i];
    if (v > m) { t = t * __expf(m - v) + 1.f; m = v; }
    else t += __expf(v - m);
  }
  smM[threadIdx.x] = m; smT[threadIdx.x] = t; __syncthreads();
  for (int st = 128; st > 0; st >>= 1) {
    if (threadIdx.x < st) {
      float m2 = smM[threadIdx.x + st], t2 = smT[threadIdx.x + st];
      float m1 = smM[threadIdx.x], t1 = smT[threadIdx.x];
      float M = fmaxf(m1, m2);
      smM[threadIdx.x] = M;
      smT[threadIdx.x] = t1 * __expf(m1 - M) + t2 * __expf(m2 - M);
    }
    __syncthreads();
  }
  if (threadIdx.x == 0) { pm[blockIdx.x] = smM[0]; pt[blockIdx.x] = smT[0]; }
}

__global__ void k_lse_fin(const float* __restrict__ pm, const float* __restrict__ pt,
                          float* __restrict__ scal) {
  __shared__ float smM[256], smT[256];
  smM[threadIdx.x] = pm[threadIdx.x];
  smT[threadIdx.x] = pt[threadIdx.x];
  __syncthreads();
  for (int st = 128; st > 0; st >>= 1) {
    if (threadIdx.x < st) {
      float m2 = smM[threadIdx.x + st], t2 = smT[threadIdx.x + st];
      float m1 = smM[threadIdx.x], t1 = smT[threadIdx.x];
      float M = fmaxf(m1, m2);
      smM[threadIdx.x] = M;
      smT[threadIdx.x] = t1 * __expf(m1 - M) + t2 * __expf(m2 - M);
    }
    __syncthreads();
  }
  if (threadIdx.x == 0) scal[2] = smM[0] + logf(smT[0]);
}

__global__ void k_logits(const float* __restrict__ s, const float* __restrict__ scal, int N,
                         float* __restrict__ out) {
  int n = blockIdx.x * 256 + threadIdx.x;
  if (n < N) out[n] = s[n] - scal[2];
}

// ---------------- value head ----------------
__global__ void k_value(const float* __restrict__ colsum, const float* __restrict__ Wv1,
                        const float* __restrict__ bv1, const float* __restrict__ Wv2,
                        const float* __restrict__ bv2, int N, float* __restrict__ out5N) {
  __shared__ float hid[64];
  float invN = 1.0f / (float)N;
  int j = threadIdx.x;
  if (j < 64) {
    float a = bv1[j];
    for (int f = 0; f < 128; f++) a += (colsum[f] * invN) * Wv1[f * 64 + j];
    hid[j] = fmaxf(a, 0.f) * Wv2[j];
  }
  __syncthreads();
  if (threadIdx.x == 0) {
    float v = bv2[0];
    for (int jj = 0; jj < 64; jj++) v += hid[jj];
    out5N[0] = v;
  }
}

extern "C" void kernel_launch(void* const* d_in, const int* in_sizes, int n_in,
                              void* d_out, int out_size, void* d_ws, size_t ws_size,
                              hipStream_t stream) {
  const float* coords = (const float*)d_in[0];
  const int* ei = (const int*)d_in[1];
  const float* W1 = (const float*)d_in[2];
  const float* b1 = (const float*)d_in[3];
  const float* W2 = (const float*)d_in[4];
  const float* b2 = (const float*)d_in[5];
  const float* Wsw = (const float*)d_in[6];
  const float* bsw = (const float*)d_in[7];
  const float* Wmu = (const float*)d_in[8];
  const float* bmu = (const float*)d_in[9];
  const float* Wls = (const float*)d_in[10];
  const float* bls = (const float*)d_in[11];
  const float* Wv1 = (const float*)d_in[12];
  const float* bv1 = (const float*)d_in[13];
  const float* Wv2 = (const float*)d_in[14];
  const float* bv2 = (const float*)d_in[15];
  int N = in_sizes[0] / 2;
  int E = in_sizes[1] / 2;
  const int* src = ei;
  const int* dst = ei + E;
  float* outf = (float*)d_out;

  char* base = (char*)d_ws;
  size_t off = 0;
  auto alloc = [&](size_t bytes) -> void* {
    void* r = base + off;
    off += (bytes + 255) & ~(size_t)255;
    return r;
  };
  size_t zero_start = off;
  int* degsrc = (int*)alloc((size_t)N * 4);
  int* indeg = (int*)alloc((size_t)N * 4);
  int* cursor = (int*)alloc((size_t)N * 4);
  float* colsum = (float*)alloc(128 * 4);
  size_t zero_bytes = off - zero_start;
  int* rowptr = (int*)alloc(((size_t)N + 1) * 4);
  int* bsum = (int*)alloc(512 * 4);
  int* colarr = (int*)alloc((size_t)E * 4);
  float4* x0s = (float4*)alloc((size_t)N * 16);
  float4* xa3 = (float4*)alloc((size_t)N * 16);
  float* dinv = (float*)alloc((size_t)N * 4);
  float* sarr = (float*)alloc((size_t)N * 4);
  float* pm = (float*)alloc(256 * 4);
  float* pt = (float*)alloc(256 * 4);
  float* scal = (float*)alloc(16 * 4);
  unsigned short* x1s = (unsigned short*)alloc((size_t)N * HID * 2);
  unsigned short* xab = (unsigned short*)alloc((size_t)N * HID * 2);
  unsigned short* x2b = (unsigned short*)alloc((size_t)N * HID * 2);
  if (off > ws_size) return;

  int nblkE = (E + 255) / 256;
  int nblkN = (N + 255) / 256;

  hipMemsetAsync(base + zero_start, 0, zero_bytes, stream);
  k_count<<<nblkE, 256, 0, stream>>>(src, dst, E, degsrc, indeg);
  k_maxpart<<<256, 256, 0, stream>>>(degsrc, N, (int*)pm);
  k_maxfin<<<1, 256, 0, stream>>>((int*)pm, scal);
  k_node<<<nblkN, 256, 0, stream>>>(coords, degsrc, indeg, scal, N, x0s, dinv);
  k_scan_part<<<nblkN, 256, 0, stream>>>(indeg, N, rowptr, bsum);
  k_scan_mid<<<1, 512, 0, stream>>>(bsum, nblkN);
  k_scan_add<<<nblkN, 256, 0, stream>>>(rowptr, bsum, N, E);
  k_scatter<<<nblkE, 256, 0, stream>>>(src, dst, E, rowptr, cursor, colarr);
  k_agg3<<<nblkN, 256, 0, stream>>>(x0s, dinv, rowptr, colarr, N, xa3);
  k_lin1<<<(N * HID + 255) / 256, 256, 0, stream>>>(xa3, dinv, W1, b1, N, x1s);
  k_agg128<<<(N + 7) / 8, 256, 0, stream>>>(x1s, dinv, rowptr, colarr, N, xab);
  k_gemm2<<<(N + 63) / 64, 256, 0, stream>>>(xab, W2, b2, N, x2b, colsum);
  k_heads<<<(N + 7) / 8, 256, 0, stream>>>(x2b, Wsw, bsw, Wmu, bmu, Wls, bls, N, sarr, outf);
  k_lse_part<<<256, 256, 0, stream>>>(sarr, N, pm, pt);
  k_lse_fin<<<1, 256, 0, stream>>>(pm, pt, scal);
  k_logits<<<nblkN, 256, 0, stream>>>(sarr, scal, N, outf);
  k_value<<<1, 64, 0, stream>>>(colsum, Wv1, bv1, Wv2, bv2, N, outf + (size_t)5 * N);
}

// Round 3
// 322.741 us; speedup vs baseline: 1.7996x; 1.4990x over previous
//
#include <hip/hip_runtime.h>
#include <hip/hip_bf16.h>

#define HID 128
#define NBMAX 512  // max coarse buckets (N up to 131072)

__device__ __forceinline__ float b2f(unsigned int u) { return __uint_as_float(u << 16); }
__device__ __forceinline__ float b2f_hi(unsigned int u) { return __uint_as_float(u & 0xFFFF0000u); }
__device__ __forceinline__ unsigned int f2b(float f) {
  unsigned int b = __float_as_uint(f);
  return (b + 0x7FFFu + ((b >> 16) & 1u)) >> 16;
}
__device__ __forceinline__ unsigned int pack2(float lo, float hi) {
  return f2b(lo) | (f2b(hi) << 16);
}

// ---------------- coarse histograms (LDS-privatized) ----------------
__global__ void k_hist(const int* __restrict__ src, const int* __restrict__ dst, int E, int NB,
                       int* __restrict__ hd_g, int* __restrict__ hs_g) {
  __shared__ int hd[NBMAX], hs[NBMAX];
  for (int i = threadIdx.x; i < NB; i += 256) { hd[i] = 0; hs[i] = 0; }
  __syncthreads();
  int stride = gridDim.x * 256;
  for (int e = blockIdx.x * 256 + threadIdx.x; e < E; e += stride) {
    atomicAdd(&hd[dst[e] >> 8], 1);
    atomicAdd(&hs[src[e] >> 8], 1);
  }
  __syncthreads();
  for (int i = threadIdx.x; i < NB; i += 256) {
    if (hd[i]) atomicAdd(&hd_g[i], hd[i]);
    if (hs[i]) atomicAdd(&hs_g[i], hs[i]);
  }
}

// ---------------- bucket scan (1 block, 512 threads) ----------------
__global__ void k_scan_buckets(const int* __restrict__ hd_g, const int* __restrict__ hs_g,
                               int NB, int E, int* __restrict__ based, int* __restrict__ bases,
                               int* __restrict__ curd, int* __restrict__ curs) {
  __shared__ int sd[NBMAX], ss[NBMAX];
  int i = threadIdx.x;
  int vd = (i < NB) ? hd_g[i] : 0;
  int vs = (i < NB) ? hs_g[i] : 0;
  sd[i] = vd; ss[i] = vs; __syncthreads();
  for (int st = 1; st < NBMAX; st <<= 1) {
    int td = (i >= st) ? sd[i - st] : 0;
    int ts = (i >= st) ? ss[i - st] : 0;
    __syncthreads();
    sd[i] += td; ss[i] += ts;
    __syncthreads();
  }
  if (i < NB) {
    int bd = sd[i] - vd, bs = ss[i] - vs;
    based[i] = bd; bases[i] = bs;
    curd[i] = bd; curs[i] = bs;
  }
  if (i == 0) { based[NB] = E; bases[NB] = E; }
}

// ---------------- bucketed scatter of (dst,src) pairs and src values ----------------
__global__ void k_bucket_scatter(const int* __restrict__ src, const int* __restrict__ dst,
                                 int E, int NB, int* __restrict__ curd, int* __restrict__ curs,
                                 int2* __restrict__ pairs, int* __restrict__ srcb) {
  __shared__ int hd[NBMAX], hs[NBMAX], bd[NBMAX], bs[NBMAX];
  for (int i = threadIdx.x; i < NB; i += 256) { hd[i] = 0; hs[i] = 0; }
  __syncthreads();
  int per = (E + gridDim.x - 1) / gridDim.x;
  int begin = blockIdx.x * per;
  int end = min(E, begin + per);
  for (int e = begin + threadIdx.x; e < end; e += 256) {
    atomicAdd(&hd[dst[e] >> 8], 1);
    atomicAdd(&hs[src[e] >> 8], 1);
  }
  __syncthreads();
  for (int i = threadIdx.x; i < NB; i += 256) {
    bd[i] = hd[i] ? atomicAdd(&curd[i], hd[i]) : 0;
    bs[i] = hs[i] ? atomicAdd(&curs[i], hs[i]) : 0;
    hd[i] = 0; hs[i] = 0;
  }
  __syncthreads();
  for (int e = begin + threadIdx.x; e < end; e += 256) {
    int d = dst[e], s = src[e];
    int p = bd[d >> 8] + atomicAdd(&hd[d >> 8], 1);
    pairs[p] = make_int2(d, s);
    int q = bs[s >> 8] + atomicAdd(&hs[s >> 8], 1);
    srcb[q] = s;
  }
}

// ---------------- per-bucket out-degree (+ per-bucket max) ----------------
__global__ void k_degsrc(const int* __restrict__ srcb, const int* __restrict__ bases, int N,
                         int* __restrict__ degsrc, int* __restrict__ bmax) {
  __shared__ int cnt[256];
  __shared__ int mx[256];
  int b = blockIdx.x;
  cnt[threadIdx.x] = 0; __syncthreads();
  int lo = bases[b], hi = bases[b + 1];
  for (int k = lo + threadIdx.x; k < hi; k += 256) atomicAdd(&cnt[srcb[k] & 255], 1);
  __syncthreads();
  int g = (b << 8) + threadIdx.x;
  int c = cnt[threadIdx.x];
  if (g < N) degsrc[g] = c;
  mx[threadIdx.x] = (g < N) ? c : 0; __syncthreads();
  for (int s = 128; s > 0; s >>= 1) {
    if (threadIdx.x < s) mx[threadIdx.x] = max(mx[threadIdx.x], mx[threadIdx.x + s]);
    __syncthreads();
  }
  if (threadIdx.x == 0) bmax[b] = mx[0];
}

__global__ void k_maxfin(const int* __restrict__ bmax, int NB, float* __restrict__ scal) {
  __shared__ int sm[NBMAX];
  int i = threadIdx.x;
  sm[i] = (i < NB) ? bmax[i] : 0; __syncthreads();
  for (int s = NBMAX / 2; s > 0; s >>= 1) {
    if (i < s) sm[i] = max(sm[i], sm[i + s]);
    __syncthreads();
  }
  if (i == 0) scal[0] = 1.0f / (float)max(sm[0], 1);
}

// ---------------- per-bucket CSR build + dinv ----------------
__global__ void k_csr(const int2* __restrict__ pairs, const int* __restrict__ based, int N, int E,
                      int* __restrict__ rowptr, float* __restrict__ dinv,
                      int* __restrict__ colarr) {
  __shared__ int cnt[256], scn[256], cur[256];
  int b = blockIdx.x;
  cnt[threadIdx.x] = 0; __syncthreads();
  int lo = based[b], hi = based[b + 1];
  for (int k = lo + threadIdx.x; k < hi; k += 256) atomicAdd(&cnt[pairs[k].x & 255], 1);
  __syncthreads();
  int c = cnt[threadIdx.x];
  scn[threadIdx.x] = c; __syncthreads();
  for (int st = 1; st < 256; st <<= 1) {
    int t = (threadIdx.x >= st) ? scn[threadIdx.x - st] : 0;
    __syncthreads();
    scn[threadIdx.x] += t;
    __syncthreads();
  }
  int excl = scn[threadIdx.x] - c;
  int g = (b << 8) + threadIdx.x;
  if (g < N) {
    rowptr[g] = lo + excl;
    dinv[g] = rsqrtf((float)(c + 1));
  }
  cur[threadIdx.x] = lo + excl;
  __syncthreads();
  for (int k = lo + threadIdx.x; k < hi; k += 256) {
    int2 p = pairs[k];
    int pos = atomicAdd(&cur[p.x & 255], 1);
    colarr[pos] = p.y;
  }
  if (b == 0 && threadIdx.x == 0) rowptr[N] = E;
}

// node features prescaled by own dinv: x0s[n] = [cx,cy,degn,0] * dinv[n]
__global__ void k_node(const float* __restrict__ coords, const int* __restrict__ degsrc,
                       const float* __restrict__ dinv, const float* __restrict__ scal,
                       int N, float4* __restrict__ x0s) {
  int n = blockIdx.x * 256 + threadIdx.x;
  if (n >= N) return;
  float inv = scal[0];
  float di = dinv[n];
  float4 v;
  v.x = coords[n * 2 + 0] * di;
  v.y = coords[n * 2 + 1] * di;
  v.z = (float)degsrc[n] * inv * di;
  v.w = 0.f;
  x0s[n] = v;
}

// ---------------- GCN layer 1 ----------------
__global__ void k_agg3(const float4* __restrict__ x0s, const float* __restrict__ dinv,
                       const int* __restrict__ rowptr, const int* __restrict__ col,
                       int N, float4* __restrict__ xa3) {
  int n = blockIdx.x * 256 + threadIdx.x;
  if (n >= N) return;
  float4 a = x0s[n];
  int b = rowptr[n], en = rowptr[n + 1];
  int k = b;
  for (; k + 1 < en; k += 2) {
    int s0 = col[k], s1 = col[k + 1];
    float4 w0 = x0s[s0];
    float4 w1 = x0s[s1];
    a.x += w0.x + w1.x; a.y += w0.y + w1.y; a.z += w0.z + w1.z;
  }
  if (k < en) {
    float4 w = x0s[col[k]];
    a.x += w.x; a.y += w.y; a.z += w.z;
  }
  float di = dinv[n];
  a.x *= di; a.y *= di; a.z *= di; a.w = 0.f;
  xa3[n] = a;
}

// linear: x1s = relu(xa3 @ W1 + b1) * dinv[n], stored bf16
__global__ void k_lin1(const float4* __restrict__ xa3, const float* __restrict__ dinv,
                       const float* __restrict__ W1, const float* __restrict__ b1, int N,
                       unsigned short* __restrict__ x1s) {
  int idx = blockIdx.x * 256 + threadIdx.x;
  if (idx >= N * HID) return;
  int n = idx >> 7, f = idx & 127;
  float4 a = xa3[n];
  float v = b1[f] + a.x * W1[f] + a.y * W1[128 + f] + a.z * W1[256 + f];
  v = fmaxf(v, 0.f) * dinv[n];
  x1s[idx] = (unsigned short)f2b(v);
}

// ---------------- GCN layer 2 aggregation ----------------
__global__ void k_agg128(const unsigned short* __restrict__ x1s, const float* __restrict__ dinv,
                         const int* __restrict__ rowptr, const int* __restrict__ col,
                         int N, unsigned short* __restrict__ xa) {
  int g = (int)((blockIdx.x * 256 + threadIdx.x) >> 5);
  int lane = threadIdx.x & 31;
  if (g >= N) return;
  const uint2* base = (const uint2*)x1s + lane;
  uint2 self = base[(size_t)g * 32];
  float a0 = b2f(self.x), a1 = b2f_hi(self.x), a2 = b2f(self.y), a3 = b2f_hi(self.y);
  int b = rowptr[g], en = rowptr[g + 1];
  int k = b;
  for (; k + 1 < en; k += 2) {
    int s0 = col[k], s1 = col[k + 1];
    uint2 w0 = base[(size_t)s0 * 32];
    uint2 w1 = base[(size_t)s1 * 32];
    a0 += b2f(w0.x) + b2f(w1.x);
    a1 += b2f_hi(w0.x) + b2f_hi(w1.x);
    a2 += b2f(w0.y) + b2f(w1.y);
    a3 += b2f_hi(w0.y) + b2f_hi(w1.y);
  }
  if (k < en) {
    uint2 w = base[(size_t)col[k] * 32];
    a0 += b2f(w.x); a1 += b2f_hi(w.x); a2 += b2f(w.y); a3 += b2f_hi(w.y);
  }
  float di = dinv[g];
  uint2 o;
  o.x = pack2(a0 * di, a1 * di);
  o.y = pack2(a2 * di, a3 * di);
  ((uint2*)xa)[(size_t)g * 32 + lane] = o;
}

// ---------------- layer 2 GEMM (bf16 in/out, f32 compute) + fused colsum ----------------
__global__ __launch_bounds__(256) void k_gemm2(const unsigned short* __restrict__ xa,
                                               const float* __restrict__ W2,
                                               const float* __restrict__ b2, int N,
                                               unsigned short* __restrict__ x2,
                                               float* __restrict__ colsum) {
  __shared__ float xs[64 * 132];
  __shared__ float cs[16][128];
  int n0 = blockIdx.x * 64;
  for (int t = threadIdx.x; t < 64 * 16; t += 256) {
    int n = t >> 4, c = t & 15;
    int gn = n0 + n;
    uint4 v = make_uint4(0, 0, 0, 0);
    if (gn < N) v = ((const uint4*)(xa + (size_t)gn * HID))[c];
    float* d = xs + n * 132 + c * 8;
    d[0] = b2f(v.x); d[1] = b2f_hi(v.x);
    d[2] = b2f(v.y); d[3] = b2f_hi(v.y);
    d[4] = b2f(v.z); d[5] = b2f_hi(v.z);
    d[6] = b2f(v.w); d[7] = b2f_hi(v.w);
  }
  __syncthreads();
  int col = threadIdx.x & 15;
  int row = threadIdx.x >> 4;
  int j0 = col * 8;
  float acc[4][8];
#pragma unroll
  for (int i = 0; i < 4; i++)
#pragma unroll
    for (int j = 0; j < 8; j++) acc[i][j] = 0.f;
  for (int k = 0; k < 128; k++) {
    float4 wA = *(const float4*)(W2 + k * 128 + j0);
    float4 wB = *(const float4*)(W2 + k * 128 + j0 + 4);
    float xv[4];
#pragma unroll
    for (int i = 0; i < 4; i++) xv[i] = xs[(row * 4 + i) * 132 + k];
#pragma unroll
    for (int i = 0; i < 4; i++) {
      acc[i][0] += xv[i] * wA.x; acc[i][1] += xv[i] * wA.y;
      acc[i][2] += xv[i] * wA.z; acc[i][3] += xv[i] * wA.w;
      acc[i][4] += xv[i] * wB.x; acc[i][5] += xv[i] * wB.y;
      acc[i][6] += xv[i] * wB.z; acc[i][7] += xv[i] * wB.w;
    }
  }
  float bj[8];
#pragma unroll
  for (int j = 0; j < 8; j++) bj[j] = b2[j0 + j];
  float csum[8];
#pragma unroll
  for (int j = 0; j < 8; j++) csum[j] = 0.f;
#pragma unroll
  for (int i = 0; i < 4; i++) {
    int gn = n0 + row * 4 + i;
    if (gn < N) {
      float o[8];
#pragma unroll
      for (int j = 0; j < 8; j++) {
        o[j] = fmaxf(acc[i][j] + bj[j], 0.f);
        csum[j] += o[j];
      }
      uint4 pk;
      pk.x = pack2(o[0], o[1]);
      pk.y = pack2(o[2], o[3]);
      pk.z = pack2(o[4], o[5]);
      pk.w = pack2(o[6], o[7]);
      *(uint4*)(x2 + (size_t)gn * HID + j0) = pk;
    }
  }
#pragma unroll
  for (int j = 0; j < 8; j++) cs[row][j0 + j] = csum[j];
  __syncthreads();
  if (threadIdx.x < 128) {
    int f = threadIdx.x;
    float t = 0.f;
#pragma unroll
    for (int r = 0; r < 16; r++) t += cs[r][f];
    atomicAdd(&colsum[f], t);
  }
}

// ---------------- heads (x2 bf16) ----------------
__global__ void k_heads(const unsigned short* __restrict__ x2, const float* __restrict__ Ws,
                        const float* __restrict__ bs, const float* __restrict__ Wmu,
                        const float* __restrict__ bmu, const float* __restrict__ Wls,
                        const float* __restrict__ bls, int N, float* __restrict__ s_arr,
                        float* __restrict__ out) {
  __shared__ float w[640];
  for (int t = threadIdx.x; t < 128; t += 256) {
    w[t] = Ws[t];
    w[128 + t] = Wmu[t * 2 + 0];
    w[256 + t] = Wmu[t * 2 + 1];
    w[384 + t] = Wls[t * 2 + 0];
    w[512 + t] = Wls[t * 2 + 1];
  }
  __syncthreads();
  int g = (int)((blockIdx.x * 256 + threadIdx.x) >> 5);
  int lane = threadIdx.x & 31;
  if (g >= N) return;
  uint2 v = ((const uint2*)x2)[(size_t)g * 32 + lane];
  float xv[4] = {b2f(v.x), b2f_hi(v.x), b2f(v.y), b2f_hi(v.y)};
  int f0 = lane * 4;
  float p0 = 0, p1 = 0, p2 = 0, p3 = 0, p4 = 0;
#pragma unroll
  for (int i = 0; i < 4; i++) {
    p0 += xv[i] * w[f0 + i];
    p1 += xv[i] * w[128 + f0 + i];
    p2 += xv[i] * w[256 + f0 + i];
    p3 += xv[i] * w[384 + f0 + i];
    p4 += xv[i] * w[512 + f0 + i];
  }
#pragma unroll
  for (int m = 1; m < 32; m <<= 1) {
    p0 += __shfl_xor(p0, m);
    p1 += __shfl_xor(p1, m);
    p2 += __shfl_xor(p2, m);
    p3 += __shfl_xor(p3, m);
    p4 += __shfl_xor(p4, m);
  }
  if (lane == 0) {
    s_arr[g] = p0 + bs[0];
    out[(size_t)N + g * 2 + 0] = p1 + bmu[0];
    out[(size_t)N + g * 2 + 1] = p2 + bmu[1];
    out[(size_t)3 * N + g * 2 + 0] = fminf(fmaxf(p3 + bls[0], -4.f), 2.f);
    out[(size_t)3 * N + g * 2 + 1] = fminf(fmaxf(p4 + bls[1], -4.f), 2.f);
  }
}

// ---------------- online logsumexp ----------------
__global__ void k_lse_part(const float* __restrict__ s, int N, float* __restrict__ pm,
                           float* __restrict__ pt) {
  __shared__ float smM[256], smT[256];
  float m = -1e30f, t = 0.f;
  for (int i = blockIdx.x * 256 + threadIdx.x; i < N; i += 256 * 256) {
    float v = s[i];
    if (v > m) { t = t * __expf(m - v) + 1.f; m = v; }
    else t += __expf(v - m);
  }
  smM[threadIdx.x] = m; smT[threadIdx.x] = t; __syncthreads();
  for (int st = 128; st > 0; st >>= 1) {
    if (threadIdx.x < st) {
      float m2 = smM[threadIdx.x + st], t2 = smT[threadIdx.x + st];
      float m1 = smM[threadIdx.x], t1 = smT[threadIdx.x];
      float M = fmaxf(m1, m2);
      smM[threadIdx.x] = M;
      smT[threadIdx.x] = t1 * __expf(m1 - M) + t2 * __expf(m2 - M);
    }
    __syncthreads();
  }
  if (threadIdx.x == 0) { pm[blockIdx.x] = smM[0]; pt[blockIdx.x] = smT[0]; }
}

__global__ void k_lse_fin(const float* __restrict__ pm, const float* __restrict__ pt,
                          float* __restrict__ scal) {
  __shared__ float smM[256], smT[256];
  smM[threadIdx.x] = pm[threadIdx.x];
  smT[threadIdx.x] = pt[threadIdx.x];
  __syncthreads();
  for (int st = 128; st > 0; st >>= 1) {
    if (threadIdx.x < st) {
      float m2 = smM[threadIdx.x + st], t2 = smT[threadIdx.x + st];
      float m1 = smM[threadIdx.x], t1 = smT[threadIdx.x];
      float M = fmaxf(m1, m2);
      smM[threadIdx.x] = M;
      smT[threadIdx.x] = t1 * __expf(m1 - M) + t2 * __expf(m2 - M);
    }
    __syncthreads();
  }
  if (threadIdx.x == 0) scal[2] = smM[0] + logf(smT[0]);
}

__global__ void k_logits(const float* __restrict__ s, const float* __restrict__ scal, int N,
                         float* __restrict__ out) {
  int n = blockIdx.x * 256 + threadIdx.x;
  if (n < N) out[n] = s[n] - scal[2];
}

// ---------------- value head ----------------
__global__ void k_value(const float* __restrict__ colsum, const float* __restrict__ Wv1,
                        const float* __restrict__ bv1, const float* __restrict__ Wv2,
                        const float* __restrict__ bv2, int N, float* __restrict__ out5N) {
  __shared__ float hid[64];
  float invN = 1.0f / (float)N;
  int j = threadIdx.x;
  if (j < 64) {
    float a = bv1[j];
    for (int f = 0; f < 128; f++) a += (colsum[f] * invN) * Wv1[f * 64 + j];
    hid[j] = fmaxf(a, 0.f) * Wv2[j];
  }
  __syncthreads();
  if (threadIdx.x == 0) {
    float v = bv2[0];
    for (int jj = 0; jj < 64; jj++) v += hid[jj];
    out5N[0] = v;
  }
}

extern "C" void kernel_launch(void* const* d_in, const int* in_sizes, int n_in,
                              void* d_out, int out_size, void* d_ws, size_t ws_size,
                              hipStream_t stream) {
  const float* coords = (const float*)d_in[0];
  const int* ei = (const int*)d_in[1];
  const float* W1 = (const float*)d_in[2];
  const float* b1 = (const float*)d_in[3];
  const float* W2 = (const float*)d_in[4];
  const float* b2 = (const float*)d_in[5];
  const float* Wsw = (const float*)d_in[6];
  const float* bsw = (const float*)d_in[7];
  const float* Wmu = (const float*)d_in[8];
  const float* bmu = (const float*)d_in[9];
  const float* Wls = (const float*)d_in[10];
  const float* bls = (const float*)d_in[11];
  const float* Wv1 = (const float*)d_in[12];
  const float* bv1 = (const float*)d_in[13];
  const float* Wv2 = (const float*)d_in[14];
  const float* bv2 = (const float*)d_in[15];
  int N = in_sizes[0] / 2;
  int E = in_sizes[1] / 2;
  const int* src = ei;
  const int* dst = ei + E;
  float* outf = (float*)d_out;
  int NB = (N + 255) >> 8;

  char* base = (char*)d_ws;
  size_t off = 0;
  auto alloc = [&](size_t bytes) -> void* {
    void* r = base + off;
    off += (bytes + 255) & ~(size_t)255;
    return r;
  };
  size_t zero_start = off;
  int* hd_g = (int*)alloc((size_t)NB * 4);
  int* hs_g = (int*)alloc((size_t)NB * 4);
  float* colsum = (float*)alloc(128 * 4);
  size_t zero_bytes = off - zero_start;
  int* based = (int*)alloc(((size_t)NB + 1) * 4);
  int* bases = (int*)alloc(((size_t)NB + 1) * 4);
  int* curd = (int*)alloc((size_t)NB * 4);
  int* curs = (int*)alloc((size_t)NB * 4);
  int* bmax = (int*)alloc((size_t)NB * 4);
  int* rowptr = (int*)alloc(((size_t)N + 1) * 4);
  int2* pairs = (int2*)alloc((size_t)E * 8);
  int* srcb = (int*)alloc((size_t)E * 4);
  int* colarr = (int*)alloc((size_t)E * 4);
  int* degsrc = (int*)alloc((size_t)N * 4);
  float* dinv = (float*)alloc((size_t)N * 4);
  float4* x0s = (float4*)alloc((size_t)N * 16);
  float4* xa3 = (float4*)alloc((size_t)N * 16);
  float* sarr = (float*)alloc((size_t)N * 4);
  float* pm = (float*)alloc(256 * 4);
  float* pt = (float*)alloc(256 * 4);
  float* scal = (float*)alloc(16 * 4);
  unsigned short* x1s = (unsigned short*)alloc((size_t)N * HID * 2);
  unsigned short* xab = (unsigned short*)alloc((size_t)N * HID * 2);
  unsigned short* x2b = (unsigned short*)alloc((size_t)N * HID * 2);
  if (off > ws_size) return;

  int nblkN = (N + 255) / 256;

  hipMemsetAsync(base + zero_start, 0, zero_bytes, stream);
  k_hist<<<256, 256, 0, stream>>>(src, dst, E, NB, hd_g, hs_g);
  k_scan_buckets<<<1, NBMAX, 0, stream>>>(hd_g, hs_g, NB, E, based, bases, curd, curs);
  k_bucket_scatter<<<256, 256, 0, stream>>>(src, dst, E, NB, curd, curs, pairs, srcb);
  k_degsrc<<<NB, 256, 0, stream>>>(srcb, bases, N, degsrc, bmax);
  k_maxfin<<<1, NBMAX, 0, stream>>>(bmax, NB, scal);
  k_csr<<<NB, 256, 0, stream>>>(pairs, based, N, E, rowptr, dinv, colarr);
  k_node<<<nblkN, 256, 0, stream>>>(coords, degsrc, dinv, scal, N, x0s);
  k_agg3<<<nblkN, 256, 0, stream>>>(x0s, dinv, rowptr, colarr, N, xa3);
  k_lin1<<<(N * HID + 255) / 256, 256, 0, stream>>>(xa3, dinv, W1, b1, N, x1s);
  k_agg128<<<(N + 7) / 8, 256, 0, stream>>>(x1s, dinv, rowptr, colarr, N, xab);
  k_gemm2<<<(N + 63) / 64, 256, 0, stream>>>(xab, W2, b2, N, x2b, colsum);
  k_heads<<<(N + 7) / 8, 256, 0, stream>>>(x2b, Wsw, bsw, Wmu, bmu, Wls, bls, N, sarr, outf);
  k_lse_part<<<256, 256, 0, stream>>>(sarr, N, pm, pt);
  k_lse_fin<<<1, 256, 0, stream>>>(pm, pt, scal);
  k_logits<<<nblkN, 256, 0, stream>>>(sarr, scal, N, outf);
  k_value<<<1, 64, 0, stream>>>(colsum, Wv1, bv1, Wv2, bv2, N, outf + (size_t)5 * N);
}

// Round 4
// 266.825 us; speedup vs baseline: 2.1767x; 1.2096x over previous
//
#include <hip/hip_runtime.h>
#include <hip/hip_bf16.h>

#define HID 128
#define NBMAX 512  // max coarse buckets (N up to 131072)

typedef __bf16 bf16x8 __attribute__((ext_vector_type(8)));
typedef float f32x4 __attribute__((ext_vector_type(4)));

__device__ __forceinline__ float b2f(unsigned int u) { return __uint_as_float(u << 16); }
__device__ __forceinline__ float b2f_hi(unsigned int u) { return __uint_as_float(u & 0xFFFF0000u); }
__device__ __forceinline__ unsigned int f2b(float f) {
  unsigned int b = __float_as_uint(f);
  return (b + 0x7FFFu + ((b >> 16) & 1u)) >> 16;
}
__device__ __forceinline__ unsigned int pack2(float lo, float hi) {
  return f2b(lo) | (f2b(hi) << 16);
}

// ---------------- coarse histograms (LDS-privatized) ----------------
__global__ void k_hist(const int* __restrict__ src, const int* __restrict__ dst, int E, int NB,
                       int* __restrict__ hd_g, int* __restrict__ hs_g) {
  __shared__ int hd[NBMAX], hs[NBMAX];
  for (int i = threadIdx.x; i < NB; i += 256) { hd[i] = 0; hs[i] = 0; }
  __syncthreads();
  int stride = gridDim.x * 256;
  for (int e = blockIdx.x * 256 + threadIdx.x; e < E; e += stride) {
    atomicAdd(&hd[dst[e] >> 8], 1);
    atomicAdd(&hs[src[e] >> 8], 1);
  }
  __syncthreads();
  for (int i = threadIdx.x; i < NB; i += 256) {
    if (hd[i]) atomicAdd(&hd_g[i], hd[i]);
    if (hs[i]) atomicAdd(&hs_g[i], hs[i]);
  }
}

// ---------------- bucket scan ----------------
__global__ void k_scan_buckets(const int* __restrict__ hd_g, const int* __restrict__ hs_g,
                               int NB, int E, int* __restrict__ based, int* __restrict__ bases,
                               int* __restrict__ curd, int* __restrict__ curs) {
  __shared__ int sd[NBMAX], ss[NBMAX];
  int i = threadIdx.x;
  int vd = (i < NB) ? hd_g[i] : 0;
  int vs = (i < NB) ? hs_g[i] : 0;
  sd[i] = vd; ss[i] = vs; __syncthreads();
  for (int st = 1; st < NBMAX; st <<= 1) {
    int td = (i >= st) ? sd[i - st] : 0;
    int ts = (i >= st) ? ss[i - st] : 0;
    __syncthreads();
    sd[i] += td; ss[i] += ts;
    __syncthreads();
  }
  if (i < NB) {
    int bd = sd[i] - vd, bs = ss[i] - vs;
    based[i] = bd; bases[i] = bs;
    curd[i] = bd; curs[i] = bs;
  }
  if (i == 0) { based[NB] = E; bases[NB] = E; }
}

// ---------------- bucketed scatter ----------------
__global__ void k_bucket_scatter(const int* __restrict__ src, const int* __restrict__ dst,
                                 int E, int NB, int* __restrict__ curd, int* __restrict__ curs,
                                 int2* __restrict__ pairs, int* __restrict__ srcb) {
  __shared__ int hd[NBMAX], hs[NBMAX], bd[NBMAX], bs[NBMAX];
  for (int i = threadIdx.x; i < NB; i += 256) { hd[i] = 0; hs[i] = 0; }
  __syncthreads();
  int per = (E + gridDim.x - 1) / gridDim.x;
  int begin = blockIdx.x * per;
  int end = min(E, begin + per);
  for (int e = begin + threadIdx.x; e < end; e += 256) {
    atomicAdd(&hd[dst[e] >> 8], 1);
    atomicAdd(&hs[src[e] >> 8], 1);
  }
  __syncthreads();
  for (int i = threadIdx.x; i < NB; i += 256) {
    bd[i] = hd[i] ? atomicAdd(&curd[i], hd[i]) : 0;
    bs[i] = hs[i] ? atomicAdd(&curs[i], hs[i]) : 0;
    hd[i] = 0; hs[i] = 0;
  }
  __syncthreads();
  for (int e = begin + threadIdx.x; e < end; e += 256) {
    int d = dst[e], s = src[e];
    int p = bd[d >> 8] + atomicAdd(&hd[d >> 8], 1);
    pairs[p] = make_int2(d, s);
    int q = bs[s >> 8] + atomicAdd(&hs[s >> 8], 1);
    srcb[q] = s;
  }
}

// ---------------- per-bucket out-degree (+ per-bucket max) ----------------
__global__ void k_degsrc(const int* __restrict__ srcb, const int* __restrict__ bases, int N,
                         int* __restrict__ degsrc, int* __restrict__ bmax) {
  __shared__ int cnt[256];
  __shared__ int mx[256];
  int b = blockIdx.x;
  cnt[threadIdx.x] = 0; __syncthreads();
  int lo = bases[b], hi = bases[b + 1];
  for (int k = lo + threadIdx.x; k < hi; k += 256) atomicAdd(&cnt[srcb[k] & 255], 1);
  __syncthreads();
  int g = (b << 8) + threadIdx.x;
  int c = cnt[threadIdx.x];
  if (g < N) degsrc[g] = c;
  mx[threadIdx.x] = (g < N) ? c : 0; __syncthreads();
  for (int s = 128; s > 0; s >>= 1) {
    if (threadIdx.x < s) mx[threadIdx.x] = max(mx[threadIdx.x], mx[threadIdx.x + s]);
    __syncthreads();
  }
  if (threadIdx.x == 0) bmax[b] = mx[0];
}

__global__ void k_maxfin(const int* __restrict__ bmax, int NB, float* __restrict__ scal) {
  __shared__ int sm[NBMAX];
  int i = threadIdx.x;
  sm[i] = (i < NB) ? bmax[i] : 0; __syncthreads();
  for (int s = NBMAX / 2; s > 0; s >>= 1) {
    if (i < s) sm[i] = max(sm[i], sm[i + s]);
    __syncthreads();
  }
  if (i == 0) scal[0] = 1.0f / (float)max(sm[0], 1);
}

// ---------------- per-bucket CSR build + dinv ----------------
__global__ void k_csr(const int2* __restrict__ pairs, const int* __restrict__ based, int N, int E,
                      int* __restrict__ rowptr, float* __restrict__ dinv,
                      int* __restrict__ colarr) {
  __shared__ int cnt[256], scn[256], cur[256];
  int b = blockIdx.x;
  cnt[threadIdx.x] = 0; __syncthreads();
  int lo = based[b], hi = based[b + 1];
  for (int k = lo + threadIdx.x; k < hi; k += 256) atomicAdd(&cnt[pairs[k].x & 255], 1);
  __syncthreads();
  int c = cnt[threadIdx.x];
  scn[threadIdx.x] = c; __syncthreads();
  for (int st = 1; st < 256; st <<= 1) {
    int t = (threadIdx.x >= st) ? scn[threadIdx.x - st] : 0;
    __syncthreads();
    scn[threadIdx.x] += t;
    __syncthreads();
  }
  int excl = scn[threadIdx.x] - c;
  int g = (b << 8) + threadIdx.x;
  if (g < N) {
    rowptr[g] = lo + excl;
    dinv[g] = rsqrtf((float)(c + 1));
  }
  cur[threadIdx.x] = lo + excl;
  __syncthreads();
  for (int k = lo + threadIdx.x; k < hi; k += 256) {
    int2 p = pairs[k];
    int pos = atomicAdd(&cur[p.x & 255], 1);
    colarr[pos] = p.y;
  }
  if (b == 0 && threadIdx.x == 0) rowptr[N] = E;
}

// ---------------- W2 -> bf16 transposed [j][k] ----------------
__global__ void k_prepW(const float* __restrict__ W2, unsigned short* __restrict__ W2T) {
  int idx = blockIdx.x * 256 + threadIdx.x;
  if (idx >= 128 * 128) return;
  int j = idx >> 7, k = idx & 127;
  W2T[j * 128 + k] = (unsigned short)f2b(W2[k * 128 + j]);
}

// node features prescaled by own dinv
__global__ void k_node(const float* __restrict__ coords, const int* __restrict__ degsrc,
                       const float* __restrict__ dinv, const float* __restrict__ scal,
                       int N, float4* __restrict__ x0s) {
  int n = blockIdx.x * 256 + threadIdx.x;
  if (n >= N) return;
  float inv = scal[0];
  float di = dinv[n];
  float4 v;
  v.x = coords[n * 2 + 0] * di;
  v.y = coords[n * 2 + 1] * di;
  v.z = (float)degsrc[n] * inv * di;
  v.w = 0.f;
  x0s[n] = v;
}

// ---------------- GCN layer 1 aggregation ----------------
__global__ void k_agg3(const float4* __restrict__ x0s, const float* __restrict__ dinv,
                       const int* __restrict__ rowptr, const int* __restrict__ col,
                       int N, float4* __restrict__ xa3) {
  int n = blockIdx.x * 256 + threadIdx.x;
  if (n >= N) return;
  float4 a = x0s[n];
  int b = rowptr[n], en = rowptr[n + 1];
  int k = b;
  for (; k + 3 < en; k += 4) {
    int s0 = col[k], s1 = col[k + 1], s2 = col[k + 2], s3 = col[k + 3];
    float4 w0 = x0s[s0];
    float4 w1 = x0s[s1];
    float4 w2 = x0s[s2];
    float4 w3 = x0s[s3];
    a.x += (w0.x + w1.x) + (w2.x + w3.x);
    a.y += (w0.y + w1.y) + (w2.y + w3.y);
    a.z += (w0.z + w1.z) + (w2.z + w3.z);
  }
  for (; k < en; k++) {
    float4 w = x0s[col[k]];
    a.x += w.x; a.y += w.y; a.z += w.z;
  }
  float di = dinv[n];
  a.x *= di; a.y *= di; a.z *= di; a.w = 0.f;
  xa3[n] = a;
}

// linear: x1s = relu(xa3 @ W1 + b1) * dinv[n], stored bf16
__global__ void k_lin1(const float4* __restrict__ xa3, const float* __restrict__ dinv,
                       const float* __restrict__ W1, const float* __restrict__ b1, int N,
                       unsigned short* __restrict__ x1s) {
  int idx = blockIdx.x * 256 + threadIdx.x;
  if (idx >= N * HID) return;
  int n = idx >> 7, f = idx & 127;
  float4 a = xa3[n];
  float v = b1[f] + a.x * W1[f] + a.y * W1[128 + f] + a.z * W1[256 + f];
  v = fmaxf(v, 0.f) * dinv[n];
  x1s[idx] = (unsigned short)f2b(v);
}

// ---------------- GCN layer 2 aggregation (4-wide MLP) ----------------
__global__ void k_agg128(const unsigned short* __restrict__ x1s, const float* __restrict__ dinv,
                         const int* __restrict__ rowptr, const int* __restrict__ col,
                         int N, unsigned short* __restrict__ xa) {
  int g = (int)((blockIdx.x * 256 + threadIdx.x) >> 5);
  int lane = threadIdx.x & 31;
  if (g >= N) return;
  const uint2* base = (const uint2*)x1s + lane;
  uint2 self = base[(size_t)g * 32];
  float a0 = b2f(self.x), a1 = b2f_hi(self.x), a2 = b2f(self.y), a3 = b2f_hi(self.y);
  int b = rowptr[g], en = rowptr[g + 1];
  int k = b;
  for (; k + 3 < en; k += 4) {
    int s0 = col[k], s1 = col[k + 1], s2 = col[k + 2], s3 = col[k + 3];
    uint2 w0 = base[(size_t)s0 * 32];
    uint2 w1 = base[(size_t)s1 * 32];
    uint2 w2 = base[(size_t)s2 * 32];
    uint2 w3 = base[(size_t)s3 * 32];
    a0 += (b2f(w0.x) + b2f(w1.x)) + (b2f(w2.x) + b2f(w3.x));
    a1 += (b2f_hi(w0.x) + b2f_hi(w1.x)) + (b2f_hi(w2.x) + b2f_hi(w3.x));
    a2 += (b2f(w0.y) + b2f(w1.y)) + (b2f(w2.y) + b2f(w3.y));
    a3 += (b2f_hi(w0.y) + b2f_hi(w1.y)) + (b2f_hi(w2.y) + b2f_hi(w3.y));
  }
  for (; k < en; k++) {
    uint2 w = base[(size_t)col[k] * 32];
    a0 += b2f(w.x); a1 += b2f_hi(w.x); a2 += b2f(w.y); a3 += b2f_hi(w.y);
  }
  float di = dinv[g];
  uint2 o;
  o.x = pack2(a0 * di, a1 * di);
  o.y = pack2(a2 * di, a3 * di);
  ((uint2*)xa)[(size_t)g * 32 + lane] = o;
}

// ---------------- layer 2 GEMM via MFMA (bf16 in/out, f32 acc) ----------------
// block = 256 thr = 4 waves; wave w: rows [blk*64 + w*16, +16), all 128 cols.
// A-frag: row = lane&15, k = (lane>>4)*8 + kk*32 (contiguous bf16x8 from xab).
// B-frag: col = lane&15 from W2T[col][k] (contiguous bf16x8).
// D: col = lane&15, row = (lane>>4)*4 + reg  (m89-verified mapping).
__global__ __launch_bounds__(256) void k_gemm2(const unsigned short* __restrict__ xab,
                                               const unsigned short* __restrict__ W2T,
                                               const float* __restrict__ b2, int N,
                                               unsigned short* __restrict__ x2,
                                               float* __restrict__ partials) {
  __shared__ float cs[4][128];
  int w = threadIdx.x >> 6;
  int lane = threadIdx.x & 63;
  int l15 = lane & 15, lhi = lane >> 4;
  int rowbase = blockIdx.x * 64 + w * 16;
  int arow = rowbase + l15;
  int arowc = min(arow, N - 1);
  const unsigned short* ap = xab + (size_t)arowc * HID + lhi * 8;
  bf16x8 a[4];
#pragma unroll
  for (int kk = 0; kk < 4; kk++) a[kk] = *(const bf16x8*)(ap + kk * 32);
  float cpart[8];
#pragma unroll
  for (int ct = 0; ct < 8; ct++) {
    f32x4 acc = {0.f, 0.f, 0.f, 0.f};
    const unsigned short* bp = W2T + (size_t)(ct * 16 + l15) * HID + lhi * 8;
#pragma unroll
    for (int kk = 0; kk < 4; kk++) {
      bf16x8 bfr = *(const bf16x8*)(bp + kk * 32);
      acc = __builtin_amdgcn_mfma_f32_16x16x32_bf16(a[kk], bfr, acc, 0, 0, 0);
    }
    float bias = b2[ct * 16 + l15];
    float cl = 0.f;
#pragma unroll
    for (int r = 0; r < 4; r++) {
      int node = rowbase + lhi * 4 + r;
      float o = fmaxf(acc[r] + bias, 0.f);
      if (node < N) {
        x2[(size_t)node * HID + ct * 16 + l15] = (unsigned short)f2b(o);
        cl += o;
      }
    }
    cl += __shfl_xor(cl, 16);
    cl += __shfl_xor(cl, 32);
    cpart[ct] = cl;
  }
  if (lane < 16) {
#pragma unroll
    for (int ct = 0; ct < 8; ct++) cs[w][ct * 16 + lane] = cpart[ct];
  }
  __syncthreads();
  if (threadIdx.x < 128) {
    int f = threadIdx.x;
    partials[(size_t)blockIdx.x * 128 + f] = cs[0][f] + cs[1][f] + cs[2][f] + cs[3][f];
  }
}

// reduce per-block colsum partials
__global__ void k_colsum_red(const float* __restrict__ partials, int nblk,
                             float* __restrict__ colsum) {
  int f = threadIdx.x;  // 128 threads
  float t = 0.f;
  for (int b = blockIdx.x; b < nblk; b += gridDim.x) t += partials[(size_t)b * 128 + f];
  atomicAdd(&colsum[f], t);
}

// ---------------- heads (x2 bf16) ----------------
__global__ void k_heads(const unsigned short* __restrict__ x2, const float* __restrict__ Ws,
                        const float* __restrict__ bs, const float* __restrict__ Wmu,
                        const float* __restrict__ bmu, const float* __restrict__ Wls,
                        const float* __restrict__ bls, int N, float* __restrict__ s_arr,
                        float* __restrict__ out) {
  __shared__ float w[640];
  for (int t = threadIdx.x; t < 128; t += 256) {
    w[t] = Ws[t];
    w[128 + t] = Wmu[t * 2 + 0];
    w[256 + t] = Wmu[t * 2 + 1];
    w[384 + t] = Wls[t * 2 + 0];
    w[512 + t] = Wls[t * 2 + 1];
  }
  __syncthreads();
  int g = (int)((blockIdx.x * 256 + threadIdx.x) >> 5);
  int lane = threadIdx.x & 31;
  if (g >= N) return;
  uint2 v = ((const uint2*)x2)[(size_t)g * 32 + lane];
  float xv[4] = {b2f(v.x), b2f_hi(v.x), b2f(v.y), b2f_hi(v.y)};
  int f0 = lane * 4;
  float p0 = 0, p1 = 0, p2 = 0, p3 = 0, p4 = 0;
#pragma unroll
  for (int i = 0; i < 4; i++) {
    p0 += xv[i] * w[f0 + i];
    p1 += xv[i] * w[128 + f0 + i];
    p2 += xv[i] * w[256 + f0 + i];
    p3 += xv[i] * w[384 + f0 + i];
    p4 += xv[i] * w[512 + f0 + i];
  }
#pragma unroll
  for (int m = 1; m < 32; m <<= 1) {
    p0 += __shfl_xor(p0, m);
    p1 += __shfl_xor(p1, m);
    p2 += __shfl_xor(p2, m);
    p3 += __shfl_xor(p3, m);
    p4 += __shfl_xor(p4, m);
  }
  if (lane == 0) {
    s_arr[g] = p0 + bs[0];
    out[(size_t)N + g * 2 + 0] = p1 + bmu[0];
    out[(size_t)N + g * 2 + 1] = p2 + bmu[1];
    out[(size_t)3 * N + g * 2 + 0] = fminf(fmaxf(p3 + bls[0], -4.f), 2.f);
    out[(size_t)3 * N + g * 2 + 1] = fminf(fmaxf(p4 + bls[1], -4.f), 2.f);
  }
}

// ---------------- online logsumexp ----------------
__global__ void k_lse_part(const float* __restrict__ s, int N, float* __restrict__ pm,
                           float* __restrict__ pt) {
  __shared__ float smM[256], smT[256];
  float m = -1e30f, t = 0.f;
  for (int i = blockIdx.x * 256 + threadIdx.x; i < N; i += 256 * 256) {
    float v = s[i];
    if (v > m) { t = t * __expf(m - v) + 1.f; m = v; }
    else t += __expf(v - m);
  }
  smM[threadIdx.x] = m; smT[threadIdx.x] = t; __syncthreads();
  for (int st = 128; st > 0; st >>= 1) {
    if (threadIdx.x < st) {
      float m2 = smM[threadIdx.x + st], t2 = smT[threadIdx.x + st];
      float m1 = smM[threadIdx.x], t1 = smT[threadIdx.x];
      float M = fmaxf(m1, m2);
      smM[threadIdx.x] = M;
      smT[threadIdx.x] = t1 * __expf(m1 - M) + t2 * __expf(m2 - M);
    }
    __syncthreads();
  }
  if (threadIdx.x == 0) { pm[blockIdx.x] = smM[0]; pt[blockIdx.x] = smT[0]; }
}

__global__ void k_lse_fin(const float* __restrict__ pm, const float* __restrict__ pt,
                          float* __restrict__ scal) {
  __shared__ float smM[256], smT[256];
  smM[threadIdx.x] = pm[threadIdx.x];
  smT[threadIdx.x] = pt[threadIdx.x];
  __syncthreads();
  for (int st = 128; st > 0; st >>= 1) {
    if (threadIdx.x < st) {
      float m2 = smM[threadIdx.x + st], t2 = smT[threadIdx.x + st];
      float m1 = smM[threadIdx.x], t1 = smT[threadIdx.x];
      float M = fmaxf(m1, m2);
      smM[threadIdx.x] = M;
      smT[threadIdx.x] = t1 * __expf(m1 - M) + t2 * __expf(m2 - M);
    }
    __syncthreads();
  }
  if (threadIdx.x == 0) scal[2] = smM[0] + logf(smT[0]);
}

__global__ void k_logits(const float* __restrict__ s, const float* __restrict__ scal, int N,
                         float* __restrict__ out) {
  int n = blockIdx.x * 256 + threadIdx.x;
  if (n < N) out[n] = s[n] - scal[2];
}

// ---------------- value head ----------------
__global__ void k_value(const float* __restrict__ colsum, const float* __restrict__ Wv1,
                        const float* __restrict__ bv1, const float* __restrict__ Wv2,
                        const float* __restrict__ bv2, int N, float* __restrict__ out5N) {
  __shared__ float hid[64];
  float invN = 1.0f / (float)N;
  int j = threadIdx.x;
  if (j < 64) {
    float a = bv1[j];
    for (int f = 0; f < 128; f++) a += (colsum[f] * invN) * Wv1[f * 64 + j];
    hid[j] = fmaxf(a, 0.f) * Wv2[j];
  }
  __syncthreads();
  if (threadIdx.x == 0) {
    float v = bv2[0];
    for (int jj = 0; jj < 64; jj++) v += hid[jj];
    out5N[0] = v;
  }
}

extern "C" void kernel_launch(void* const* d_in, const int* in_sizes, int n_in,
                              void* d_out, int out_size, void* d_ws, size_t ws_size,
                              hipStream_t stream) {
  const float* coords = (const float*)d_in[0];
  const int* ei = (const int*)d_in[1];
  const float* W1 = (const float*)d_in[2];
  const float* b1 = (const float*)d_in[3];
  const float* W2 = (const float*)d_in[4];
  const float* b2 = (const float*)d_in[5];
  const float* Wsw = (const float*)d_in[6];
  const float* bsw = (const float*)d_in[7];
  const float* Wmu = (const float*)d_in[8];
  const float* bmu = (const float*)d_in[9];
  const float* Wls = (const float*)d_in[10];
  const float* bls = (const float*)d_in[11];
  const float* Wv1 = (const float*)d_in[12];
  const float* bv1 = (const float*)d_in[13];
  const float* Wv2 = (const float*)d_in[14];
  const float* bv2 = (const float*)d_in[15];
  int N = in_sizes[0] / 2;
  int E = in_sizes[1] / 2;
  const int* src = ei;
  const int* dst = ei + E;
  float* outf = (float*)d_out;
  int NB = (N + 255) >> 8;
  int nblkG = (N + 63) / 64;

  char* base = (char*)d_ws;
  size_t off = 0;
  auto alloc = [&](size_t bytes) -> void* {
    void* r = base + off;
    off += (bytes + 255) & ~(size_t)255;
    return r;
  };
  size_t zero_start = off;
  int* hd_g = (int*)alloc((size_t)NB * 4);
  int* hs_g = (int*)alloc((size_t)NB * 4);
  float* colsum = (float*)alloc(128 * 4);
  size_t zero_bytes = off - zero_start;
  int* based = (int*)alloc(((size_t)NB + 1) * 4);
  int* bases = (int*)alloc(((size_t)NB + 1) * 4);
  int* curd = (int*)alloc((size_t)NB * 4);
  int* curs = (int*)alloc((size_t)NB * 4);
  int* bmax = (int*)alloc((size_t)NB * 4);
  int* rowptr = (int*)alloc(((size_t)N + 1) * 4);
  int2* pairs = (int2*)alloc((size_t)E * 8);
  int* srcb = (int*)alloc((size_t)E * 4);
  int* colarr = (int*)alloc((size_t)E * 4);
  int* degsrc = (int*)alloc((size_t)N * 4);
  float* dinv = (float*)alloc((size_t)N * 4);
  float4* x0s = (float4*)alloc((size_t)N * 16);
  float4* xa3 = (float4*)alloc((size_t)N * 16);
  float* sarr = (float*)alloc((size_t)N * 4);
  float* pm = (float*)alloc(256 * 4);
  float* pt = (float*)alloc(256 * 4);
  float* scal = (float*)alloc(16 * 4);
  unsigned short* W2T = (unsigned short*)alloc(128 * 128 * 2);
  float* partials = (float*)alloc((size_t)nblkG * 128 * 4);
  unsigned short* x1s = (unsigned short*)alloc((size_t)N * HID * 2);
  unsigned short* xab = (unsigned short*)alloc((size_t)N * HID * 2);
  unsigned short* x2b = (unsigned short*)alloc((size_t)N * HID * 2);
  if (off > ws_size) return;

  int nblkN = (N + 255) / 256;

  hipMemsetAsync(base + zero_start, 0, zero_bytes, stream);
  k_hist<<<256, 256, 0, stream>>>(src, dst, E, NB, hd_g, hs_g);
  k_scan_buckets<<<1, NBMAX, 0, stream>>>(hd_g, hs_g, NB, E, based, bases, curd, curs);
  k_bucket_scatter<<<256, 256, 0, stream>>>(src, dst, E, NB, curd, curs, pairs, srcb);
  k_degsrc<<<NB, 256, 0, stream>>>(srcb, bases, N, degsrc, bmax);
  k_maxfin<<<1, NBMAX, 0, stream>>>(bmax, NB, scal);
  k_csr<<<NB, 256, 0, stream>>>(pairs, based, N, E, rowptr, dinv, colarr);
  k_prepW<<<64, 256, 0, stream>>>(W2, W2T);
  k_node<<<nblkN, 256, 0, stream>>>(coords, degsrc, dinv, scal, N, x0s);
  k_agg3<<<nblkN, 256, 0, stream>>>(x0s, dinv, rowptr, colarr, N, xa3);
  k_lin1<<<(N * HID + 255) / 256, 256, 0, stream>>>(xa3, dinv, W1, b1, N, x1s);
  k_agg128<<<(N + 7) / 8, 256, 0, stream>>>(x1s, dinv, rowptr, colarr, N, xab);
  k_gemm2<<<nblkG, 256, 0, stream>>>(xab, W2T, b2, N, x2b, partials);
  k_colsum_red<<<64, 128, 0, stream>>>(partials, nblkG, colsum);
  k_heads<<<(N + 7) / 8, 256, 0, stream>>>(x2b, Wsw, bsw, Wmu, bmu, Wls, bls, N, sarr, outf);
  k_lse_part<<<256, 256, 0, stream>>>(sarr, N, pm, pt);
  k_lse_fin<<<1, 256, 0, stream>>>(pm, pt, scal);
  k_logits<<<nblkN, 256, 0, stream>>>(sarr, scal, N, outf);
  k_value<<<1, 64, 0, stream>>>(colsum, Wv1, bv1, Wv2, bv2, N, outf + (size_t)5 * N);
}

// Round 5
// 244.306 us; speedup vs baseline: 2.3774x; 1.0922x over previous
//
#include <hip/hip_runtime.h>
#include <hip/hip_bf16.h>

#define HID 128
#define NBMAX 512  // max coarse buckets (N up to 131072)

typedef __bf16 bf16x8 __attribute__((ext_vector_type(8)));
typedef float f32x4 __attribute__((ext_vector_type(4)));

__device__ __forceinline__ float b2f(unsigned int u) { return __uint_as_float(u << 16); }
__device__ __forceinline__ float b2f_hi(unsigned int u) { return __uint_as_float(u & 0xFFFF0000u); }
__device__ __forceinline__ unsigned int f2b(float f) {
  unsigned int b = __float_as_uint(f);
  return (b + 0x7FFFu + ((b >> 16) & 1u)) >> 16;
}
__device__ __forceinline__ unsigned int pack2(float lo, float hi) {
  return f2b(lo) | (f2b(hi) << 16);
}

// ---------------- coarse histograms (LDS-privatized) ----------------
__global__ void k_hist(const int* __restrict__ src, const int* __restrict__ dst, int E, int NB,
                       int* __restrict__ hd_g, int* __restrict__ hs_g) {
  __shared__ int hd[NBMAX], hs[NBMAX];
  for (int i = threadIdx.x; i < NB; i += 256) { hd[i] = 0; hs[i] = 0; }
  __syncthreads();
  int stride = gridDim.x * 256;
  for (int e = blockIdx.x * 256 + threadIdx.x; e < E; e += stride) {
    atomicAdd(&hd[dst[e] >> 8], 1);
    atomicAdd(&hs[src[e] >> 8], 1);
  }
  __syncthreads();
  for (int i = threadIdx.x; i < NB; i += 256) {
    if (hd[i]) atomicAdd(&hd_g[i], hd[i]);
    if (hs[i]) atomicAdd(&hs_g[i], hs[i]);
  }
}

// ---------------- bucket scan ----------------
__global__ void k_scan_buckets(const int* __restrict__ hd_g, const int* __restrict__ hs_g,
                               int NB, int E, int* __restrict__ based, int* __restrict__ bases,
                               int* __restrict__ curd, int* __restrict__ curs) {
  __shared__ int sd[NBMAX], ss[NBMAX];
  int i = threadIdx.x;
  int vd = (i < NB) ? hd_g[i] : 0;
  int vs = (i < NB) ? hs_g[i] : 0;
  sd[i] = vd; ss[i] = vs; __syncthreads();
  for (int st = 1; st < NBMAX; st <<= 1) {
    int td = (i >= st) ? sd[i - st] : 0;
    int ts = (i >= st) ? ss[i - st] : 0;
    __syncthreads();
    sd[i] += td; ss[i] += ts;
    __syncthreads();
  }
  if (i < NB) {
    int bd = sd[i] - vd, bs = ss[i] - vs;
    based[i] = bd; bases[i] = bs;
    curd[i] = bd; curs[i] = bs;
  }
  if (i == 0) { based[NB] = E; bases[NB] = E; }
}

// ---------------- bucketed scatter ----------------
__global__ void k_bucket_scatter(const int* __restrict__ src, const int* __restrict__ dst,
                                 int E, int NB, int* __restrict__ curd, int* __restrict__ curs,
                                 int2* __restrict__ pairs, int* __restrict__ srcb) {
  __shared__ int hd[NBMAX], hs[NBMAX], bd[NBMAX], bs[NBMAX];
  for (int i = threadIdx.x; i < NB; i += 256) { hd[i] = 0; hs[i] = 0; }
  __syncthreads();
  int per = (E + gridDim.x - 1) / gridDim.x;
  int begin = blockIdx.x * per;
  int end = min(E, begin + per);
  for (int e = begin + threadIdx.x; e < end; e += 256) {
    atomicAdd(&hd[dst[e] >> 8], 1);
    atomicAdd(&hs[src[e] >> 8], 1);
  }
  __syncthreads();
  for (int i = threadIdx.x; i < NB; i += 256) {
    bd[i] = hd[i] ? atomicAdd(&curd[i], hd[i]) : 0;
    bs[i] = hs[i] ? atomicAdd(&curs[i], hs[i]) : 0;
    hd[i] = 0; hs[i] = 0;
  }
  __syncthreads();
  for (int e = begin + threadIdx.x; e < end; e += 256) {
    int d = dst[e], s = src[e];
    int p = bd[d >> 8] + atomicAdd(&hd[d >> 8], 1);
    pairs[p] = make_int2(d, s);
    int q = bs[s >> 8] + atomicAdd(&hs[s >> 8], 1);
    srcb[q] = s;
  }
}

// ---------------- per-bucket out-degree (+ per-bucket max) ----------------
__global__ void k_degsrc(const int* __restrict__ srcb, const int* __restrict__ bases, int N,
                         int* __restrict__ degsrc, int* __restrict__ bmax) {
  __shared__ int cnt[256];
  __shared__ int mx[256];
  int b = blockIdx.x;
  cnt[threadIdx.x] = 0; __syncthreads();
  int lo = bases[b], hi = bases[b + 1];
  for (int k = lo + threadIdx.x; k < hi; k += 256) atomicAdd(&cnt[srcb[k] & 255], 1);
  __syncthreads();
  int g = (b << 8) + threadIdx.x;
  int c = cnt[threadIdx.x];
  if (g < N) degsrc[g] = c;
  mx[threadIdx.x] = (g < N) ? c : 0; __syncthreads();
  for (int s = 128; s > 0; s >>= 1) {
    if (threadIdx.x < s) mx[threadIdx.x] = max(mx[threadIdx.x], mx[threadIdx.x + s]);
    __syncthreads();
  }
  if (threadIdx.x == 0) bmax[b] = mx[0];
}

__global__ void k_maxfin(const int* __restrict__ bmax, int NB, float* __restrict__ scal) {
  __shared__ int sm[NBMAX];
  int i = threadIdx.x;
  sm[i] = (i < NB) ? bmax[i] : 0; __syncthreads();
  for (int s = NBMAX / 2; s > 0; s >>= 1) {
    if (i < s) sm[i] = max(sm[i], sm[i + s]);
    __syncthreads();
  }
  if (i == 0) scal[0] = 1.0f / (float)max(sm[0], 1);
}

// ---------------- per-bucket CSR build + dinv ----------------
__global__ void k_csr(const int2* __restrict__ pairs, const int* __restrict__ based, int N, int E,
                      int* __restrict__ rowptr, float* __restrict__ dinv,
                      int* __restrict__ colarr) {
  __shared__ int cnt[256], scn[256], cur[256];
  int b = blockIdx.x;
  cnt[threadIdx.x] = 0; __syncthreads();
  int lo = based[b], hi = based[b + 1];
  for (int k = lo + threadIdx.x; k < hi; k += 256) atomicAdd(&cnt[pairs[k].x & 255], 1);
  __syncthreads();
  int c = cnt[threadIdx.x];
  scn[threadIdx.x] = c; __syncthreads();
  for (int st = 1; st < 256; st <<= 1) {
    int t = (threadIdx.x >= st) ? scn[threadIdx.x - st] : 0;
    __syncthreads();
    scn[threadIdx.x] += t;
    __syncthreads();
  }
  int excl = scn[threadIdx.x] - c;
  int g = (b << 8) + threadIdx.x;
  if (g < N) {
    rowptr[g] = lo + excl;
    dinv[g] = rsqrtf((float)(c + 1));
  }
  cur[threadIdx.x] = lo + excl;
  __syncthreads();
  for (int k = lo + threadIdx.x; k < hi; k += 256) {
    int2 p = pairs[k];
    int pos = atomicAdd(&cur[p.x & 255], 1);
    colarr[pos] = p.y;
  }
  if (b == 0 && threadIdx.x == 0) rowptr[N] = E;
}

// ---------------- W2 -> bf16 transposed [j][k] ----------------
__global__ void k_prepW(const float* __restrict__ W2, unsigned short* __restrict__ W2T) {
  int idx = blockIdx.x * 256 + threadIdx.x;
  if (idx >= 128 * 128) return;
  int j = idx >> 7, k = idx & 127;
  W2T[j * 128 + k] = (unsigned short)f2b(W2[k * 128 + j]);
}

// node features prescaled by own dinv
__global__ void k_node(const float* __restrict__ coords, const int* __restrict__ degsrc,
                       const float* __restrict__ dinv, const float* __restrict__ scal,
                       int N, float4* __restrict__ x0s) {
  int n = blockIdx.x * 256 + threadIdx.x;
  if (n >= N) return;
  float inv = scal[0];
  float di = dinv[n];
  float4 v;
  v.x = coords[n * 2 + 0] * di;
  v.y = coords[n * 2 + 1] * di;
  v.z = (float)degsrc[n] * inv * di;
  v.w = 0.f;
  x0s[n] = v;
}

// ---------------- GCN layer 1 aggregation ----------------
__global__ void k_agg3(const float4* __restrict__ x0s, const float* __restrict__ dinv,
                       const int* __restrict__ rowptr, const int* __restrict__ col,
                       int N, float4* __restrict__ xa3) {
  int n = blockIdx.x * 256 + threadIdx.x;
  if (n >= N) return;
  float4 a = x0s[n];
  int b = rowptr[n], en = rowptr[n + 1];
  int k = b;
  for (; k + 3 < en; k += 4) {
    int s0 = col[k], s1 = col[k + 1], s2 = col[k + 2], s3 = col[k + 3];
    float4 w0 = x0s[s0];
    float4 w1 = x0s[s1];
    float4 w2 = x0s[s2];
    float4 w3 = x0s[s3];
    a.x += (w0.x + w1.x) + (w2.x + w3.x);
    a.y += (w0.y + w1.y) + (w2.y + w3.y);
    a.z += (w0.z + w1.z) + (w2.z + w3.z);
  }
  for (; k < en; k++) {
    float4 w = x0s[col[k]];
    a.x += w.x; a.y += w.y; a.z += w.z;
  }
  float di = dinv[n];
  a.x *= di; a.y *= di; a.z *= di; a.w = 0.f;
  xa3[n] = a;
}

// linear: x1s = relu(xa3 @ W1 + b1) * dinv[n], stored bf16
__global__ void k_lin1(const float4* __restrict__ xa3, const float* __restrict__ dinv,
                       const float* __restrict__ W1, const float* __restrict__ b1, int N,
                       unsigned short* __restrict__ x1s) {
  int idx = blockIdx.x * 256 + threadIdx.x;
  if (idx >= N * HID) return;
  int n = idx >> 7, f = idx & 127;
  float4 a = xa3[n];
  float v = b1[f] + a.x * W1[f] + a.y * W1[128 + f] + a.z * W1[256 + f];
  v = fmaxf(v, 0.f) * dinv[n];
  x1s[idx] = (unsigned short)f2b(v);
}

// ---------------- GCN layer 2 aggregation: 16 lanes/node, uint4 (8 bf16)/lane ----------------
__global__ void k_agg128(const unsigned short* __restrict__ x1s, const float* __restrict__ dinv,
                         const int* __restrict__ rowptr, const int* __restrict__ col,
                         int N, unsigned short* __restrict__ xa) {
  int g = (int)((blockIdx.x * 256 + threadIdx.x) >> 4);
  int lane = threadIdx.x & 15;
  if (g >= N) return;
  const uint4* base = (const uint4*)x1s + lane;  // row stride = 16 uint4
  uint4 self = base[(size_t)g * 16];
  float a0 = b2f(self.x), a1 = b2f_hi(self.x);
  float a2 = b2f(self.y), a3 = b2f_hi(self.y);
  float a4 = b2f(self.z), a5 = b2f_hi(self.z);
  float a6 = b2f(self.w), a7 = b2f_hi(self.w);
  int b = rowptr[g], en = rowptr[g + 1];
  int k = b;
  for (; k + 3 < en; k += 4) {
    int s0 = col[k], s1 = col[k + 1], s2 = col[k + 2], s3 = col[k + 3];
    uint4 w0 = base[(size_t)s0 * 16];
    uint4 w1 = base[(size_t)s1 * 16];
    uint4 w2 = base[(size_t)s2 * 16];
    uint4 w3 = base[(size_t)s3 * 16];
    a0 += (b2f(w0.x) + b2f(w1.x)) + (b2f(w2.x) + b2f(w3.x));
    a1 += (b2f_hi(w0.x) + b2f_hi(w1.x)) + (b2f_hi(w2.x) + b2f_hi(w3.x));
    a2 += (b2f(w0.y) + b2f(w1.y)) + (b2f(w2.y) + b2f(w3.y));
    a3 += (b2f_hi(w0.y) + b2f_hi(w1.y)) + (b2f_hi(w2.y) + b2f_hi(w3.y));
    a4 += (b2f(w0.z) + b2f(w1.z)) + (b2f(w2.z) + b2f(w3.z));
    a5 += (b2f_hi(w0.z) + b2f_hi(w1.z)) + (b2f_hi(w2.z) + b2f_hi(w3.z));
    a6 += (b2f(w0.w) + b2f(w1.w)) + (b2f(w2.w) + b2f(w3.w));
    a7 += (b2f_hi(w0.w) + b2f_hi(w1.w)) + (b2f_hi(w2.w) + b2f_hi(w3.w));
  }
  for (; k < en; k++) {
    uint4 w = base[(size_t)col[k] * 16];
    a0 += b2f(w.x); a1 += b2f_hi(w.x);
    a2 += b2f(w.y); a3 += b2f_hi(w.y);
    a4 += b2f(w.z); a5 += b2f_hi(w.z);
    a6 += b2f(w.w); a7 += b2f_hi(w.w);
  }
  float di = dinv[g];
  uint4 o;
  o.x = pack2(a0 * di, a1 * di);
  o.y = pack2(a2 * di, a3 * di);
  o.z = pack2(a4 * di, a5 * di);
  o.w = pack2(a6 * di, a7 * di);
  ((uint4*)xa)[(size_t)g * 16 + lane] = o;
}

// ---------------- layer 2 GEMM via MFMA, fused heads + colsum (x2 never stored) ----------
// block = 256 thr = 4 waves; wave wv: rows [blk*64 + wv*16, +16), all 128 cols.
// A-frag: row = lane&15, k = (lane>>4)*8 + kk*32. B-frag: col = lane&15 from W2T[col][k].
// D: col = lane&15, row = (lane>>4)*4 + reg (m89-verified mapping).
__global__ __launch_bounds__(256) void k_gemm2(const unsigned short* __restrict__ xab,
                                               const unsigned short* __restrict__ W2T,
                                               const float* __restrict__ b2,
                                               const float* __restrict__ Ws,
                                               const float* __restrict__ bs,
                                               const float* __restrict__ Wmu,
                                               const float* __restrict__ bmu,
                                               const float* __restrict__ Wls,
                                               const float* __restrict__ bls,
                                               int N, float* __restrict__ s_arr,
                                               float* __restrict__ out,
                                               float* __restrict__ partials) {
  __shared__ float w[640];
  __shared__ float cs[4][128];
  for (int t = threadIdx.x; t < 128; t += 256) {
    w[t] = Ws[t];
    w[128 + t] = Wmu[t * 2 + 0];
    w[256 + t] = Wmu[t * 2 + 1];
    w[384 + t] = Wls[t * 2 + 0];
    w[512 + t] = Wls[t * 2 + 1];
  }
  __syncthreads();
  int wv = threadIdx.x >> 6;
  int lane = threadIdx.x & 63;
  int l15 = lane & 15, lhi = lane >> 4;
  int rowbase = blockIdx.x * 64 + wv * 16;
  int arow = rowbase + l15;
  int arowc = min(arow, N - 1);
  const unsigned short* ap = xab + (size_t)arowc * HID + lhi * 8;
  bf16x8 a[4];
#pragma unroll
  for (int kk = 0; kk < 4; kk++) a[kk] = *(const bf16x8*)(ap + kk * 32);
  float cpart[8];
  float p0[4] = {0, 0, 0, 0}, p1[4] = {0, 0, 0, 0}, p2[4] = {0, 0, 0, 0};
  float p3[4] = {0, 0, 0, 0}, p4[4] = {0, 0, 0, 0};
#pragma unroll
  for (int ct = 0; ct < 8; ct++) {
    f32x4 acc = {0.f, 0.f, 0.f, 0.f};
    const unsigned short* bp = W2T + (size_t)(ct * 16 + l15) * HID + lhi * 8;
#pragma unroll
    for (int kk = 0; kk < 4; kk++) {
      bf16x8 bfr = *(const bf16x8*)(bp + kk * 32);
      acc = __builtin_amdgcn_mfma_f32_16x16x32_bf16(a[kk], bfr, acc, 0, 0, 0);
    }
    int cidx = ct * 16 + l15;
    float bias = b2[cidx];
    float ws_ = w[cidx];
    float wm0 = w[128 + cidx], wm1 = w[256 + cidx];
    float wl0 = w[384 + cidx], wl1 = w[512 + cidx];
    float cl = 0.f;
#pragma unroll
    for (int r = 0; r < 4; r++) {
      int node = rowbase + lhi * 4 + r;
      float o = fmaxf(acc[r] + bias, 0.f);
      if (node < N) cl += o;
      p0[r] += o * ws_;
      p1[r] += o * wm0;
      p2[r] += o * wm1;
      p3[r] += o * wl0;
      p4[r] += o * wl1;
    }
    cl += __shfl_xor(cl, 16);
    cl += __shfl_xor(cl, 32);
    cpart[ct] = cl;
  }
  // reduce heads across the 16 column lanes
#pragma unroll
  for (int r = 0; r < 4; r++) {
#pragma unroll
    for (int m = 1; m < 16; m <<= 1) {
      p0[r] += __shfl_xor(p0[r], m);
      p1[r] += __shfl_xor(p1[r], m);
      p2[r] += __shfl_xor(p2[r], m);
      p3[r] += __shfl_xor(p3[r], m);
      p4[r] += __shfl_xor(p4[r], m);
    }
  }
  if (l15 == 0) {
#pragma unroll
    for (int r = 0; r < 4; r++) {
      int node = rowbase + lhi * 4 + r;
      if (node < N) {
        s_arr[node] = p0[r] + bs[0];
        out[(size_t)N + node * 2 + 0] = p1[r] + bmu[0];
        out[(size_t)N + node * 2 + 1] = p2[r] + bmu[1];
        out[(size_t)3 * N + node * 2 + 0] = fminf(fmaxf(p3[r] + bls[0], -4.f), 2.f);
        out[(size_t)3 * N + node * 2 + 1] = fminf(fmaxf(p4[r] + bls[1], -4.f), 2.f);
      }
    }
  }
  if (lane < 16) {
#pragma unroll
    for (int ct = 0; ct < 8; ct++) cs[wv][ct * 16 + lane] = cpart[ct];
  }
  __syncthreads();
  if (threadIdx.x < 128) {
    int f = threadIdx.x;
    partials[(size_t)blockIdx.x * 128 + f] = cs[0][f] + cs[1][f] + cs[2][f] + cs[3][f];
  }
}

// reduce per-block colsum partials
__global__ void k_colsum_red(const float* __restrict__ partials, int nblk,
                             float* __restrict__ colsum) {
  int f = threadIdx.x;  // 128 threads
  float t = 0.f;
  for (int b = blockIdx.x; b < nblk; b += gridDim.x) t += partials[(size_t)b * 128 + f];
  atomicAdd(&colsum[f], t);
}

// ---------------- online logsumexp ----------------
__global__ void k_lse_part(const float* __restrict__ s, int N, float* __restrict__ pm,
                           float* __restrict__ pt) {
  __shared__ float smM[256], smT[256];
  float m = -1e30f, t = 0.f;
  for (int i = blockIdx.x * 256 + threadIdx.x; i < N; i += 256 * 256) {
    float v = s[i];
    if (v > m) { t = t * __expf(m - v) + 1.f; m = v; }
    else t += __expf(v - m);
  }
  smM[threadIdx.x] = m; smT[threadIdx.x] = t; __syncthreads();
  for (int st = 128; st > 0; st >>= 1) {
    if (threadIdx.x < st) {
      float m2 = smM[threadIdx.x + st], t2 = smT[threadIdx.x + st];
      float m1 = smM[threadIdx.x], t1 = smT[threadIdx.x];
      float M = fmaxf(m1, m2);
      smM[threadIdx.x] = M;
      smT[threadIdx.x] = t1 * __expf(m1 - M) + t2 * __expf(m2 - M);
    }
    __syncthreads();
  }
  if (threadIdx.x == 0) { pm[blockIdx.x] = smM[0]; pt[blockIdx.x] = smT[0]; }
}

__global__ void k_lse_fin(const float* __restrict__ pm, const float* __restrict__ pt,
                          float* __restrict__ scal) {
  __shared__ float smM[256], smT[256];
  smM[threadIdx.x] = pm[threadIdx.x];
  smT[threadIdx.x] = pt[threadIdx.x];
  __syncthreads();
  for (int st = 128; st > 0; st >>= 1) {
    if (threadIdx.x < st) {
      float m2 = smM[threadIdx.x + st], t2 = smT[threadIdx.x + st];
      float m1 = smM[threadIdx.x], t1 = smT[threadIdx.x];
      float M = fmaxf(m1, m2);
      smM[threadIdx.x] = M;
      smT[threadIdx.x] = t1 * __expf(m1 - M) + t2 * __expf(m2 - M);
    }
    __syncthreads();
  }
  if (threadIdx.x == 0) scal[2] = smM[0] + logf(smT[0]);
}

__global__ void k_logits(const float* __restrict__ s, const float* __restrict__ scal, int N,
                         float* __restrict__ out) {
  int n = blockIdx.x * 256 + threadIdx.x;
  if (n < N) out[n] = s[n] - scal[2];
}

// ---------------- value head ----------------
__global__ void k_value(const float* __restrict__ colsum, const float* __restrict__ Wv1,
                        const float* __restrict__ bv1, const float* __restrict__ Wv2,
                        const float* __restrict__ bv2, int N, float* __restrict__ out5N) {
  __shared__ float hid[64];
  float invN = 1.0f / (float)N;
  int j = threadIdx.x;
  if (j < 64) {
    float a = bv1[j];
    for (int f = 0; f < 128; f++) a += (colsum[f] * invN) * Wv1[f * 64 + j];
    hid[j] = fmaxf(a, 0.f) * Wv2[j];
  }
  __syncthreads();
  if (threadIdx.x == 0) {
    float v = bv2[0];
    for (int jj = 0; jj < 64; jj++) v += hid[jj];
    out5N[0] = v;
  }
}

extern "C" void kernel_launch(void* const* d_in, const int* in_sizes, int n_in,
                              void* d_out, int out_size, void* d_ws, size_t ws_size,
                              hipStream_t stream) {
  const float* coords = (const float*)d_in[0];
  const int* ei = (const int*)d_in[1];
  const float* W1 = (const float*)d_in[2];
  const float* b1 = (const float*)d_in[3];
  const float* W2 = (const float*)d_in[4];
  const float* b2 = (const float*)d_in[5];
  const float* Wsw = (const float*)d_in[6];
  const float* bsw = (const float*)d_in[7];
  const float* Wmu = (const float*)d_in[8];
  const float* bmu = (const float*)d_in[9];
  const float* Wls = (const float*)d_in[10];
  const float* bls = (const float*)d_in[11];
  const float* Wv1 = (const float*)d_in[12];
  const float* bv1 = (const float*)d_in[13];
  const float* Wv2 = (const float*)d_in[14];
  const float* bv2 = (const float*)d_in[15];
  int N = in_sizes[0] / 2;
  int E = in_sizes[1] / 2;
  const int* src = ei;
  const int* dst = ei + E;
  float* outf = (float*)d_out;
  int NB = (N + 255) >> 8;
  int nblkG = (N + 63) / 64;

  char* base = (char*)d_ws;
  size_t off = 0;
  auto alloc = [&](size_t bytes) -> void* {
    void* r = base + off;
    off += (bytes + 255) & ~(size_t)255;
    return r;
  };
  size_t zero_start = off;
  int* hd_g = (int*)alloc((size_t)NB * 4);
  int* hs_g = (int*)alloc((size_t)NB * 4);
  float* colsum = (float*)alloc(128 * 4);
  size_t zero_bytes = off - zero_start;
  int* based = (int*)alloc(((size_t)NB + 1) * 4);
  int* bases = (int*)alloc(((size_t)NB + 1) * 4);
  int* curd = (int*)alloc((size_t)NB * 4);
  int* curs = (int*)alloc((size_t)NB * 4);
  int* bmax = (int*)alloc((size_t)NB * 4);
  int* rowptr = (int*)alloc(((size_t)N + 1) * 4);
  int2* pairs = (int2*)alloc((size_t)E * 8);
  int* srcb = (int*)alloc((size_t)E * 4);
  int* colarr = (int*)alloc((size_t)E * 4);
  int* degsrc = (int*)alloc((size_t)N * 4);
  float* dinv = (float*)alloc((size_t)N * 4);
  float4* x0s = (float4*)alloc((size_t)N * 16);
  float4* xa3 = (float4*)alloc((size_t)N * 16);
  float* sarr = (float*)alloc((size_t)N * 4);
  float* pm = (float*)alloc(256 * 4);
  float* pt = (float*)alloc(256 * 4);
  float* scal = (float*)alloc(16 * 4);
  unsigned short* W2T = (unsigned short*)alloc(128 * 128 * 2);
  float* partials = (float*)alloc((size_t)nblkG * 128 * 4);
  unsigned short* x1s = (unsigned short*)alloc((size_t)N * HID * 2);
  unsigned short* xab = (unsigned short*)alloc((size_t)N * HID * 2);
  if (off > ws_size) return;

  int nblkN = (N + 255) / 256;

  hipMemsetAsync(base + zero_start, 0, zero_bytes, stream);
  k_hist<<<256, 256, 0, stream>>>(src, dst, E, NB, hd_g, hs_g);
  k_scan_buckets<<<1, NBMAX, 0, stream>>>(hd_g, hs_g, NB, E, based, bases, curd, curs);
  k_bucket_scatter<<<256, 256, 0, stream>>>(src, dst, E, NB, curd, curs, pairs, srcb);
  k_degsrc<<<NB, 256, 0, stream>>>(srcb, bases, N, degsrc, bmax);
  k_maxfin<<<1, NBMAX, 0, stream>>>(bmax, NB, scal);
  k_csr<<<NB, 256, 0, stream>>>(pairs, based, N, E, rowptr, dinv, colarr);
  k_prepW<<<64, 256, 0, stream>>>(W2, W2T);
  k_node<<<nblkN, 256, 0, stream>>>(coords, degsrc, dinv, scal, N, x0s);
  k_agg3<<<nblkN, 256, 0, stream>>>(x0s, dinv, rowptr, colarr, N, xa3);
  k_lin1<<<(N * HID + 255) / 256, 256, 0, stream>>>(xa3, dinv, W1, b1, N, x1s);
  k_agg128<<<(N + 15) / 16, 256, 0, stream>>>(x1s, dinv, rowptr, colarr, N, xab);
  k_gemm2<<<nblkG, 256, 0, stream>>>(xab, W2T, b2, Wsw, bsw, Wmu, bmu, Wls, bls, N, sarr, outf,
                                     partials);
  k_colsum_red<<<64, 128, 0, stream>>>(partials, nblkG, colsum);
  k_lse_part<<<256, 256, 0, stream>>>(sarr, N, pm, pt);
  k_lse_fin<<<1, 256, 0, stream>>>(pm, pt, scal);
  k_logits<<<nblkN, 256, 0, stream>>>(sarr, scal, N, outf);
  k_value<<<1, 64, 0, stream>>>(colsum, Wv1, bv1, Wv2, bv2, N, outf + (size_t)5 * N);
}

// Round 6
// 202.923 us; speedup vs baseline: 2.8622x; 1.2039x over previous
//
#include <hip/hip_runtime.h>
#include <hip/hip_bf16.h>

#define HID 128
#define NBMAX 512  // max coarse buckets (N up to 131072)

typedef __bf16 bf16x8 __attribute__((ext_vector_type(8)));
typedef float f32x4 __attribute__((ext_vector_type(4)));
typedef float f32x2 __attribute__((ext_vector_type(2)));

#if defined(__has_builtin)
#if __has_builtin(__builtin_amdgcn_cvt_pk_f32_fp8) && __has_builtin(__builtin_amdgcn_cvt_pk_fp8_f32)
#define HAVE_FP8_CVT 1
#endif
#endif
#ifndef HAVE_FP8_CVT
#define HAVE_FP8_CVT 0
#include <hip/hip_fp8.h>
#endif

__device__ __forceinline__ float b2f(unsigned int u) { return __uint_as_float(u << 16); }
__device__ __forceinline__ float b2f_hi(unsigned int u) { return __uint_as_float(u & 0xFFFF0000u); }
__device__ __forceinline__ unsigned int f2b(float f) {
  unsigned int b = __float_as_uint(f);
  return (b + 0x7FFFu + ((b >> 16) & 1u)) >> 16;
}
__device__ __forceinline__ unsigned int pack2(float lo, float hi) {
  return f2b(lo) | (f2b(hi) << 16);
}

#if !HAVE_FP8_CVT
__device__ __forceinline__ float fp8dec(unsigned int u) {
  unsigned int e = (u >> 3) & 15, m = u & 7, sgn = (u >> 7) & 1;
  float v;
  if (e) v = __uint_as_float(((e + 120) << 23) | (m << 20));
  else v = (float)m * 0.001953125f;
  return sgn ? -v : v;
}
#endif

__device__ __forceinline__ unsigned int pk4_fp8(float v0, float v1, float v2, float v3) {
#if HAVE_FP8_CVT
  int pk = 0;
  pk = __builtin_amdgcn_cvt_pk_fp8_f32(v0, v1, pk, false);
  pk = __builtin_amdgcn_cvt_pk_fp8_f32(v2, v3, pk, true);
  return (unsigned int)pk;
#else
  __hip_fp8_e4m3 a(v0), b(v1), c(v2), d(v3);
  return (unsigned)a.__x | ((unsigned)b.__x << 8) | ((unsigned)c.__x << 16) |
         ((unsigned)d.__x << 24);
#endif
}

__device__ __forceinline__ void acc4_fp8(unsigned int u, float* a) {
#if HAVE_FP8_CVT
  f32x2 lo = __builtin_amdgcn_cvt_pk_f32_fp8((int)u, false);
  f32x2 hi = __builtin_amdgcn_cvt_pk_f32_fp8((int)u, true);
  a[0] += lo.x; a[1] += lo.y; a[2] += hi.x; a[3] += hi.y;
#else
  a[0] += fp8dec(u & 255); a[1] += fp8dec((u >> 8) & 255);
  a[2] += fp8dec((u >> 16) & 255); a[3] += fp8dec((u >> 24) & 255);
#endif
}

// ---------------- coarse histograms (LDS-privatized) ----------------
__global__ void k_hist(const int* __restrict__ src, const int* __restrict__ dst, int E, int NB,
                       int* __restrict__ hd_g, int* __restrict__ hs_g) {
  __shared__ int hd[NBMAX], hs[NBMAX];
  for (int i = threadIdx.x; i < NB; i += 256) { hd[i] = 0; hs[i] = 0; }
  __syncthreads();
  int stride = gridDim.x * 256;
  for (int e = blockIdx.x * 256 + threadIdx.x; e < E; e += stride) {
    atomicAdd(&hd[dst[e] >> 8], 1);
    atomicAdd(&hs[src[e] >> 8], 1);
  }
  __syncthreads();
  for (int i = threadIdx.x; i < NB; i += 256) {
    if (hd[i]) atomicAdd(&hd_g[i], hd[i]);
    if (hs[i]) atomicAdd(&hs_g[i], hs[i]);
  }
}

// ---------------- bucket scan ----------------
__global__ void k_scan_buckets(const int* __restrict__ hd_g, const int* __restrict__ hs_g,
                               int NB, int E, int* __restrict__ based, int* __restrict__ bases,
                               int* __restrict__ curd, int* __restrict__ curs) {
  __shared__ int sd[NBMAX], ss[NBMAX];
  int i = threadIdx.x;
  int vd = (i < NB) ? hd_g[i] : 0;
  int vs = (i < NB) ? hs_g[i] : 0;
  sd[i] = vd; ss[i] = vs; __syncthreads();
  for (int st = 1; st < NBMAX; st <<= 1) {
    int td = (i >= st) ? sd[i - st] : 0;
    int ts = (i >= st) ? ss[i - st] : 0;
    __syncthreads();
    sd[i] += td; ss[i] += ts;
    __syncthreads();
  }
  if (i < NB) {
    int bd = sd[i] - vd, bs = ss[i] - vs;
    based[i] = bd; bases[i] = bs;
    curd[i] = bd; curs[i] = bs;
  }
  if (i == 0) { based[NB] = E; bases[NB] = E; }
}

// ---------------- bucketed scatter: packed (src<<8|dst&255) pairs + srcb ----------------
__global__ void k_bucket_scatter(const int* __restrict__ src, const int* __restrict__ dst,
                                 int E, int NB, int* __restrict__ curd, int* __restrict__ curs,
                                 int* __restrict__ pairsp, int* __restrict__ srcb) {
  __shared__ int hd[NBMAX], hs[NBMAX], bd[NBMAX], bs[NBMAX];
  for (int i = threadIdx.x; i < NB; i += 256) { hd[i] = 0; hs[i] = 0; }
  __syncthreads();
  int per = (E + gridDim.x - 1) / gridDim.x;
  int begin = blockIdx.x * per;
  int end = min(E, begin + per);
  for (int e = begin + threadIdx.x; e < end; e += 256) {
    atomicAdd(&hd[dst[e] >> 8], 1);
    atomicAdd(&hs[src[e] >> 8], 1);
  }
  __syncthreads();
  for (int i = threadIdx.x; i < NB; i += 256) {
    bd[i] = hd[i] ? atomicAdd(&curd[i], hd[i]) : 0;
    bs[i] = hs[i] ? atomicAdd(&curs[i], hs[i]) : 0;
    hd[i] = 0; hs[i] = 0;
  }
  __syncthreads();
  for (int e = begin + threadIdx.x; e < end; e += 256) {
    int d = dst[e], s = src[e];
    int p = bd[d >> 8] + atomicAdd(&hd[d >> 8], 1);
    pairsp[p] = (s << 8) | (d & 255);
    int q = bs[s >> 8] + atomicAdd(&hs[s >> 8], 1);
    srcb[q] = s;
  }
}

// ---------------- merged: out-degree (+bmax) AND CSR build ----------------
__global__ void k_degcsr(const int* __restrict__ srcb, const int* __restrict__ bases,
                         const int* __restrict__ pairsp, const int* __restrict__ based,
                         int N, int E, int* __restrict__ degsrc, int* __restrict__ bmax,
                         int* __restrict__ rowptr, float* __restrict__ dinv,
                         int* __restrict__ colarr) {
  __shared__ int cnt[256], scn[256], cur[256];
  int b = blockIdx.x, tid = threadIdx.x;
  int g = (b << 8) + tid;
  // phase A: out-degree from srcb bucket b
  cnt[tid] = 0; __syncthreads();
  int lo = bases[b], hi = bases[b + 1];
  for (int k = lo + tid; k < hi; k += 256) atomicAdd(&cnt[srcb[k] & 255], 1);
  __syncthreads();
  int c = cnt[tid];
  if (g < N) degsrc[g] = c;
  scn[tid] = (g < N) ? c : 0; __syncthreads();
  for (int s = 128; s > 0; s >>= 1) {
    if (tid < s) scn[tid] = max(scn[tid], scn[tid + s]);
    __syncthreads();
  }
  if (tid == 0) bmax[b] = scn[0];
  __syncthreads();
  // phase B: CSR from packed pairs bucket b
  cnt[tid] = 0; __syncthreads();
  lo = based[b]; hi = based[b + 1];
  for (int k = lo + tid; k < hi; k += 256) atomicAdd(&cnt[pairsp[k] & 255], 1);
  __syncthreads();
  c = cnt[tid];
  scn[tid] = c; __syncthreads();
  for (int st = 1; st < 256; st <<= 1) {
    int t = (tid >= st) ? scn[tid - st] : 0;
    __syncthreads();
    scn[tid] += t;
    __syncthreads();
  }
  int excl = scn[tid] - c;
  if (g < N) {
    rowptr[g] = lo + excl;
    dinv[g] = rsqrtf((float)(c + 1));
  }
  cur[tid] = lo + excl;
  __syncthreads();
  for (int k = lo + tid; k < hi; k += 256) {
    int p = pairsp[k];
    int pos = atomicAdd(&cur[p & 255], 1);
    colarr[pos] = ((unsigned)p) >> 8;
  }
  if (b == 0 && tid == 0) rowptr[N] = E;
}

// ---------------- W2 -> bf16 transposed [j][k] ----------------
__global__ void k_prepW(const float* __restrict__ W2, unsigned short* __restrict__ W2T) {
  int idx = blockIdx.x * 256 + threadIdx.x;
  if (idx >= 128 * 128) return;
  int j = idx >> 7, k = idx & 127;
  W2T[j * 128 + k] = (unsigned short)f2b(W2[k * 128 + j]);
}

// node features prescaled by own dinv (inline global bmax reduction)
__global__ void k_node(const float* __restrict__ coords, const int* __restrict__ degsrc,
                       const float* __restrict__ dinv, const int* __restrict__ bmax, int NB,
                       int N, float4* __restrict__ x0s) {
  __shared__ int sm[256];
  int tid = threadIdx.x;
  int m = 0;
  for (int i = tid; i < NB; i += 256) m = max(m, bmax[i]);
  sm[tid] = m; __syncthreads();
  for (int s = 128; s > 0; s >>= 1) {
    if (tid < s) sm[tid] = max(sm[tid], sm[tid + s]);
    __syncthreads();
  }
  float inv = 1.0f / (float)max(sm[0], 1);
  int n = blockIdx.x * 256 + tid;
  if (n >= N) return;
  float di = dinv[n];
  float4 v;
  v.x = coords[n * 2 + 0] * di;
  v.y = coords[n * 2 + 1] * di;
  v.z = (float)degsrc[n] * inv * di;
  v.w = 0.f;
  x0s[n] = v;
}

// ---------------- fused layer-1: aggregate 3 feats + linear + relu + prescale -> fp8 ----
__global__ void k_agg3lin(const float4* __restrict__ x0s, const float* __restrict__ dinv,
                          const int* __restrict__ rowptr, const int* __restrict__ col,
                          const float* __restrict__ W1, const float* __restrict__ b1, int N,
                          unsigned int* __restrict__ x1f8) {
  __shared__ float w0s[128], w1s[128], w2s[128], bsm[128];
  for (int t = threadIdx.x; t < 128; t += 256) {
    w0s[t] = W1[t];
    w1s[t] = W1[128 + t];
    w2s[t] = W1[256 + t];
    bsm[t] = b1[t];
  }
  __syncthreads();
  int n = blockIdx.x * 256 + threadIdx.x;
  if (n >= N) return;
  float4 a = x0s[n];
  int b = rowptr[n], en = rowptr[n + 1];
  int k = b;
  for (; k + 3 < en; k += 4) {
    int s0 = col[k], s1 = col[k + 1], s2 = col[k + 2], s3 = col[k + 3];
    float4 w0 = x0s[s0];
    float4 w1 = x0s[s1];
    float4 w2 = x0s[s2];
    float4 w3 = x0s[s3];
    a.x += (w0.x + w1.x) + (w2.x + w3.x);
    a.y += (w0.y + w1.y) + (w2.y + w3.y);
    a.z += (w0.z + w1.z) + (w2.z + w3.z);
  }
  for (; k < en; k++) {
    float4 w = x0s[col[k]];
    a.x += w.x; a.y += w.y; a.z += w.z;
  }
  float di = dinv[n];
  float ax = a.x * di, ay = a.y * di, az = a.z * di;
  unsigned int* orow = x1f8 + (size_t)n * 32;
#pragma unroll 8
  for (int f0 = 0; f0 < 128; f0 += 4) {
    float v0 = fmaxf(bsm[f0] + ax * w0s[f0] + ay * w1s[f0] + az * w2s[f0], 0.f) * di;
    float v1 = fmaxf(bsm[f0 + 1] + ax * w0s[f0 + 1] + ay * w1s[f0 + 1] + az * w2s[f0 + 1], 0.f) * di;
    float v2 = fmaxf(bsm[f0 + 2] + ax * w0s[f0 + 2] + ay * w1s[f0 + 2] + az * w2s[f0 + 2], 0.f) * di;
    float v3 = fmaxf(bsm[f0 + 3] + ax * w0s[f0 + 3] + ay * w1s[f0 + 3] + az * w2s[f0 + 3], 0.f) * di;
    orow[f0 >> 2] = pk4_fp8(v0, v1, v2, v3);
  }
}

// ---------------- GCN layer 2 aggregation: fp8 gather, 8 lanes/node x uint4 ----------------
__global__ void k_agg128(const unsigned int* __restrict__ x1f8, const float* __restrict__ dinv,
                         const int* __restrict__ rowptr, const int* __restrict__ col,
                         int N, unsigned short* __restrict__ xa) {
  int g = (int)((blockIdx.x * 256 + threadIdx.x) >> 3);
  int lane = threadIdx.x & 7;
  if (g >= N) return;
  const uint4* base = (const uint4*)x1f8 + lane;  // row stride = 8 uint4 (128 B)
  float acc[16];
#pragma unroll
  for (int i = 0; i < 16; i++) acc[i] = 0.f;
  uint4 self = base[(size_t)g * 8];
  acc4_fp8(self.x, acc); acc4_fp8(self.y, acc + 4);
  acc4_fp8(self.z, acc + 8); acc4_fp8(self.w, acc + 12);
  int b = rowptr[g], en = rowptr[g + 1];
  int k = b;
  for (; k + 3 < en; k += 4) {
    int s0 = col[k], s1 = col[k + 1], s2 = col[k + 2], s3 = col[k + 3];
    uint4 w0 = base[(size_t)s0 * 8];
    uint4 w1 = base[(size_t)s1 * 8];
    uint4 w2 = base[(size_t)s2 * 8];
    uint4 w3 = base[(size_t)s3 * 8];
    acc4_fp8(w0.x, acc); acc4_fp8(w0.y, acc + 4); acc4_fp8(w0.z, acc + 8); acc4_fp8(w0.w, acc + 12);
    acc4_fp8(w1.x, acc); acc4_fp8(w1.y, acc + 4); acc4_fp8(w1.z, acc + 8); acc4_fp8(w1.w, acc + 12);
    acc4_fp8(w2.x, acc); acc4_fp8(w2.y, acc + 4); acc4_fp8(w2.z, acc + 8); acc4_fp8(w2.w, acc + 12);
    acc4_fp8(w3.x, acc); acc4_fp8(w3.y, acc + 4); acc4_fp8(w3.z, acc + 8); acc4_fp8(w3.w, acc + 12);
  }
  for (; k < en; k++) {
    uint4 w = base[(size_t)col[k] * 8];
    acc4_fp8(w.x, acc); acc4_fp8(w.y, acc + 4); acc4_fp8(w.z, acc + 8); acc4_fp8(w.w, acc + 12);
  }
  float di = dinv[g];
  uint4 o1, o2;
  o1.x = pack2(acc[0] * di, acc[1] * di);
  o1.y = pack2(acc[2] * di, acc[3] * di);
  o1.z = pack2(acc[4] * di, acc[5] * di);
  o1.w = pack2(acc[6] * di, acc[7] * di);
  o2.x = pack2(acc[8] * di, acc[9] * di);
  o2.y = pack2(acc[10] * di, acc[11] * di);
  o2.z = pack2(acc[12] * di, acc[13] * di);
  o2.w = pack2(acc[14] * di, acc[15] * di);
  uint4* op = (uint4*)xa + (size_t)g * 16 + lane * 2;
  op[0] = o1;
  op[1] = o2;
}

// ---------------- layer 2 GEMM via MFMA, fused heads + colsum (x2 never stored) ----------
__global__ __launch_bounds__(256) void k_gemm2(const unsigned short* __restrict__ xab,
                                               const unsigned short* __restrict__ W2T,
                                               const float* __restrict__ b2,
                                               const float* __restrict__ Ws,
                                               const float* __restrict__ bs,
                                               const float* __restrict__ Wmu,
                                               const float* __restrict__ bmu,
                                               const float* __restrict__ Wls,
                                               const float* __restrict__ bls,
                                               int N, float* __restrict__ s_arr,
                                               float* __restrict__ out,
                                               float* __restrict__ partials) {
  __shared__ float w[640];
  __shared__ float cs[4][128];
  for (int t = threadIdx.x; t < 128; t += 256) {
    w[t] = Ws[t];
    w[128 + t] = Wmu[t * 2 + 0];
    w[256 + t] = Wmu[t * 2 + 1];
    w[384 + t] = Wls[t * 2 + 0];
    w[512 + t] = Wls[t * 2 + 1];
  }
  __syncthreads();
  int wv = threadIdx.x >> 6;
  int lane = threadIdx.x & 63;
  int l15 = lane & 15, lhi = lane >> 4;
  int rowbase = blockIdx.x * 64 + wv * 16;
  int arow = rowbase + l15;
  int arowc = min(arow, N - 1);
  const unsigned short* ap = xab + (size_t)arowc * HID + lhi * 8;
  bf16x8 a[4];
#pragma unroll
  for (int kk = 0; kk < 4; kk++) a[kk] = *(const bf16x8*)(ap + kk * 32);
  float cpart[8];
  float p0[4] = {0, 0, 0, 0}, p1[4] = {0, 0, 0, 0}, p2[4] = {0, 0, 0, 0};
  float p3[4] = {0, 0, 0, 0}, p4[4] = {0, 0, 0, 0};
#pragma unroll
  for (int ct = 0; ct < 8; ct++) {
    f32x4 acc = {0.f, 0.f, 0.f, 0.f};
    const unsigned short* bp = W2T + (size_t)(ct * 16 + l15) * HID + lhi * 8;
#pragma unroll
    for (int kk = 0; kk < 4; kk++) {
      bf16x8 bfr = *(const bf16x8*)(bp + kk * 32);
      acc = __builtin_amdgcn_mfma_f32_16x16x32_bf16(a[kk], bfr, acc, 0, 0, 0);
    }
    int cidx = ct * 16 + l15;
    float bias = b2[cidx];
    float ws_ = w[cidx];
    float wm0 = w[128 + cidx], wm1 = w[256 + cidx];
    float wl0 = w[384 + cidx], wl1 = w[512 + cidx];
    float cl = 0.f;
#pragma unroll
    for (int r = 0; r < 4; r++) {
      int node = rowbase + lhi * 4 + r;
      float o = fmaxf(acc[r] + bias, 0.f);
      if (node < N) cl += o;
      p0[r] += o * ws_;
      p1[r] += o * wm0;
      p2[r] += o * wm1;
      p3[r] += o * wl0;
      p4[r] += o * wl1;
    }
    cl += __shfl_xor(cl, 16);
    cl += __shfl_xor(cl, 32);
    cpart[ct] = cl;
  }
#pragma unroll
  for (int r = 0; r < 4; r++) {
#pragma unroll
    for (int m = 1; m < 16; m <<= 1) {
      p0[r] += __shfl_xor(p0[r], m);
      p1[r] += __shfl_xor(p1[r], m);
      p2[r] += __shfl_xor(p2[r], m);
      p3[r] += __shfl_xor(p3[r], m);
      p4[r] += __shfl_xor(p4[r], m);
    }
  }
  if (l15 == 0) {
#pragma unroll
    for (int r = 0; r < 4; r++) {
      int node = rowbase + lhi * 4 + r;
      if (node < N) {
        s_arr[node] = p0[r] + bs[0];
        out[(size_t)N + node * 2 + 0] = p1[r] + bmu[0];
        out[(size_t)N + node * 2 + 1] = p2[r] + bmu[1];
        out[(size_t)3 * N + node * 2 + 0] = fminf(fmaxf(p3[r] + bls[0], -4.f), 2.f);
        out[(size_t)3 * N + node * 2 + 1] = fminf(fmaxf(p4[r] + bls[1], -4.f), 2.f);
      }
    }
  }
  if (lane < 16) {
#pragma unroll
    for (int ct = 0; ct < 8; ct++) cs[wv][ct * 16 + lane] = cpart[ct];
  }
  __syncthreads();
  if (threadIdx.x < 128) {
    int f = threadIdx.x;
    partials[(size_t)blockIdx.x * 128 + f] = cs[0][f] + cs[1][f] + cs[2][f] + cs[3][f];
  }
}

// ---------------- merged: online-LSE partials (blocks 0..255) + colsum reduce (256..319) ----
__global__ void k_lse_colsum(const float* __restrict__ s, int N, float* __restrict__ pm,
                             float* __restrict__ pt, const float* __restrict__ partials,
                             int nblkG, float* __restrict__ colsum) {
  if (blockIdx.x >= 256) {
    int bb = blockIdx.x - 256;
    int f = threadIdx.x;
    if (f < 128) {
      float t = 0.f;
      for (int b = bb; b < nblkG; b += 64) t += partials[(size_t)b * 128 + f];
      atomicAdd(&colsum[f], t);
    }
    return;
  }
  __shared__ float smM[256], smT[256];
  float m = -1e30f, t = 0.f;
  for (int i = blockIdx.x * 256 + threadIdx.x; i < N; i += 256 * 256) {
    float v = s[i];
    if (v > m) { t = t * __expf(m - v) + 1.f; m = v; }
    else t += __expf(v - m);
  }
  smM[threadIdx.x] = m; smT[threadIdx.x] = t; __syncthreads();
  for (int st = 128; st > 0; st >>= 1) {
    if (threadIdx.x < st) {
      float m2 = smM[threadIdx.x + st], t2 = smT[threadIdx.x + st];
      float m1 = smM[threadIdx.x], t1 = smT[threadIdx.x];
      float M = fmaxf(m1, m2);
      smM[threadIdx.x] = M;
      smT[threadIdx.x] = t1 * __expf(m1 - M) + t2 * __expf(m2 - M);
    }
    __syncthreads();
  }
  if (threadIdx.x == 0) { pm[blockIdx.x] = smM[0]; pt[blockIdx.x] = smT[0]; }
}

// ---------------- merged: logits (inline LSE finish) + value head (last block) ----------
__global__ void k_logits_value(const float* __restrict__ sarr, const float* __restrict__ pm,
                               const float* __restrict__ pt, int N, float* __restrict__ out,
                               const float* __restrict__ colsum, const float* __restrict__ Wv1,
                               const float* __restrict__ bv1, const float* __restrict__ Wv2,
                               const float* __restrict__ bv2, int nblkN) {
  if ((int)blockIdx.x == nblkN) {
    __shared__ float hid[64];
    float invN = 1.0f / (float)N;
    int j = threadIdx.x;
    if (j < 64) {
      float a = bv1[j];
      for (int f = 0; f < 128; f++) a += (colsum[f] * invN) * Wv1[f * 64 + j];
      hid[j] = fmaxf(a, 0.f) * Wv2[j];
    }
    __syncthreads();
    if (threadIdx.x == 0) {
      float v = bv2[0];
      for (int jj = 0; jj < 64; jj++) v += hid[jj];
      out[(size_t)5 * N] = v;
    }
    return;
  }
  __shared__ float smM[256], smT[256];
  smM[threadIdx.x] = pm[threadIdx.x];
  smT[threadIdx.x] = pt[threadIdx.x];
  __syncthreads();
  for (int st = 128; st > 0; st >>= 1) {
    if (threadIdx.x < st) {
      float m2 = smM[threadIdx.x + st], t2 = smT[threadIdx.x + st];
      float m1 = smM[threadIdx.x], t1 = smT[threadIdx.x];
      float M = fmaxf(m1, m2);
      smM[threadIdx.x] = M;
      smT[threadIdx.x] = t1 * __expf(m1 - M) + t2 * __expf(m2 - M);
    }
    __syncthreads();
  }
  float lse = smM[0] + logf(smT[0]);
  int n = blockIdx.x * 256 + threadIdx.x;
  if (n < N) out[n] = sarr[n] - lse;
}

extern "C" void kernel_launch(void* const* d_in, const int* in_sizes, int n_in,
                              void* d_out, int out_size, void* d_ws, size_t ws_size,
                              hipStream_t stream) {
  const float* coords = (const float*)d_in[0];
  const int* ei = (const int*)d_in[1];
  const float* W1 = (const float*)d_in[2];
  const float* b1 = (const float*)d_in[3];
  const float* W2 = (const float*)d_in[4];
  const float* b2 = (const float*)d_in[5];
  const float* Wsw = (const float*)d_in[6];
  const float* bsw = (const float*)d_in[7];
  const float* Wmu = (const float*)d_in[8];
  const float* bmu = (const float*)d_in[9];
  const float* Wls = (const float*)d_in[10];
  const float* bls = (const float*)d_in[11];
  const float* Wv1 = (const float*)d_in[12];
  const float* bv1 = (const float*)d_in[13];
  const float* Wv2 = (const float*)d_in[14];
  const float* bv2 = (const float*)d_in[15];
  int N = in_sizes[0] / 2;
  int E = in_sizes[1] / 2;
  const int* src = ei;
  const int* dst = ei + E;
  float* outf = (float*)d_out;
  int NB = (N + 255) >> 8;
  int nblkG = (N + 63) / 64;
  int nblkN = (N + 255) / 256;

  char* base = (char*)d_ws;
  size_t off = 0;
  auto alloc = [&](size_t bytes) -> void* {
    void* r = base + off;
    off += (bytes + 255) & ~(size_t)255;
    return r;
  };
  size_t zero_start = off;
  int* hd_g = (int*)alloc((size_t)NB * 4);
  int* hs_g = (int*)alloc((size_t)NB * 4);
  float* colsum = (float*)alloc(128 * 4);
  size_t zero_bytes = off - zero_start;
  int* based = (int*)alloc(((size_t)NB + 1) * 4);
  int* bases = (int*)alloc(((size_t)NB + 1) * 4);
  int* curd = (int*)alloc((size_t)NB * 4);
  int* curs = (int*)alloc((size_t)NB * 4);
  int* bmax = (int*)alloc((size_t)NB * 4);
  int* rowptr = (int*)alloc(((size_t)N + 1) * 4);
  int* pairsp = (int*)alloc((size_t)E * 4);
  int* srcb = (int*)alloc((size_t)E * 4);
  int* colarr = (int*)alloc((size_t)E * 4);
  int* degsrc = (int*)alloc((size_t)N * 4);
  float* dinv = (float*)alloc((size_t)N * 4);
  float4* x0s = (float4*)alloc((size_t)N * 16);
  float* sarr = (float*)alloc((size_t)N * 4);
  float* pm = (float*)alloc(256 * 4);
  float* pt = (float*)alloc(256 * 4);
  unsigned short* W2T = (unsigned short*)alloc(128 * 128 * 2);
  float* partials = (float*)alloc((size_t)nblkG * 128 * 4);
  unsigned int* x1f8 = (unsigned int*)alloc((size_t)N * 128);      // fp8 e4m3, N x 128
  unsigned short* xab = (unsigned short*)alloc((size_t)N * HID * 2);
  if (off > ws_size) return;

  hipMemsetAsync(base + zero_start, 0, zero_bytes, stream);
  k_hist<<<256, 256, 0, stream>>>(src, dst, E, NB, hd_g, hs_g);
  k_scan_buckets<<<1, NBMAX, 0, stream>>>(hd_g, hs_g, NB, E, based, bases, curd, curs);
  k_bucket_scatter<<<512, 256, 0, stream>>>(src, dst, E, NB, curd, curs, pairsp, srcb);
  k_degcsr<<<NB, 256, 0, stream>>>(srcb, bases, pairsp, based, N, E, degsrc, bmax, rowptr, dinv,
                                   colarr);
  k_prepW<<<64, 256, 0, stream>>>(W2, W2T);
  k_node<<<nblkN, 256, 0, stream>>>(coords, degsrc, dinv, bmax, NB, N, x0s);
  k_agg3lin<<<nblkN, 256, 0, stream>>>(x0s, dinv, rowptr, colarr, W1, b1, N, x1f8);
  k_agg128<<<(N * 8 + 255) / 256, 256, 0, stream>>>(x1f8, dinv, rowptr, colarr, N, xab);
  k_gemm2<<<nblkG, 256, 0, stream>>>(xab, W2T, b2, Wsw, bsw, Wmu, bmu, Wls, bls, N, sarr, outf,
                                     partials);
  k_lse_colsum<<<320, 256, 0, stream>>>(sarr, N, pm, pt, partials, nblkG, colsum);
  k_logits_value<<<nblkN + 1, 256, 0, stream>>>(sarr, pm, pt, N, outf, colsum, Wv1, bv1, Wv2,
                                                bv2, nblkN);
}

// Round 7
// 183.154 us; speedup vs baseline: 3.1711x; 1.1079x over previous
//
#include <hip/hip_runtime.h>
#include <hip/hip_bf16.h>

#define HID 128
#define NB2MAX 128  // 1024-node buckets, N up to 131072

typedef __bf16 bf16x8 __attribute__((ext_vector_type(8)));
typedef float f32x4 __attribute__((ext_vector_type(4)));
typedef float f32x2 __attribute__((ext_vector_type(2)));

#if defined(__has_builtin)
#if __has_builtin(__builtin_amdgcn_cvt_pk_f32_fp8) && __has_builtin(__builtin_amdgcn_cvt_pk_fp8_f32)
#define HAVE_FP8_CVT 1
#endif
#endif
#ifndef HAVE_FP8_CVT
#define HAVE_FP8_CVT 0
#include <hip/hip_fp8.h>
#endif

__device__ __forceinline__ float b2f(unsigned int u) { return __uint_as_float(u << 16); }
__device__ __forceinline__ unsigned int f2b(float f) {
  unsigned int b = __float_as_uint(f);
  return (b + 0x7FFFu + ((b >> 16) & 1u)) >> 16;
}
__device__ __forceinline__ unsigned int pack2(float lo, float hi) {
  return f2b(lo) | (f2b(hi) << 16);
}

#if !HAVE_FP8_CVT
__device__ __forceinline__ float fp8dec(unsigned int u) {
  unsigned int e = (u >> 3) & 15, m = u & 7, sgn = (u >> 7) & 1;
  float v;
  if (e) v = __uint_as_float(((e + 120) << 23) | (m << 20));
  else v = (float)m * 0.001953125f;
  return sgn ? -v : v;
}
#endif

__device__ __forceinline__ unsigned int pk4_fp8(float v0, float v1, float v2, float v3) {
#if HAVE_FP8_CVT
  int pk = 0;
  pk = __builtin_amdgcn_cvt_pk_fp8_f32(v0, v1, pk, false);
  pk = __builtin_amdgcn_cvt_pk_fp8_f32(v2, v3, pk, true);
  return (unsigned int)pk;
#else
  __hip_fp8_e4m3 a(v0), b(v1), c(v2), d(v3);
  return (unsigned)a.__x | ((unsigned)b.__x << 8) | ((unsigned)c.__x << 16) |
         ((unsigned)d.__x << 24);
#endif
}

__device__ __forceinline__ void acc4_fp8(unsigned int u, float* a) {
#if HAVE_FP8_CVT
  f32x2 lo = __builtin_amdgcn_cvt_pk_f32_fp8((int)u, false);
  f32x2 hi = __builtin_amdgcn_cvt_pk_f32_fp8((int)u, true);
  a[0] += lo.x; a[1] += lo.y; a[2] += hi.x; a[3] += hi.y;
#else
  a[0] += fp8dec(u & 255); a[1] += fp8dec((u >> 8) & 255);
  a[2] += fp8dec((u >> 16) & 255); a[3] += fp8dec((u >> 24) & 255);
#endif
}

// ---------------- one-pass bucketed scatter into fixed-CAP regions ----------------
// pairsp[bD*CAP + off] = (s<<10)|(d&1023)   (dst-bucketed)
// srcb  [bS*CAP + off] = s&1023             (src-bucketed)
__global__ void k_scatter2(const int* __restrict__ src, const int* __restrict__ dst, int E,
                           int NB2, int CAP, int* __restrict__ curd, int* __restrict__ curs,
                           int* __restrict__ pairsp, int* __restrict__ srcb) {
  __shared__ int hd[NB2MAX], hs[NB2MAX], bd[NB2MAX], bs[NB2MAX];
  for (int i = threadIdx.x; i < NB2; i += 256) { hd[i] = 0; hs[i] = 0; }
  __syncthreads();
  int per = (E + gridDim.x - 1) / gridDim.x;
  int begin = blockIdx.x * per;
  int end = min(E, begin + per);
  for (int e = begin + threadIdx.x; e < end; e += 256) {
    atomicAdd(&hd[dst[e] >> 10], 1);
    atomicAdd(&hs[src[e] >> 10], 1);
  }
  __syncthreads();
  for (int i = threadIdx.x; i < NB2; i += 256) {
    bd[i] = hd[i] ? atomicAdd(&curd[i], hd[i]) : 0;
    bs[i] = hs[i] ? atomicAdd(&curs[i], hs[i]) : 0;
    hd[i] = 0; hs[i] = 0;
  }
  __syncthreads();
  for (int e = begin + threadIdx.x; e < end; e += 256) {
    int d = dst[e], s = src[e];
    int bD = d >> 10, bS = s >> 10;
    int offD = bd[bD] + atomicAdd(&hd[bD], 1);
    if (offD < CAP) pairsp[(size_t)bD * CAP + offD] = (s << 10) | (d & 1023);
    int offS = bs[bS] + atomicAdd(&hs[bS], 1);
    if (offS < CAP) srcb[(size_t)bS * CAP + offS] = s & 1023;
  }
}

// ---------------- per-bucket: out-degree (+bmax) AND CSR build (1024 thr/block) ----------
__global__ __launch_bounds__(1024) void k_degcsr(
    const int* __restrict__ srcb, const int* __restrict__ curs, const int* __restrict__ pairsp,
    const int* __restrict__ curd, int NB2, int CAP, int N, int* __restrict__ degsrc,
    int* __restrict__ bmax, int2* __restrict__ rowptr2, float* __restrict__ dinv,
    int* __restrict__ colarr) {
  __shared__ int cnt[1024], scn[1024], cur[1024];
  int b = blockIdx.x, tid = threadIdx.x;
  int g = (b << 10) + tid;
  int lo = b * CAP;
  // phase A: out-degree from srcb bucket b
  cnt[tid] = 0; __syncthreads();
  int szS = min(curs[b], CAP);
  const int* sb = srcb + (size_t)lo;
  for (int k = tid; k < szS; k += 1024) atomicAdd(&cnt[sb[k]], 1);
  __syncthreads();
  int c = cnt[tid];
  if (g < N) degsrc[g] = c;
  scn[tid] = (g < N) ? c : 0; __syncthreads();
  for (int s = 512; s > 0; s >>= 1) {
    if (tid < s) scn[tid] = max(scn[tid], scn[tid + s]);
    __syncthreads();
  }
  if (tid == 0) bmax[b] = scn[0];
  __syncthreads();
  // phase B: in-degree count + scan + cursor scatter of colarr
  cnt[tid] = 0; __syncthreads();
  int szD = min(curd[b], CAP);
  const int* pb = pairsp + (size_t)lo;
  for (int k = tid; k < szD; k += 1024) atomicAdd(&cnt[pb[k] & 1023], 1);
  __syncthreads();
  c = cnt[tid];
  scn[tid] = c; __syncthreads();
  for (int st = 1; st < 1024; st <<= 1) {
    int t = (tid >= st) ? scn[tid - st] : 0;
    __syncthreads();
    scn[tid] += t;
    __syncthreads();
  }
  int excl = scn[tid] - c;
  if (g < N) {
    rowptr2[g] = make_int2(lo + excl, lo + excl + c);
    dinv[g] = rsqrtf((float)(c + 1));
  }
  cur[tid] = lo + excl;
  __syncthreads();
  for (int k = tid; k < szD; k += 1024) {
    int p = pb[k];
    int pos = atomicAdd(&cur[p & 1023], 1);
    colarr[pos] = ((unsigned)p) >> 10;
  }
}

// ---------------- W2 -> bf16 transposed [j][k] ----------------
__global__ void k_prepW(const float* __restrict__ W2, unsigned short* __restrict__ W2T) {
  int idx = blockIdx.x * 256 + threadIdx.x;
  if (idx >= 128 * 128) return;
  int j = idx >> 7, k = idx & 127;
  W2T[j * 128 + k] = (unsigned short)f2b(W2[k * 128 + j]);
}

// node features prescaled by own dinv (inline global bmax reduction over NB2<=128)
__global__ void k_node(const float* __restrict__ coords, const int* __restrict__ degsrc,
                       const float* __restrict__ dinv, const int* __restrict__ bmax, int NB2,
                       int N, float4* __restrict__ x0s) {
  __shared__ int sm[128];
  int tid = threadIdx.x;
  if (tid < 128) sm[tid] = (tid < NB2) ? bmax[tid] : 0;
  __syncthreads();
  if (tid < 64) { sm[tid] = max(sm[tid], sm[tid + 64]); }
  __syncthreads();
  if (tid < 32) { sm[tid] = max(sm[tid], sm[tid + 32]); }
  __syncthreads();
  if (tid < 16) { sm[tid] = max(sm[tid], sm[tid + 16]); }
  __syncthreads();
  if (tid < 8) { sm[tid] = max(sm[tid], sm[tid + 8]); }
  __syncthreads();
  if (tid < 4) { sm[tid] = max(sm[tid], sm[tid + 4]); }
  __syncthreads();
  if (tid < 2) { sm[tid] = max(sm[tid], sm[tid + 2]); }
  __syncthreads();
  if (tid == 0) sm[0] = max(sm[0], sm[1]);
  __syncthreads();
  float inv = 1.0f / (float)max(sm[0], 1);
  int n = blockIdx.x * 256 + tid;
  if (n >= N) return;
  float di = dinv[n];
  float4 v;
  v.x = coords[n * 2 + 0] * di;
  v.y = coords[n * 2 + 1] * di;
  v.z = (float)degsrc[n] * inv * di;
  v.w = 0.f;
  x0s[n] = v;
}

// ---------------- fused layer-1: aggregate 3 feats + linear + relu + prescale -> fp8 ----
__global__ void k_agg3lin(const float4* __restrict__ x0s, const float* __restrict__ dinv,
                          const int2* __restrict__ rowptr2, const int* __restrict__ col,
                          const float* __restrict__ W1, const float* __restrict__ b1, int N,
                          unsigned int* __restrict__ x1f8) {
  __shared__ float w0s[128], w1s[128], w2s[128], bsm[128];
  for (int t = threadIdx.x; t < 128; t += 256) {
    w0s[t] = W1[t];
    w1s[t] = W1[128 + t];
    w2s[t] = W1[256 + t];
    bsm[t] = b1[t];
  }
  __syncthreads();
  int n = blockIdx.x * 256 + threadIdx.x;
  if (n >= N) return;
  float4 a = x0s[n];
  int2 rp = rowptr2[n];
  int k = rp.x, en = rp.y;
  for (; k + 3 < en; k += 4) {
    int s0 = col[k], s1 = col[k + 1], s2 = col[k + 2], s3 = col[k + 3];
    float4 w0 = x0s[s0];
    float4 w1 = x0s[s1];
    float4 w2 = x0s[s2];
    float4 w3 = x0s[s3];
    a.x += (w0.x + w1.x) + (w2.x + w3.x);
    a.y += (w0.y + w1.y) + (w2.y + w3.y);
    a.z += (w0.z + w1.z) + (w2.z + w3.z);
  }
  for (; k < en; k++) {
    float4 w = x0s[col[k]];
    a.x += w.x; a.y += w.y; a.z += w.z;
  }
  float di = dinv[n];
  float ax = a.x * di, ay = a.y * di, az = a.z * di;
  unsigned int* orow = x1f8 + (size_t)n * 32;
#pragma unroll 8
  for (int f0 = 0; f0 < 128; f0 += 4) {
    float v0 = fmaxf(bsm[f0] + ax * w0s[f0] + ay * w1s[f0] + az * w2s[f0], 0.f) * di;
    float v1 = fmaxf(bsm[f0 + 1] + ax * w0s[f0 + 1] + ay * w1s[f0 + 1] + az * w2s[f0 + 1], 0.f) * di;
    float v2 = fmaxf(bsm[f0 + 2] + ax * w0s[f0 + 2] + ay * w1s[f0 + 2] + az * w2s[f0 + 2], 0.f) * di;
    float v3 = fmaxf(bsm[f0 + 3] + ax * w0s[f0 + 3] + ay * w1s[f0 + 3] + az * w2s[f0 + 3], 0.f) * di;
    orow[f0 >> 2] = pk4_fp8(v0, v1, v2, v3);
  }
}

// ---------------- GCN layer 2 aggregation: fp8 gather, 8 lanes/node x uint4 ----------------
__global__ void k_agg128(const unsigned int* __restrict__ x1f8, const float* __restrict__ dinv,
                         const int2* __restrict__ rowptr2, const int* __restrict__ col,
                         int N, unsigned short* __restrict__ xa) {
  int g = (int)((blockIdx.x * 256 + threadIdx.x) >> 3);
  int lane = threadIdx.x & 7;
  if (g >= N) return;
  const uint4* base = (const uint4*)x1f8 + lane;  // row stride = 8 uint4 (128 B)
  float acc[16];
#pragma unroll
  for (int i = 0; i < 16; i++) acc[i] = 0.f;
  uint4 self = base[(size_t)g * 8];
  acc4_fp8(self.x, acc); acc4_fp8(self.y, acc + 4);
  acc4_fp8(self.z, acc + 8); acc4_fp8(self.w, acc + 12);
  int2 rp = rowptr2[g];
  int k = rp.x, en = rp.y;
  for (; k + 3 < en; k += 4) {
    int s0 = col[k], s1 = col[k + 1], s2 = col[k + 2], s3 = col[k + 3];
    uint4 w0 = base[(size_t)s0 * 8];
    uint4 w1 = base[(size_t)s1 * 8];
    uint4 w2 = base[(size_t)s2 * 8];
    uint4 w3 = base[(size_t)s3 * 8];
    acc4_fp8(w0.x, acc); acc4_fp8(w0.y, acc + 4); acc4_fp8(w0.z, acc + 8); acc4_fp8(w0.w, acc + 12);
    acc4_fp8(w1.x, acc); acc4_fp8(w1.y, acc + 4); acc4_fp8(w1.z, acc + 8); acc4_fp8(w1.w, acc + 12);
    acc4_fp8(w2.x, acc); acc4_fp8(w2.y, acc + 4); acc4_fp8(w2.z, acc + 8); acc4_fp8(w2.w, acc + 12);
    acc4_fp8(w3.x, acc); acc4_fp8(w3.y, acc + 4); acc4_fp8(w3.z, acc + 8); acc4_fp8(w3.w, acc + 12);
  }
  for (; k < en; k++) {
    uint4 w = base[(size_t)col[k] * 8];
    acc4_fp8(w.x, acc); acc4_fp8(w.y, acc + 4); acc4_fp8(w.z, acc + 8); acc4_fp8(w.w, acc + 12);
  }
  float di = dinv[g];
  uint4 o1, o2;
  o1.x = pack2(acc[0] * di, acc[1] * di);
  o1.y = pack2(acc[2] * di, acc[3] * di);
  o1.z = pack2(acc[4] * di, acc[5] * di);
  o1.w = pack2(acc[6] * di, acc[7] * di);
  o2.x = pack2(acc[8] * di, acc[9] * di);
  o2.y = pack2(acc[10] * di, acc[11] * di);
  o2.z = pack2(acc[12] * di, acc[13] * di);
  o2.w = pack2(acc[14] * di, acc[15] * di);
  uint4* op = (uint4*)xa + (size_t)g * 16 + lane * 2;
  op[0] = o1;
  op[1] = o2;
}

// ---------------- layer 2 GEMM via MFMA, fused heads + colsum (x2 never stored) ----------
__global__ __launch_bounds__(256) void k_gemm2(const unsigned short* __restrict__ xab,
                                               const unsigned short* __restrict__ W2T,
                                               const float* __restrict__ b2,
                                               const float* __restrict__ Ws,
                                               const float* __restrict__ bs,
                                               const float* __restrict__ Wmu,
                                               const float* __restrict__ bmu,
                                               const float* __restrict__ Wls,
                                               const float* __restrict__ bls,
                                               int N, float* __restrict__ s_arr,
                                               float* __restrict__ out,
                                               float* __restrict__ partials) {
  __shared__ float w[640];
  __shared__ float cs[4][128];
  for (int t = threadIdx.x; t < 128; t += 256) {
    w[t] = Ws[t];
    w[128 + t] = Wmu[t * 2 + 0];
    w[256 + t] = Wmu[t * 2 + 1];
    w[384 + t] = Wls[t * 2 + 0];
    w[512 + t] = Wls[t * 2 + 1];
  }
  __syncthreads();
  int wv = threadIdx.x >> 6;
  int lane = threadIdx.x & 63;
  int l15 = lane & 15, lhi = lane >> 4;
  int rowbase = blockIdx.x * 64 + wv * 16;
  int arow = rowbase + l15;
  int arowc = min(arow, N - 1);
  const unsigned short* ap = xab + (size_t)arowc * HID + lhi * 8;
  bf16x8 a[4];
#pragma unroll
  for (int kk = 0; kk < 4; kk++) a[kk] = *(const bf16x8*)(ap + kk * 32);
  float cpart[8];
  float p0[4] = {0, 0, 0, 0}, p1[4] = {0, 0, 0, 0}, p2[4] = {0, 0, 0, 0};
  float p3[4] = {0, 0, 0, 0}, p4[4] = {0, 0, 0, 0};
#pragma unroll
  for (int ct = 0; ct < 8; ct++) {
    f32x4 acc = {0.f, 0.f, 0.f, 0.f};
    const unsigned short* bp = W2T + (size_t)(ct * 16 + l15) * HID + lhi * 8;
#pragma unroll
    for (int kk = 0; kk < 4; kk++) {
      bf16x8 bfr = *(const bf16x8*)(bp + kk * 32);
      acc = __builtin_amdgcn_mfma_f32_16x16x32_bf16(a[kk], bfr, acc, 0, 0, 0);
    }
    int cidx = ct * 16 + l15;
    float bias = b2[cidx];
    float ws_ = w[cidx];
    float wm0 = w[128 + cidx], wm1 = w[256 + cidx];
    float wl0 = w[384 + cidx], wl1 = w[512 + cidx];
    float cl = 0.f;
#pragma unroll
    for (int r = 0; r < 4; r++) {
      int node = rowbase + lhi * 4 + r;
      float o = fmaxf(acc[r] + bias, 0.f);
      if (node < N) cl += o;
      p0[r] += o * ws_;
      p1[r] += o * wm0;
      p2[r] += o * wm1;
      p3[r] += o * wl0;
      p4[r] += o * wl1;
    }
    cl += __shfl_xor(cl, 16);
    cl += __shfl_xor(cl, 32);
    cpart[ct] = cl;
  }
#pragma unroll
  for (int r = 0; r < 4; r++) {
#pragma unroll
    for (int m = 1; m < 16; m <<= 1) {
      p0[r] += __shfl_xor(p0[r], m);
      p1[r] += __shfl_xor(p1[r], m);
      p2[r] += __shfl_xor(p2[r], m);
      p3[r] += __shfl_xor(p3[r], m);
      p4[r] += __shfl_xor(p4[r], m);
    }
  }
  if (l15 == 0) {
#pragma unroll
    for (int r = 0; r < 4; r++) {
      int node = rowbase + lhi * 4 + r;
      if (node < N) {
        s_arr[node] = p0[r] + bs[0];
        out[(size_t)N + node * 2 + 0] = p1[r] + bmu[0];
        out[(size_t)N + node * 2 + 1] = p2[r] + bmu[1];
        out[(size_t)3 * N + node * 2 + 0] = fminf(fmaxf(p3[r] + bls[0], -4.f), 2.f);
        out[(size_t)3 * N + node * 2 + 1] = fminf(fmaxf(p4[r] + bls[1], -4.f), 2.f);
      }
    }
  }
  if (lane < 16) {
#pragma unroll
    for (int ct = 0; ct < 8; ct++) cs[wv][ct * 16 + lane] = cpart[ct];
  }
  __syncthreads();
  if (threadIdx.x < 128) {
    int f = threadIdx.x;
    partials[(size_t)blockIdx.x * 128 + f] = cs[0][f] + cs[1][f] + cs[2][f] + cs[3][f];
  }
}

// ---------------- merged: online-LSE partials (blocks 0..255) + colsum reduce (256..319) ----
__global__ void k_lse_colsum(const float* __restrict__ s, int N, float* __restrict__ pm,
                             float* __restrict__ pt, const float* __restrict__ partials,
                             int nblkG, float* __restrict__ colsum) {
  if (blockIdx.x >= 256) {
    int bb = blockIdx.x - 256;
    int f = threadIdx.x;
    if (f < 128) {
      float t = 0.f;
      for (int b = bb; b < nblkG; b += 64) t += partials[(size_t)b * 128 + f];
      atomicAdd(&colsum[f], t);
    }
    return;
  }
  __shared__ float smM[256], smT[256];
  float m = -1e30f, t = 0.f;
  for (int i = blockIdx.x * 256 + threadIdx.x; i < N; i += 256 * 256) {
    float v = s[i];
    if (v > m) { t = t * __expf(m - v) + 1.f; m = v; }
    else t += __expf(v - m);
  }
  smM[threadIdx.x] = m; smT[threadIdx.x] = t; __syncthreads();
  for (int st = 128; st > 0; st >>= 1) {
    if (threadIdx.x < st) {
      float m2 = smM[threadIdx.x + st], t2 = smT[threadIdx.x + st];
      float m1 = smM[threadIdx.x], t1 = smT[threadIdx.x];
      float M = fmaxf(m1, m2);
      smM[threadIdx.x] = M;
      smT[threadIdx.x] = t1 * __expf(m1 - M) + t2 * __expf(m2 - M);
    }
    __syncthreads();
  }
  if (threadIdx.x == 0) { pm[blockIdx.x] = smM[0]; pt[blockIdx.x] = smT[0]; }
}

// ---------------- merged: logits (inline LSE finish) + value head (last block) ----------
__global__ void k_logits_value(const float* __restrict__ sarr, const float* __restrict__ pm,
                               const float* __restrict__ pt, int N, float* __restrict__ out,
                               const float* __restrict__ colsum, const float* __restrict__ Wv1,
                               const float* __restrict__ bv1, const float* __restrict__ Wv2,
                               const float* __restrict__ bv2, int nblkN) {
  if ((int)blockIdx.x == nblkN) {
    __shared__ float hid[64];
    float invN = 1.0f / (float)N;
    int j = threadIdx.x;
    if (j < 64) {
      float a = bv1[j];
      for (int f = 0; f < 128; f++) a += (colsum[f] * invN) * Wv1[f * 64 + j];
      hid[j] = fmaxf(a, 0.f) * Wv2[j];
    }
    __syncthreads();
    if (threadIdx.x == 0) {
      float v = bv2[0];
      for (int jj = 0; jj < 64; jj++) v += hid[jj];
      out[(size_t)5 * N] = v;
    }
    return;
  }
  __shared__ float smM[256], smT[256];
  smM[threadIdx.x] = pm[threadIdx.x];
  smT[threadIdx.x] = pt[threadIdx.x];
  __syncthreads();
  for (int st = 128; st > 0; st >>= 1) {
    if (threadIdx.x < st) {
      float m2 = smM[threadIdx.x + st], t2 = smT[threadIdx.x + st];
      float m1 = smM[threadIdx.x], t1 = smT[threadIdx.x];
      float M = fmaxf(m1, m2);
      smM[threadIdx.x] = M;
      smT[threadIdx.x] = t1 * __expf(m1 - M) + t2 * __expf(m2 - M);
    }
    __syncthreads();
  }
  float lse = smM[0] + logf(smT[0]);
  int n = blockIdx.x * 256 + threadIdx.x;
  if (n < N) out[n] = sarr[n] - lse;
}

extern "C" void kernel_launch(void* const* d_in, const int* in_sizes, int n_in,
                              void* d_out, int out_size, void* d_ws, size_t ws_size,
                              hipStream_t stream) {
  const float* coords = (const float*)d_in[0];
  const int* ei = (const int*)d_in[1];
  const float* W1 = (const float*)d_in[2];
  const float* b1 = (const float*)d_in[3];
  const float* W2 = (const float*)d_in[4];
  const float* b2 = (const float*)d_in[5];
  const float* Wsw = (const float*)d_in[6];
  const float* bsw = (const float*)d_in[7];
  const float* Wmu = (const float*)d_in[8];
  const float* bmu = (const float*)d_in[9];
  const float* Wls = (const float*)d_in[10];
  const float* bls = (const float*)d_in[11];
  const float* Wv1 = (const float*)d_in[12];
  const float* bv1 = (const float*)d_in[13];
  const float* Wv2 = (const float*)d_in[14];
  const float* bv2 = (const float*)d_in[15];
  int N = in_sizes[0] / 2;
  int E = in_sizes[1] / 2;
  const int* src = ei;
  const int* dst = ei + E;
  float* outf = (float*)d_out;
  int NB2 = (N + 1023) >> 10;
  int CAP = ((E / NB2) * 5 / 4 + 1024 + 255) & ~255;
  int nblkG = (N + 63) / 64;
  int nblkN = (N + 255) / 256;

  char* base = (char*)d_ws;
  size_t off = 0;
  auto alloc = [&](size_t bytes) -> void* {
    void* r = base + off;
    off += (bytes + 255) & ~(size_t)255;
    return r;
  };
  size_t zero_start = off;
  int* curd = (int*)alloc((size_t)NB2 * 4);
  int* curs = (int*)alloc((size_t)NB2 * 4);
  float* colsum = (float*)alloc(128 * 4);
  size_t zero_bytes = off - zero_start;
  int* bmax = (int*)alloc((size_t)NB2 * 4);
  int2* rowptr2 = (int2*)alloc((size_t)N * 8);
  int* pairsp = (int*)alloc((size_t)NB2 * CAP * 4);
  int* srcb = (int*)alloc((size_t)NB2 * CAP * 4);
  int* colarr = (int*)alloc((size_t)NB2 * CAP * 4);
  int* degsrc = (int*)alloc((size_t)N * 4);
  float* dinv = (float*)alloc((size_t)N * 4);
  float4* x0s = (float4*)alloc((size_t)N * 16);
  float* sarr = (float*)alloc((size_t)N * 4);
  float* pm = (float*)alloc(256 * 4);
  float* pt = (float*)alloc(256 * 4);
  unsigned short* W2T = (unsigned short*)alloc(128 * 128 * 2);
  float* partials = (float*)alloc((size_t)nblkG * 128 * 4);
  unsigned int* x1f8 = (unsigned int*)alloc((size_t)N * 128);      // fp8 e4m3, N x 128
  unsigned short* xab = (unsigned short*)alloc((size_t)N * HID * 2);
  if (off > ws_size) return;

  hipMemsetAsync(base + zero_start, 0, zero_bytes, stream);
  k_scatter2<<<1024, 256, 0, stream>>>(src, dst, E, NB2, CAP, curd, curs, pairsp, srcb);
  k_degcsr<<<NB2, 1024, 0, stream>>>(srcb, curs, pairsp, curd, NB2, CAP, N, degsrc, bmax,
                                     rowptr2, dinv, colarr);
  k_prepW<<<64, 256, 0, stream>>>(W2, W2T);
  k_node<<<nblkN, 256, 0, stream>>>(coords, degsrc, dinv, bmax, NB2, N, x0s);
  k_agg3lin<<<nblkN, 256, 0, stream>>>(x0s, dinv, rowptr2, colarr, W1, b1, N, x1f8);
  k_agg128<<<(N * 8 + 255) / 256, 256, 0, stream>>>(x1f8, dinv, rowptr2, colarr, N, xab);
  k_gemm2<<<nblkG, 256, 0, stream>>>(xab, W2T, b2, Wsw, bsw, Wmu, bmu, Wls, bls, N, sarr, outf,
                                     partials);
  k_lse_colsum<<<320, 256, 0, stream>>>(sarr, N, pm, pt, partials, nblkG, colsum);
  k_logits_value<<<nblkN + 1, 256, 0, stream>>>(sarr, pm, pt, N, outf, colsum, Wv1, bv1, Wv2,
                                                bv2, nblkN);
}

// Round 8
// 171.055 us; speedup vs baseline: 3.3954x; 1.0707x over previous
//
#include <hip/hip_runtime.h>
#include <hip/hip_bf16.h>

#define HID 128
#define NB2MAX 128  // 1024-node buckets, N up to 131072

typedef __bf16 bf16x8 __attribute__((ext_vector_type(8)));
typedef float f32x4 __attribute__((ext_vector_type(4)));
typedef float f32x2 __attribute__((ext_vector_type(2)));

#if defined(__has_builtin)
#if __has_builtin(__builtin_amdgcn_cvt_pk_f32_fp8) && __has_builtin(__builtin_amdgcn_cvt_pk_fp8_f32)
#define HAVE_FP8_CVT 1
#endif
#endif
#ifndef HAVE_FP8_CVT
#define HAVE_FP8_CVT 0
#include <hip/hip_fp8.h>
#endif

__device__ __forceinline__ float b2f(unsigned int u) { return __uint_as_float(u << 16); }
__device__ __forceinline__ unsigned int f2b(float f) {
  unsigned int b = __float_as_uint(f);
  return (b + 0x7FFFu + ((b >> 16) & 1u)) >> 16;
}
__device__ __forceinline__ unsigned int pack2(float lo, float hi) {
  return f2b(lo) | (f2b(hi) << 16);
}

#if !HAVE_FP8_CVT
__device__ __forceinline__ float fp8dec(unsigned int u) {
  unsigned int e = (u >> 3) & 15, m = u & 7, sgn = (u >> 7) & 1;
  float v;
  if (e) v = __uint_as_float(((e + 120) << 23) | (m << 20));
  else v = (float)m * 0.001953125f;
  return sgn ? -v : v;
}
#endif

__device__ __forceinline__ unsigned int pk4_fp8(float v0, float v1, float v2, float v3) {
#if HAVE_FP8_CVT
  int pk = 0;
  pk = __builtin_amdgcn_cvt_pk_fp8_f32(v0, v1, pk, false);
  pk = __builtin_amdgcn_cvt_pk_fp8_f32(v2, v3, pk, true);
  return (unsigned int)pk;
#else
  __hip_fp8_e4m3 a(v0), b(v1), c(v2), d(v3);
  return (unsigned)a.__x | ((unsigned)b.__x << 8) | ((unsigned)c.__x << 16) |
         ((unsigned)d.__x << 24);
#endif
}

__device__ __forceinline__ void acc4_fp8(unsigned int u, float* a) {
#if HAVE_FP8_CVT
  f32x2 lo = __builtin_amdgcn_cvt_pk_f32_fp8((int)u, false);
  f32x2 hi = __builtin_amdgcn_cvt_pk_f32_fp8((int)u, true);
  a[0] += lo.x; a[1] += lo.y; a[2] += hi.x; a[3] += hi.y;
#else
  a[0] += fp8dec(u & 255); a[1] += fp8dec((u >> 8) & 255);
  a[2] += fp8dec((u >> 16) & 255); a[3] += fp8dec((u >> 24) & 255);
#endif
}

// ---------------- one-pass bucketed scatter into fixed-CAP regions ----------------
// pairsp[bD*CAP + off] = (s<<10)|(d&1023)   (dst-bucketed, 32-bit)
// srcb  [bS*CAP + off] = s&1023             (src-bucketed, 16-bit)
__global__ void k_scatter2(const int* __restrict__ src, const int* __restrict__ dst, int E,
                           int NB2, int CAP, int* __restrict__ curd, int* __restrict__ curs,
                           int* __restrict__ pairsp, unsigned short* __restrict__ srcb) {
  __shared__ int hd[NB2MAX], hs[NB2MAX], bd[NB2MAX], bs[NB2MAX];
  for (int i = threadIdx.x; i < NB2; i += 256) { hd[i] = 0; hs[i] = 0; }
  __syncthreads();
  int per = (E + gridDim.x - 1) / gridDim.x;
  int begin = blockIdx.x * per;
  int end = min(E, begin + per);
  for (int e = begin + threadIdx.x; e < end; e += 256) {
    atomicAdd(&hd[dst[e] >> 10], 1);
    atomicAdd(&hs[src[e] >> 10], 1);
  }
  __syncthreads();
  for (int i = threadIdx.x; i < NB2; i += 256) {
    bd[i] = hd[i] ? atomicAdd(&curd[i], hd[i]) : 0;
    bs[i] = hs[i] ? atomicAdd(&curs[i], hs[i]) : 0;
    hd[i] = 0; hs[i] = 0;
  }
  __syncthreads();
  for (int e = begin + threadIdx.x; e < end; e += 256) {
    int d = dst[e], s = src[e];
    int bD = d >> 10, bS = s >> 10;
    int offD = bd[bD] + atomicAdd(&hd[bD], 1);
    if (offD < CAP) pairsp[(size_t)bD * CAP + offD] = (s << 10) | (d & 1023);
    int offS = bs[bS] + atomicAdd(&hs[bS], 1);
    if (offS < CAP) srcb[(size_t)bS * CAP + offS] = (unsigned short)(s & 1023);
  }
}

// ---------------- per-bucket: out-degree (+bmax) AND CSR build (1024 thr/block) ----------
__global__ __launch_bounds__(1024) void k_degcsr(
    const unsigned short* __restrict__ srcb, const int* __restrict__ curs,
    const int* __restrict__ pairsp, const int* __restrict__ curd, int NB2, int CAP, int N,
    int* __restrict__ degsrc, int* __restrict__ bmax, int2* __restrict__ rowptr2,
    float* __restrict__ dinv, int* __restrict__ colarr) {
  __shared__ int cnt[1024], scn[1024], cur[1024];
  int b = blockIdx.x, tid = threadIdx.x;
  int g = (b << 10) + tid;
  int lo = b * CAP;
  // phase A: out-degree from srcb bucket b
  cnt[tid] = 0; __syncthreads();
  int szS = min(curs[b], CAP);
  const unsigned short* sb = srcb + (size_t)lo;
  for (int k = tid; k < szS; k += 1024) atomicAdd(&cnt[sb[k]], 1);
  __syncthreads();
  int c = cnt[tid];
  if (g < N) degsrc[g] = c;
  scn[tid] = (g < N) ? c : 0; __syncthreads();
  for (int s = 512; s > 0; s >>= 1) {
    if (tid < s) scn[tid] = max(scn[tid], scn[tid + s]);
    __syncthreads();
  }
  if (tid == 0) bmax[b] = scn[0];
  __syncthreads();
  // phase B: in-degree count + scan + cursor scatter of colarr
  cnt[tid] = 0; __syncthreads();
  int szD = min(curd[b], CAP);
  const int* pb = pairsp + (size_t)lo;
  for (int k = tid; k < szD; k += 1024) atomicAdd(&cnt[pb[k] & 1023], 1);
  __syncthreads();
  c = cnt[tid];
  scn[tid] = c; __syncthreads();
  for (int st = 1; st < 1024; st <<= 1) {
    int t = (tid >= st) ? scn[tid - st] : 0;
    __syncthreads();
    scn[tid] += t;
    __syncthreads();
  }
  int excl = scn[tid] - c;
  if (g < N) {
    rowptr2[g] = make_int2(lo + excl, lo + excl + c);
    dinv[g] = rsqrtf((float)(c + 1));
  }
  cur[tid] = lo + excl;
  __syncthreads();
  for (int k = tid; k < szD; k += 1024) {
    int p = pb[k];
    int pos = atomicAdd(&cur[p & 1023], 1);
    colarr[pos] = ((unsigned)p) >> 10;
  }
}

// ---------------- W2 -> bf16 transposed [j][k] ----------------
__global__ void k_prepW(const float* __restrict__ W2, unsigned short* __restrict__ W2T) {
  int idx = blockIdx.x * 256 + threadIdx.x;
  if (idx >= 128 * 128) return;
  int j = idx >> 7, k = idx & 127;
  W2T[j * 128 + k] = (unsigned short)f2b(W2[k * 128 + j]);
}

// node features prescaled by own dinv (inline global bmax reduction over NB2<=128)
__global__ void k_node(const float* __restrict__ coords, const int* __restrict__ degsrc,
                       const float* __restrict__ dinv, const int* __restrict__ bmax, int NB2,
                       int N, float4* __restrict__ x0s) {
  __shared__ int sm[128];
  int tid = threadIdx.x;
  if (tid < 128) sm[tid] = (tid < NB2) ? bmax[tid] : 0;
  __syncthreads();
  if (tid < 64) { sm[tid] = max(sm[tid], sm[tid + 64]); }
  __syncthreads();
  if (tid < 32) { sm[tid] = max(sm[tid], sm[tid + 32]); }
  __syncthreads();
  if (tid < 16) { sm[tid] = max(sm[tid], sm[tid + 16]); }
  __syncthreads();
  if (tid < 8) { sm[tid] = max(sm[tid], sm[tid + 8]); }
  __syncthreads();
  if (tid < 4) { sm[tid] = max(sm[tid], sm[tid + 4]); }
  __syncthreads();
  if (tid < 2) { sm[tid] = max(sm[tid], sm[tid + 2]); }
  __syncthreads();
  if (tid == 0) sm[0] = max(sm[0], sm[1]);
  __syncthreads();
  float inv = 1.0f / (float)max(sm[0], 1);
  int n = blockIdx.x * 256 + tid;
  if (n >= N) return;
  float di = dinv[n];
  float4 v;
  v.x = coords[n * 2 + 0] * di;
  v.y = coords[n * 2 + 1] * di;
  v.z = (float)degsrc[n] * inv * di;
  v.w = 0.f;
  x0s[n] = v;
}

// ---------------- fused layer-1: aggregate 3 feats + linear + relu + prescale -> fp8 ----
__global__ void k_agg3lin(const float4* __restrict__ x0s, const float* __restrict__ dinv,
                          const int2* __restrict__ rowptr2, const int* __restrict__ col,
                          const float* __restrict__ W1, const float* __restrict__ b1, int N,
                          unsigned int* __restrict__ x1f8) {
  __shared__ float w0s[128], w1s[128], w2s[128], bsm[128];
  for (int t = threadIdx.x; t < 128; t += 256) {
    w0s[t] = W1[t];
    w1s[t] = W1[128 + t];
    w2s[t] = W1[256 + t];
    bsm[t] = b1[t];
  }
  __syncthreads();
  int n = blockIdx.x * 256 + threadIdx.x;
  if (n >= N) return;
  float4 a = x0s[n];
  int2 rp = rowptr2[n];
  int k = rp.x, en = rp.y;
  for (; k + 3 < en; k += 4) {
    int s0 = col[k], s1 = col[k + 1], s2 = col[k + 2], s3 = col[k + 3];
    float4 w0 = x0s[s0];
    float4 w1 = x0s[s1];
    float4 w2 = x0s[s2];
    float4 w3 = x0s[s3];
    a.x += (w0.x + w1.x) + (w2.x + w3.x);
    a.y += (w0.y + w1.y) + (w2.y + w3.y);
    a.z += (w0.z + w1.z) + (w2.z + w3.z);
  }
  for (; k < en; k++) {
    float4 w = x0s[col[k]];
    a.x += w.x; a.y += w.y; a.z += w.z;
  }
  float di = dinv[n];
  float ax = a.x * di, ay = a.y * di, az = a.z * di;
  unsigned int* orow = x1f8 + (size_t)n * 32;
#pragma unroll 8
  for (int f0 = 0; f0 < 128; f0 += 4) {
    float v0 = fmaxf(bsm[f0] + ax * w0s[f0] + ay * w1s[f0] + az * w2s[f0], 0.f) * di;
    float v1 = fmaxf(bsm[f0 + 1] + ax * w0s[f0 + 1] + ay * w1s[f0 + 1] + az * w2s[f0 + 1], 0.f) * di;
    float v2 = fmaxf(bsm[f0 + 2] + ax * w0s[f0 + 2] + ay * w1s[f0 + 2] + az * w2s[f0 + 2], 0.f) * di;
    float v3 = fmaxf(bsm[f0 + 3] + ax * w0s[f0 + 3] + ay * w1s[f0 + 3] + az * w2s[f0 + 3], 0.f) * di;
    orow[f0 >> 2] = pk4_fp8(v0, v1, v2, v3);
  }
}

// ---------------- GCN layer 2 aggregation: fp8 gather, 8 lanes/node x uint4 ----------------
__global__ void k_agg128(const unsigned int* __restrict__ x1f8, const float* __restrict__ dinv,
                         const int2* __restrict__ rowptr2, const int* __restrict__ col,
                         int N, unsigned short* __restrict__ xa) {
  int g = (int)((blockIdx.x * 256 + threadIdx.x) >> 3);
  int lane = threadIdx.x & 7;
  if (g >= N) return;
  const uint4* base = (const uint4*)x1f8 + lane;  // row stride = 8 uint4 (128 B)
  float acc[16];
#pragma unroll
  for (int i = 0; i < 16; i++) acc[i] = 0.f;
  uint4 self = base[(size_t)g * 8];
  acc4_fp8(self.x, acc); acc4_fp8(self.y, acc + 4);
  acc4_fp8(self.z, acc + 8); acc4_fp8(self.w, acc + 12);
  int2 rp = rowptr2[g];
  int k = rp.x, en = rp.y;
  for (; k + 3 < en; k += 4) {
    int s0 = col[k], s1 = col[k + 1], s2 = col[k + 2], s3 = col[k + 3];
    uint4 w0 = base[(size_t)s0 * 8];
    uint4 w1 = base[(size_t)s1 * 8];
    uint4 w2 = base[(size_t)s2 * 8];
    uint4 w3 = base[(size_t)s3 * 8];
    acc4_fp8(w0.x, acc); acc4_fp8(w0.y, acc + 4); acc4_fp8(w0.z, acc + 8); acc4_fp8(w0.w, acc + 12);
    acc4_fp8(w1.x, acc); acc4_fp8(w1.y, acc + 4); acc4_fp8(w1.z, acc + 8); acc4_fp8(w1.w, acc + 12);
    acc4_fp8(w2.x, acc); acc4_fp8(w2.y, acc + 4); acc4_fp8(w2.z, acc + 8); acc4_fp8(w2.w, acc + 12);
    acc4_fp8(w3.x, acc); acc4_fp8(w3.y, acc + 4); acc4_fp8(w3.z, acc + 8); acc4_fp8(w3.w, acc + 12);
  }
  for (; k < en; k++) {
    uint4 w = base[(size_t)col[k] * 8];
    acc4_fp8(w.x, acc); acc4_fp8(w.y, acc + 4); acc4_fp8(w.z, acc + 8); acc4_fp8(w.w, acc + 12);
  }
  float di = dinv[g];
  uint4 o1, o2;
  o1.x = pack2(acc[0] * di, acc[1] * di);
  o1.y = pack2(acc[2] * di, acc[3] * di);
  o1.z = pack2(acc[4] * di, acc[5] * di);
  o1.w = pack2(acc[6] * di, acc[7] * di);
  o2.x = pack2(acc[8] * di, acc[9] * di);
  o2.y = pack2(acc[10] * di, acc[11] * di);
  o2.z = pack2(acc[12] * di, acc[13] * di);
  o2.w = pack2(acc[14] * di, acc[15] * di);
  uint4* op = (uint4*)xa + (size_t)g * 16 + lane * 2;
  op[0] = o1;
  op[1] = o2;
}

// ---------------- layer 2 GEMM via MFMA, fused heads + colsum (x2 never stored) ----------
__global__ __launch_bounds__(256) void k_gemm2(const unsigned short* __restrict__ xab,
                                               const unsigned short* __restrict__ W2T,
                                               const float* __restrict__ b2,
                                               const float* __restrict__ Ws,
                                               const float* __restrict__ bs,
                                               const float* __restrict__ Wmu,
                                               const float* __restrict__ bmu,
                                               const float* __restrict__ Wls,
                                               const float* __restrict__ bls,
                                               int N, float* __restrict__ s_arr,
                                               float* __restrict__ out,
                                               float* __restrict__ partials) {
  __shared__ float w[640];
  __shared__ float cs[4][128];
  for (int t = threadIdx.x; t < 128; t += 256) {
    w[t] = Ws[t];
    w[128 + t] = Wmu[t * 2 + 0];
    w[256 + t] = Wmu[t * 2 + 1];
    w[384 + t] = Wls[t * 2 + 0];
    w[512 + t] = Wls[t * 2 + 1];
  }
  __syncthreads();
  int wv = threadIdx.x >> 6;
  int lane = threadIdx.x & 63;
  int l15 = lane & 15, lhi = lane >> 4;
  int rowbase = blockIdx.x * 64 + wv * 16;
  int arow = rowbase + l15;
  int arowc = min(arow, N - 1);
  const unsigned short* ap = xab + (size_t)arowc * HID + lhi * 8;
  bf16x8 a[4];
#pragma unroll
  for (int kk = 0; kk < 4; kk++) a[kk] = *(const bf16x8*)(ap + kk * 32);
  float cpart[8];
  float p0[4] = {0, 0, 0, 0}, p1[4] = {0, 0, 0, 0}, p2[4] = {0, 0, 0, 0};
  float p3[4] = {0, 0, 0, 0}, p4[4] = {0, 0, 0, 0};
#pragma unroll
  for (int ct = 0; ct < 8; ct++) {
    f32x4 acc = {0.f, 0.f, 0.f, 0.f};
    const unsigned short* bp = W2T + (size_t)(ct * 16 + l15) * HID + lhi * 8;
#pragma unroll
    for (int kk = 0; kk < 4; kk++) {
      bf16x8 bfr = *(const bf16x8*)(bp + kk * 32);
      acc = __builtin_amdgcn_mfma_f32_16x16x32_bf16(a[kk], bfr, acc, 0, 0, 0);
    }
    int cidx = ct * 16 + l15;
    float bias = b2[cidx];
    float ws_ = w[cidx];
    float wm0 = w[128 + cidx], wm1 = w[256 + cidx];
    float wl0 = w[384 + cidx], wl1 = w[512 + cidx];
    float cl = 0.f;
#pragma unroll
    for (int r = 0; r < 4; r++) {
      int node = rowbase + lhi * 4 + r;
      float o = fmaxf(acc[r] + bias, 0.f);
      if (node < N) cl += o;
      p0[r] += o * ws_;
      p1[r] += o * wm0;
      p2[r] += o * wm1;
      p3[r] += o * wl0;
      p4[r] += o * wl1;
    }
    cl += __shfl_xor(cl, 16);
    cl += __shfl_xor(cl, 32);
    cpart[ct] = cl;
  }
#pragma unroll
  for (int r = 0; r < 4; r++) {
#pragma unroll
    for (int m = 1; m < 16; m <<= 1) {
      p0[r] += __shfl_xor(p0[r], m);
      p1[r] += __shfl_xor(p1[r], m);
      p2[r] += __shfl_xor(p2[r], m);
      p3[r] += __shfl_xor(p3[r], m);
      p4[r] += __shfl_xor(p4[r], m);
    }
  }
  if (l15 == 0) {
#pragma unroll
    for (int r = 0; r < 4; r++) {
      int node = rowbase + lhi * 4 + r;
      if (node < N) {
        s_arr[node] = p0[r] + bs[0];
        out[(size_t)N + node * 2 + 0] = p1[r] + bmu[0];
        out[(size_t)N + node * 2 + 1] = p2[r] + bmu[1];
        out[(size_t)3 * N + node * 2 + 0] = fminf(fmaxf(p3[r] + bls[0], -4.f), 2.f);
        out[(size_t)3 * N + node * 2 + 1] = fminf(fmaxf(p4[r] + bls[1], -4.f), 2.f);
      }
    }
  }
  if (lane < 16) {
#pragma unroll
    for (int ct = 0; ct < 8; ct++) cs[wv][ct * 16 + lane] = cpart[ct];
  }
  __syncthreads();
  if (threadIdx.x < 128) {
    int f = threadIdx.x;
    partials[(size_t)blockIdx.x * 128 + f] = cs[0][f] + cs[1][f] + cs[2][f] + cs[3][f];
  }
}

// ---------------- merged: online-LSE partials (blocks 0..255) + colsum reduce (256..319) ----
__global__ void k_lse_colsum(const float* __restrict__ s, int N, float* __restrict__ pm,
                             float* __restrict__ pt, const float* __restrict__ partials,
                             int nblkG, float* __restrict__ colsum) {
  if (blockIdx.x >= 256) {
    int bb = blockIdx.x - 256;
    int f = threadIdx.x;
    if (f < 128) {
      float t = 0.f;
      for (int b = bb; b < nblkG; b += 64) t += partials[(size_t)b * 128 + f];
      atomicAdd(&colsum[f], t);
    }
    return;
  }
  __shared__ float smM[256], smT[256];
  float m = -1e30f, t = 0.f;
  for (int i = blockIdx.x * 256 + threadIdx.x; i < N; i += 256 * 256) {
    float v = s[i];
    if (v > m) { t = t * __expf(m - v) + 1.f; m = v; }
    else t += __expf(v - m);
  }
  smM[threadIdx.x] = m; smT[threadIdx.x] = t; __syncthreads();
  for (int st = 128; st > 0; st >>= 1) {
    if (threadIdx.x < st) {
      float m2 = smM[threadIdx.x + st], t2 = smT[threadIdx.x + st];
      float m1 = smM[threadIdx.x], t1 = smT[threadIdx.x];
      float M = fmaxf(m1, m2);
      smM[threadIdx.x] = M;
      smT[threadIdx.x] = t1 * __expf(m1 - M) + t2 * __expf(m2 - M);
    }
    __syncthreads();
  }
  if (threadIdx.x == 0) { pm[blockIdx.x] = smM[0]; pt[blockIdx.x] = smT[0]; }
}

// ---------------- merged: logits (inline LSE finish) + value head (last block) ----------
__global__ void k_logits_value(const float* __restrict__ sarr, const float* __restrict__ pm,
                               const float* __restrict__ pt, int N, float* __restrict__ out,
                               const float* __restrict__ colsum, const float* __restrict__ Wv1,
                               const float* __restrict__ bv1, const float* __restrict__ Wv2,
                               const float* __restrict__ bv2, int nblkN) {
  if ((int)blockIdx.x == nblkN) {
    __shared__ float hid[64];
    float invN = 1.0f / (float)N;
    int j = threadIdx.x;
    if (j < 64) {
      float a = bv1[j];
      for (int f = 0; f < 128; f++) a += (colsum[f] * invN) * Wv1[f * 64 + j];
      hid[j] = fmaxf(a, 0.f) * Wv2[j];
    }
    __syncthreads();
    if (threadIdx.x == 0) {
      float v = bv2[0];
      for (int jj = 0; jj < 64; jj++) v += hid[jj];
      out[(size_t)5 * N] = v;
    }
    return;
  }
  __shared__ float smM[256], smT[256];
  smM[threadIdx.x] = pm[threadIdx.x];
  smT[threadIdx.x] = pt[threadIdx.x];
  __syncthreads();
  for (int st = 128; st > 0; st >>= 1) {
    if (threadIdx.x < st) {
      float m2 = smM[threadIdx.x + st], t2 = smT[threadIdx.x + st];
      float m1 = smM[threadIdx.x], t1 = smT[threadIdx.x];
      float M = fmaxf(m1, m2);
      smM[threadIdx.x] = M;
      smT[threadIdx.x] = t1 * __expf(m1 - M) + t2 * __expf(m2 - M);
    }
    __syncthreads();
  }
  float lse = smM[0] + logf(smT[0]);
  int n = blockIdx.x * 256 + threadIdx.x;
  if (n < N) out[n] = sarr[n] - lse;
}

extern "C" void kernel_launch(void* const* d_in, const int* in_sizes, int n_in,
                              void* d_out, int out_size, void* d_ws, size_t ws_size,
                              hipStream_t stream) {
  const float* coords = (const float*)d_in[0];
  const int* ei = (const int*)d_in[1];
  const float* W1 = (const float*)d_in[2];
  const float* b1 = (const float*)d_in[3];
  const float* W2 = (const float*)d_in[4];
  const float* b2 = (const float*)d_in[5];
  const float* Wsw = (const float*)d_in[6];
  const float* bsw = (const float*)d_in[7];
  const float* Wmu = (const float*)d_in[8];
  const float* bmu = (const float*)d_in[9];
  const float* Wls = (const float*)d_in[10];
  const float* bls = (const float*)d_in[11];
  const float* Wv1 = (const float*)d_in[12];
  const float* bv1 = (const float*)d_in[13];
  const float* Wv2 = (const float*)d_in[14];
  const float* bv2 = (const float*)d_in[15];
  int N = in_sizes[0] / 2;
  int E = in_sizes[1] / 2;
  const int* src = ei;
  const int* dst = ei + E;
  float* outf = (float*)d_out;
  int NB2 = (N + 1023) >> 10;
  int CAP = ((E / NB2) * 5 / 4 + 1024 + 255) & ~255;
  int nblkG = (N + 63) / 64;
  int nblkN = (N + 255) / 256;

  char* base = (char*)d_ws;
  size_t off = 0;
  auto alloc = [&](size_t bytes) -> void* {
    void* r = base + off;
    off += (bytes + 255) & ~(size_t)255;
    return r;
  };
  size_t zero_start = off;
  int* curd = (int*)alloc((size_t)NB2 * 4);
  int* curs = (int*)alloc((size_t)NB2 * 4);
  float* colsum = (float*)alloc(128 * 4);
  size_t zero_bytes = off - zero_start;
  int* bmax = (int*)alloc((size_t)NB2 * 4);
  int2* rowptr2 = (int2*)alloc((size_t)N * 8);
  int* pairsp = (int*)alloc((size_t)NB2 * CAP * 4);
  unsigned short* srcb = (unsigned short*)alloc((size_t)NB2 * CAP * 2);
  int* colarr = (int*)alloc((size_t)NB2 * CAP * 4);
  int* degsrc = (int*)alloc((size_t)N * 4);
  float* dinv = (float*)alloc((size_t)N * 4);
  float4* x0s = (float4*)alloc((size_t)N * 16);
  float* sarr = (float*)alloc((size_t)N * 4);
  float* pm = (float*)alloc(256 * 4);
  float* pt = (float*)alloc(256 * 4);
  unsigned short* W2T = (unsigned short*)alloc(128 * 128 * 2);
  float* partials = (float*)alloc((size_t)nblkG * 128 * 4);
  unsigned int* x1f8 = (unsigned int*)alloc((size_t)N * 128);      // fp8 e4m3, N x 128
  unsigned short* xab = (unsigned short*)alloc((size_t)N * HID * 2);
  if (off > ws_size) return;

  hipMemsetAsync(base + zero_start, 0, zero_bytes, stream);
  k_scatter2<<<512, 256, 0, stream>>>(src, dst, E, NB2, CAP, curd, curs, pairsp, srcb);
  k_degcsr<<<NB2, 1024, 0, stream>>>(srcb, curs, pairsp, curd, NB2, CAP, N, degsrc, bmax,
                                     rowptr2, dinv, colarr);
  k_prepW<<<64, 256, 0, stream>>>(W2, W2T);
  k_node<<<nblkN, 256, 0, stream>>>(coords, degsrc, dinv, bmax, NB2, N, x0s);
  k_agg3lin<<<nblkN, 256, 0, stream>>>(x0s, dinv, rowptr2, colarr, W1, b1, N, x1f8);
  k_agg128<<<(N * 8 + 255) / 256, 256, 0, stream>>>(x1f8, dinv, rowptr2, colarr, N, xab);
  k_gemm2<<<nblkG, 256, 0, stream>>>(xab, W2T, b2, Wsw, bsw, Wmu, bmu, Wls, bls, N, sarr, outf,
                                     partials);
  k_lse_colsum<<<320, 256, 0, stream>>>(sarr, N, pm, pt, partials, nblkG, colsum);
  k_logits_value<<<nblkN + 1, 256, 0, stream>>>(sarr, pm, pt, N, outf, colsum, Wv1, bv1, Wv2,
                                                bv2, nblkN);
}